// Round 5
// baseline (4063.593 us; speedup 1.0000x reference)
//
#include <hip/hip_runtime.h>
#include <math.h>

#define S_LEN 2048
#define DMODEL 768
#define NHEAD 12
#define DHEAD 64
#define NLAYER 12
#define FFDIM 3072
#define CHUNK 128
#define NCHUNK 16
#define QKV_N 3840   // q|k|v|kg|vg concatenated
#define DD (DMODEL * DMODEL)
#define DF (DMODEL * FFDIM)

typedef __attribute__((ext_vector_type(8))) short short8;
typedef __attribute__((ext_vector_type(4))) float f32x4;

__device__ __forceinline__ float gelu_f(float x) {
  return 0.5f * x * (1.0f + erff(x * 0.7071067811865476f));
}
// float -> bf16 bits (RNE)
__device__ __forceinline__ unsigned short f2b(float f) {
  unsigned int u = __float_as_uint(f);
  return (unsigned short)((u + 0x7FFFu + ((u >> 16) & 1u)) >> 16);
}
__device__ __forceinline__ float b2f(unsigned short u) {
  return __uint_as_float((unsigned int)u << 16);
}

// ================= embedding + LN =================
__global__ __launch_bounds__(256) void embed_ln_kernel(
    const int* __restrict__ ids, const float* __restrict__ wemb,
    const float* __restrict__ pemb, const float* __restrict__ g,
    const float* __restrict__ b, float* __restrict__ x, unsigned short* __restrict__ xb)
{
  const int s = blockIdx.x, tid = threadIdx.x;
  __shared__ float red[4];
  const size_t wbase = (size_t)ids[s] * DMODEL;
  const size_t pbase = (size_t)s * DMODEL;
  float y0 = wemb[wbase + tid]       + pemb[pbase + tid];
  float y1 = wemb[wbase + tid + 256] + pemb[pbase + tid + 256];
  float y2 = wemb[wbase + tid + 512] + pemb[pbase + tid + 512];
  float sum = y0 + y1 + y2;
  #pragma unroll
  for (int off = 32; off; off >>= 1) sum += __shfl_down(sum, off);
  if ((tid & 63) == 0) red[tid >> 6] = sum;
  __syncthreads();
  const float mean = (red[0] + red[1] + red[2] + red[3]) * (1.0f / 768.0f);
  __syncthreads();
  float d0 = y0 - mean, d1 = y1 - mean, d2 = y2 - mean;
  float vs = d0*d0 + d1*d1 + d2*d2;
  #pragma unroll
  for (int off = 32; off; off >>= 1) vs += __shfl_down(vs, off);
  if ((tid & 63) == 0) red[tid >> 6] = vs;
  __syncthreads();
  const float rstd = rsqrtf((red[0]+red[1]+red[2]+red[3]) * (1.0f/768.0f) + 1e-5f);
  float o0 = d0 * rstd * g[tid]       + b[tid];
  float o1 = d1 * rstd * g[tid + 256] + b[tid + 256];
  float o2 = d2 * rstd * g[tid + 512] + b[tid + 512];
  x[pbase + tid] = o0; x[pbase + tid + 256] = o1; x[pbase + tid + 512] = o2;
  xb[pbase + tid] = f2b(o0); xb[pbase + tid + 256] = f2b(o1); xb[pbase + tid + 512] = f2b(o2);
}

// ================= LN of t (t already holds residual sum) -> x (f32) + xb (bf16) ======
__global__ __launch_bounds__(256) void ln_fused_kernel(
    const float* __restrict__ t, const float* __restrict__ g,
    const float* __restrict__ b, float* __restrict__ x, unsigned short* __restrict__ xb)
{
  const int s = blockIdx.x, tid = threadIdx.x;
  __shared__ float red[4];
  const size_t base = (size_t)s * DMODEL;
  float y0 = t[base + tid], y1 = t[base + tid + 256], y2 = t[base + tid + 512];
  float sum = y0 + y1 + y2;
  #pragma unroll
  for (int off = 32; off; off >>= 1) sum += __shfl_down(sum, off);
  if ((tid & 63) == 0) red[tid >> 6] = sum;
  __syncthreads();
  const float mean = (red[0] + red[1] + red[2] + red[3]) * (1.0f / 768.0f);
  __syncthreads();
  float d0 = y0 - mean, d1 = y1 - mean, d2 = y2 - mean;
  float vs = d0*d0 + d1*d1 + d2*d2;
  #pragma unroll
  for (int off = 32; off; off >>= 1) vs += __shfl_down(vs, off);
  if ((tid & 63) == 0) red[tid >> 6] = vs;
  __syncthreads();
  const float rstd = rsqrtf((red[0]+red[1]+red[2]+red[3]) * (1.0f/768.0f) + 1e-5f);
  float o0 = d0 * rstd * g[tid]       + b[tid];
  float o1 = d1 * rstd * g[tid + 256] + b[tid + 256];
  float o2 = d2 * rstd * g[tid + 512] + b[tid + 512];
  x[base + tid] = o0; x[base + tid + 256] = o1; x[base + tid + 512] = o2;
  xb[base + tid] = f2b(o0); xb[base + tid + 256] = f2b(o1); xb[base + tid + 512] = f2b(o2);
}

__global__ __launch_bounds__(256) void ln_vec_kernel(
    const float* __restrict__ in, const float* __restrict__ g,
    const float* __restrict__ b, float* __restrict__ out)
{
  const int tid = threadIdx.x;
  __shared__ float red[4];
  float y0 = in[tid], y1 = in[tid + 256], y2 = in[tid + 512];
  float sum = y0 + y1 + y2;
  #pragma unroll
  for (int off = 32; off; off >>= 1) sum += __shfl_down(sum, off);
  if ((tid & 63) == 0) red[tid >> 6] = sum;
  __syncthreads();
  const float mean = (red[0] + red[1] + red[2] + red[3]) * (1.0f / 768.0f);
  __syncthreads();
  float d0 = y0 - mean, d1 = y1 - mean, d2 = y2 - mean;
  float vs = d0*d0 + d1*d1 + d2*d2;
  #pragma unroll
  for (int off = 32; off; off >>= 1) vs += __shfl_down(vs, off);
  if ((tid & 63) == 0) red[tid >> 6] = vs;
  __syncthreads();
  const float rstd = rsqrtf((red[0]+red[1]+red[2]+red[3]) * (1.0f/768.0f) + 1e-5f);
  out[tid]       = d0 * rstd * g[tid]       + b[tid];
  out[tid + 256] = d1 * rstd * g[tid + 256] + b[tid + 256];
  out[tid + 512] = d2 * rstd * g[tid + 512] + b[tid + 512];
}

// ====== one-shot weight convert+transpose, 64x64 tiles (f32 [K][N] -> bf16 [N][K]) ====
__global__ __launch_bounds__(256) void conv_all_dd_kernel(
    const float* __restrict__ Wq, const float* __restrict__ Wk, const float* __restrict__ Wv,
    const float* __restrict__ Wkg, const float* __restrict__ Wvg, const float* __restrict__ Wo,
    const float* __restrict__ bq, const float* __restrict__ bk, const float* __restrict__ bv,
    const float* __restrict__ bkg, const float* __restrict__ bvg,
    unsigned short* __restrict__ WqkvT, unsigned short* __restrict__ WoT,
    float* __restrict__ bqkv)
{
  const int z = blockIdx.z, layer = z / 6, mat = z % 6;
  const size_t off = (size_t)layer * DD;
  const float* src = (mat==0?Wq: mat==1?Wk: mat==2?Wv: mat==3?Wkg: mat==4?Wvg: Wo) + off;
  unsigned short* dst = (mat < 5)
      ? (WqkvT + (size_t)layer * 5 * DD + (size_t)mat * DD)
      : (WoT + off);
  __shared__ float tbuf[64][65];
  const int n0 = blockIdx.x * 64, k0 = blockIdx.y * 64;
  const int t = threadIdx.x;
  #pragma unroll
  for (int i = 0; i < 4; ++i) {
    const int idx = i * 256 + t;
    const int r = idx >> 4, c4 = (idx & 15) * 4;
    const float4 v = *(const float4*)&src[(size_t)(k0 + r) * DMODEL + n0 + c4];
    tbuf[r][c4] = v.x; tbuf[r][c4+1] = v.y; tbuf[r][c4+2] = v.z; tbuf[r][c4+3] = v.w;
  }
  __syncthreads();
  const int n = t >> 2, seg = (t & 3) * 16;
  unsigned short o[16];
  #pragma unroll
  for (int i = 0; i < 16; ++i) o[i] = f2b(tbuf[seg + i][n]);
  unsigned short* dp = &dst[(size_t)(n0 + n) * DMODEL + k0 + seg];
  *(short8*)dp = *(const short8*)&o[0];
  *(short8*)(dp + 8) = *(const short8*)&o[8];
  if (mat < 5 && blockIdx.x == 0 && blockIdx.y == 0) {
    const float* bs = (mat==0?bq: mat==1?bk: mat==2?bv: mat==3?bkg: bvg) + (size_t)layer * DMODEL;
    for (int i = t; i < DMODEL; i += 256) bqkv[(size_t)layer * QKV_N + mat * DMODEL + i] = bs[i];
  }
}

__global__ __launch_bounds__(256) void conv_all_ffn_kernel(
    const float* __restrict__ Wf1, const float* __restrict__ Wf2,
    unsigned short* __restrict__ Wf1T, unsigned short* __restrict__ Wf2T)
{
  const int z = blockIdx.z, layer = z / 2, which = z % 2;
  __shared__ float tbuf[64][65];
  const float* src; unsigned short* dst; int Kd, Nd, n0, k0;
  if (which == 0) { src = Wf1 + (size_t)layer * DF; dst = Wf1T + (size_t)layer * DF;
                    Kd = DMODEL; Nd = FFDIM; n0 = blockIdx.x * 64; k0 = blockIdx.y * 64; }
  else            { src = Wf2 + (size_t)layer * DF; dst = Wf2T + (size_t)layer * DF;
                    Kd = FFDIM; Nd = DMODEL; n0 = blockIdx.y * 64; k0 = blockIdx.x * 64; }
  const int t = threadIdx.x;
  #pragma unroll
  for (int i = 0; i < 4; ++i) {
    const int idx = i * 256 + t;
    const int r = idx >> 4, c4 = (idx & 15) * 4;
    const float4 v = *(const float4*)&src[(size_t)(k0 + r) * Nd + n0 + c4];
    tbuf[r][c4] = v.x; tbuf[r][c4+1] = v.y; tbuf[r][c4+2] = v.z; tbuf[r][c4+3] = v.w;
  }
  __syncthreads();
  const int n = t >> 2, seg = (t & 3) * 16;
  unsigned short o[16];
  #pragma unroll
  for (int i = 0; i < 16; ++i) o[i] = f2b(tbuf[seg + i][n]);
  unsigned short* dp = &dst[(size_t)(n0 + n) * Kd + k0 + seg];
  *(short8*)dp = *(const short8*)&o[0];
  *(short8*)(dp + 8) = *(const short8*)&o[8];
}

// ======= bf16 MFMA GEMM (BMx128 tile, BK=64, swizzled LDS, XCD swizzle, residual) =====
template <int BM>
__global__ __launch_bounds__(256) void gemm_mfma_kernel(
    const unsigned short* __restrict__ A, const unsigned short* __restrict__ Bt,
    const float* __restrict__ bias, const float* __restrict__ Res,
    float* __restrict__ Cf, unsigned short* __restrict__ Cb, int N, int K, int act)
{
  constexpr int ASLOTS = BM * 8;
  constexpr int MI = BM / 32;
  __shared__ unsigned short As[ASLOTS * 8];
  __shared__ unsigned short Bs[8192];
  const int tid = threadIdx.x, wave = tid >> 6, lane = tid & 63;
  const int gx = gridDim.x, nwg = gx * gridDim.y;
  int flat = blockIdx.y * gx + blockIdx.x;
  flat = (flat & 7) * (nwg >> 3) + (flat >> 3);
  const int bm = (flat % gx) * BM, bn = (flat / gx) * 128;
  const int wr = (wave >> 1) * (BM / 2), wc = (wave & 1) * 64;
  f32x4 acc[MI][4];
  const f32x4 zz = {0.f, 0.f, 0.f, 0.f};
  #pragma unroll
  for (int i = 0; i < MI; ++i)
    #pragma unroll
    for (int j = 0; j < 4; ++j) acc[i][j] = zz;

  for (int k0 = 0; k0 < K; k0 += 64) {
    #pragma unroll
    for (int it = 0; it < ASLOTS / 256; ++it) {
      const int s = it * 256 + tid;
      const int mr = s >> 3;
      const int kg = (s & 7) ^ (mr & 7);
      const unsigned short* src = A + (size_t)(bm + mr) * K + k0 + kg * 8;
      __builtin_amdgcn_global_load_lds(
          (const __attribute__((address_space(1))) void*)src,
          (__attribute__((address_space(3))) void*)&As[(size_t)(it * 256 + wave * 64) * 8], 16, 0, 0);
    }
    #pragma unroll
    for (int it = 0; it < 4; ++it) {
      const int s = it * 256 + tid;
      const int mr = s >> 3;
      const int kg = (s & 7) ^ (mr & 7);
      const unsigned short* src = Bt + (size_t)(bn + mr) * K + k0 + kg * 8;
      __builtin_amdgcn_global_load_lds(
          (const __attribute__((address_space(1))) void*)src,
          (__attribute__((address_space(3))) void*)&Bs[(size_t)(it * 256 + wave * 64) * 8], 16, 0, 0);
    }
    __syncthreads();
    #pragma unroll
    for (int ks = 0; ks < 2; ++ks) {
      const int kg = ks * 4 + (lane >> 4);
      short8 af[MI], bfr[4];
      #pragma unroll
      for (int i = 0; i < MI; ++i) {
        const int m = wr + i * 16 + (lane & 15);
        af[i] = *(const short8*)&As[(m * 8 + (kg ^ (m & 7))) * 8];
      }
      #pragma unroll
      for (int j = 0; j < 4; ++j) {
        const int n = wc + j * 16 + (lane & 15);
        bfr[j] = *(const short8*)&Bs[(n * 8 + (kg ^ (n & 7))) * 8];
      }
      #pragma unroll
      for (int i = 0; i < MI; ++i)
        #pragma unroll
        for (int j = 0; j < 4; ++j)
          acc[i][j] = __builtin_amdgcn_mfma_f32_16x16x32_bf16(af[i], bfr[j], acc[i][j], 0, 0, 0);
    }
    __syncthreads();
  }

  const int lr = (lane >> 4) * 4, lc = lane & 15;
  #pragma unroll
  for (int i = 0; i < MI; ++i) {
    #pragma unroll
    for (int j = 0; j < 4; ++j) {
      const int n = bn + wc + j * 16 + lc;
      const float bv = bias[n];
      #pragma unroll
      for (int p = 0; p < 4; ++p) {
        const int m = bm + wr + i * 16 + lr + p;
        float val = acc[i][j][p] + bv;
        if (Res) val += Res[(size_t)m * N + n];
        if (act) val = gelu_f(val);
        if (Cf) Cf[(size_t)m * N + n] = val;
        if (Cb) Cb[(size_t)m * N + n] = f2b(val);
      }
    }
  }
}

// ============ fused attention: banded flash (y<16) + global CLS row (y==16) ==========
__global__ __launch_bounds__(256) void attn_fused_kernel(
    const unsigned short* __restrict__ qkvb, const float* __restrict__ xf,
    const float* __restrict__ Wqg, const float* __restrict__ bqg,
    const int* __restrict__ am, unsigned short* __restrict__ outb)
{
  __shared__ __align__(16) unsigned char smem[67072];
  const int h = blockIdx.x, tid = threadIdx.x;

  if (blockIdx.y == NCHUNK) {
    // ---------------- global CLS query row ----------------
    float* sc  = (float*)smem;            // 2048 f32
    float* qs  = (float*)(smem + 8192);   // 64
    float* red = (float*)(smem + 8448);   // 4
    float* pb  = (float*)(smem + 8464);   // 4*64
    float* pqg = (float*)(smem + 9488);   // 4*64
    const int d = tid & 63, grp = tid >> 6;
    // qg0 slice for this head: x[0] @ Wqg[:, h*64+d]
    {
      float p = 0.f;
      const float* wcol = Wqg + (size_t)(grp * 192) * DMODEL + h * DHEAD + d;
      #pragma unroll 4
      for (int k = 0; k < 192; ++k)
        p = fmaf(xf[grp * 192 + k], wcol[(size_t)k * DMODEL], p);
      pqg[grp * 64 + d] = p;
    }
    __syncthreads();
    if (tid < 64)
      qs[tid] = (pqg[tid] + pqg[64 + tid] + pqg[128 + tid] + pqg[192 + tid]
                 + bqg[h * DHEAD + tid]) * 0.125f;
    __syncthreads();
    const unsigned short* kg = qkvb + 3 * DMODEL + h * DHEAD;
    const unsigned short* vg = qkvb + 4 * DMODEL + h * DHEAD;
    for (int s0 = tid; s0 < S_LEN; s0 += 256) {
      const unsigned short* kr = kg + (size_t)s0 * QKV_N;
      float dd = 0.f;
      #pragma unroll
      for (int d0 = 0; d0 < DHEAD; d0 += 8) {
        const short8 k8 = *(const short8*)(kr + d0);
        #pragma unroll
        for (int e = 0; e < 8; ++e) dd += qs[d0 + e] * b2f((unsigned short)k8[e]);
      }
      sc[s0] = (am[s0] > 0) ? dd : -1e9f;
    }
    __syncthreads();
    float mx = -1e30f;
    for (int s0 = tid; s0 < S_LEN; s0 += 256) mx = fmaxf(mx, sc[s0]);
    #pragma unroll
    for (int off = 32; off; off >>= 1) mx = fmaxf(mx, __shfl_down(mx, off));
    if ((tid & 63) == 0) red[tid >> 6] = mx;
    __syncthreads();
    mx = fmaxf(fmaxf(red[0], red[1]), fmaxf(red[2], red[3]));
    __syncthreads();
    float sum = 0.f;
    for (int s0 = tid; s0 < S_LEN; s0 += 256) {
      const float e = __expf(sc[s0] - mx);
      sc[s0] = e;
      sum += e;
    }
    #pragma unroll
    for (int off = 32; off; off >>= 1) sum += __shfl_down(sum, off);
    if ((tid & 63) == 0) red[tid >> 6] = sum;
    __syncthreads();
    const float total = red[0] + red[1] + red[2] + red[3];
    float pa = 0.f;
    for (int s0 = grp; s0 < S_LEN; s0 += 4)
      pa = fmaf(sc[s0], b2f(vg[(size_t)s0 * QKV_N + d]), pa);
    pb[grp * 64 + d] = pa;
    __syncthreads();
    if (tid < 64)
      outb[h * DHEAD + tid] = f2b((pb[tid] + pb[64 + tid] + pb[128 + tid] + pb[192 + tid]) / total);
    return;
  }

  // ---------------- banded sliding-window flash ----------------
  const int nc = blockIdx.y;
  const int wave = tid >> 6, lane = tid & 63;
  const int c = lane & 15, g = lane >> 4;
  unsigned short* Ks = (unsigned short*)smem;             // 16 KB
  unsigned short* Vt = (unsigned short*)(smem + 16384);   // 16 KB
  unsigned short* Ps = (unsigned short*)(smem + 32768);   // 32 KB
  float* smcls = (float*)(smem + 65536);                  // 512 B
  float* sv0   = (float*)(smem + 66048);                  // 256 B
  int*   sam   = (int*)(smem + 66304);                    // 512 B

  if (tid < 64) sv0[tid] = b2f(qkvb[2 * DMODEL + h * DHEAD + tid]);
  if (tid < 128) {
    const int qrow = nc * CHUNK + tid;
    const unsigned short* qp = qkvb + (size_t)qrow * QKV_N + h * DHEAD;
    const unsigned short* k0 = qkvb + DMODEL + h * DHEAD;
    float d = 0.f;
    #pragma unroll
    for (int dd = 0; dd < 64; dd += 8) {
      const short8 a8 = *(const short8*)(qp + dd);
      const short8 b8 = *(const short8*)(k0 + dd);
      #pragma unroll
      for (int e = 0; e < 8; ++e)
        d += b2f((unsigned short)a8[e]) * b2f((unsigned short)b8[e]);
    }
    smcls[tid] = (am[0] > 0) ? d * 0.125f : -1e9f;
  }

  short8 af[2][2];
  #pragma unroll
  for (int i = 0; i < 2; ++i)
    #pragma unroll
    for (int ks = 0; ks < 2; ++ks) {
      const int qrow = nc * CHUNK + wave * 32 + i * 16 + c;
      af[i][ks] = *(const short8*)(qkvb + (size_t)qrow * QKV_N + h * DHEAD + (ks * 4 + g) * 8);
    }

  __syncthreads();

  float mrow[2][4], lrow[2][4];
  f32x4 acc_o[2][4];
  #pragma unroll
  for (int i = 0; i < 2; ++i)
    #pragma unroll
    for (int p = 0; p < 4; ++p) {
      mrow[i][p] = smcls[wave * 32 + i * 16 + g * 4 + p];
      lrow[i][p] = 1.f;
    }
  #pragma unroll
  for (int i = 0; i < 2; ++i)
    #pragma unroll
    for (int j = 0; j < 4; ++j) {
      const float v0 = sv0[j * 16 + c];
      acc_o[i][j][0] = v0; acc_o[i][j][1] = v0; acc_o[i][j][2] = v0; acc_o[i][j][3] = v0;
    }

  for (int kci = 0; kci < 3; ++kci) {
    const int ck = nc - 1 + kci;
    if (ck < 0 || ck > 15) continue;
    __syncthreads();

    #pragma unroll
    for (int it = 0; it < 4; ++it) {
      const int sidx = it * 256 + tid;
      const int mr = sidx >> 3;
      const int kg = (sidx & 7) ^ (mr & 7);
      const unsigned short* src = qkvb + (size_t)(ck * CHUNK + mr) * QKV_N + DMODEL + h * DHEAD + kg * 8;
      __builtin_amdgcn_global_load_lds(
          (const __attribute__((address_space(1))) void*)src,
          (__attribute__((address_space(3))) void*)&Ks[(size_t)(it * 256 + wave * 64) * 8], 16, 0, 0);
    }
    {
      const int kp = tid & 63, dh = tid >> 6;
      const unsigned short* v0p = qkvb + (size_t)(ck * CHUNK + 2 * kp) * QKV_N + 2 * DMODEL + h * DHEAD + dh * 16;
      const short8 a0 = *(const short8*)(v0p);
      const short8 a1 = *(const short8*)(v0p + 8);
      const short8 b0 = *(const short8*)(v0p + QKV_N);
      const short8 b1 = *(const short8*)(v0p + QKV_N + 8);
      #pragma unroll
      for (int dd = 0; dd < 16; ++dd) {
        const int dim = dh * 16 + dd;
        const unsigned short lo = (unsigned short)(dd < 8 ? a0[dd] : a1[dd - 8]);
        const unsigned short hi = (unsigned short)(dd < 8 ? b0[dd] : b1[dd - 8]);
        const unsigned int w = (unsigned int)lo | ((unsigned int)hi << 16);
        const int si = dim * 128 + (((kp >> 2) ^ (dim & 7)) << 3) + ((kp & 3) << 1);
        *(unsigned int*)&Vt[si] = w;
      }
    }
    if (tid < 128) sam[tid] = am[ck * CHUNK + tid];
    __syncthreads();

    f32x4 accs[2][8];
    const f32x4 zz = {0.f, 0.f, 0.f, 0.f};
    #pragma unroll
    for (int i = 0; i < 2; ++i)
      #pragma unroll
      for (int j = 0; j < 8; ++j) accs[i][j] = zz;
    #pragma unroll
    for (int ks = 0; ks < 2; ++ks) {
      const int kg = ks * 4 + g;
      short8 bfr[8];
      #pragma unroll
      for (int j = 0; j < 8; ++j) {
        const int jj = j * 16 + c;
        bfr[j] = *(const short8*)&Ks[(jj * 8 + (kg ^ (jj & 7))) * 8];
      }
      #pragma unroll
      for (int i = 0; i < 2; ++i)
        #pragma unroll
        for (int j = 0; j < 8; ++j)
          accs[i][j] = __builtin_amdgcn_mfma_f32_16x16x32_bf16(af[i][ks], bfr[j], accs[i][j], 0, 0, 0);
    }

    #pragma unroll
    for (int i = 0; i < 2; ++i) {
      #pragma unroll
      for (int p = 0; p < 4; ++p) {
        const int mloc = wave * 32 + i * 16 + g * 4 + p;
        const int qi = nc * CHUNK + mloc;
        float sv[8];
        float rmax = -1e30f;
        #pragma unroll
        for (int j = 0; j < 8; ++j) {
          const int jj = j * 16 + c;
          const int kj = ck * CHUNK + jj;
          const int diff = qi - kj;
          const bool ok = (diff <= 128) && (diff >= -128) && (kj != 0) && (sam[jj] > 0);
          const float s = ok ? accs[i][j][p] * 0.125f : -1e9f;
          sv[j] = s;
          rmax = fmaxf(rmax, s);
        }
        rmax = fmaxf(rmax, __shfl_xor(rmax, 1));
        rmax = fmaxf(rmax, __shfl_xor(rmax, 2));
        rmax = fmaxf(rmax, __shfl_xor(rmax, 4));
        rmax = fmaxf(rmax, __shfl_xor(rmax, 8));
        const float mnew = fmaxf(mrow[i][p], rmax);
        const float corr = __expf(mrow[i][p] - mnew);
        float psum = 0.f;
        #pragma unroll
        for (int j = 0; j < 8; ++j) {
          const float pv = __expf(sv[j] - mnew);
          sv[j] = pv;
          psum += pv;
        }
        psum += __shfl_xor(psum, 1);
        psum += __shfl_xor(psum, 2);
        psum += __shfl_xor(psum, 4);
        psum += __shfl_xor(psum, 8);
        lrow[i][p] = lrow[i][p] * corr + psum;
        mrow[i][p] = mnew;
        #pragma unroll
        for (int j = 0; j < 4; ++j) acc_o[i][j][p] *= corr;
        #pragma unroll
        for (int j = 0; j < 8; ++j) {
          const int key = j * 16 + c;
          const int kslot = key >> 3;
          Ps[mloc * 128 + ((kslot ^ (mloc & 7)) << 3) + (key & 7)] = f2b(sv[j]);
        }
      }
    }
    asm volatile("s_waitcnt lgkmcnt(0)" ::: "memory");

    #pragma unroll
    for (int ks2 = 0; ks2 < 4; ++ks2) {
      const int kg2 = ks2 * 4 + g;
      short8 pa[2], vb[4];
      #pragma unroll
      for (int i = 0; i < 2; ++i) {
        const int row = wave * 32 + i * 16 + c;
        pa[i] = *(const short8*)&Ps[row * 128 + ((kg2 ^ (row & 7)) << 3)];
      }
      #pragma unroll
      for (int j = 0; j < 4; ++j) {
        const int n = j * 16 + c;
        vb[j] = *(const short8*)&Vt[n * 128 + ((kg2 ^ (n & 7)) << 3)];
      }
      #pragma unroll
      for (int i = 0; i < 2; ++i)
        #pragma unroll
        for (int j = 0; j < 4; ++j)
          acc_o[i][j] = __builtin_amdgcn_mfma_f32_16x16x32_bf16(pa[i], vb[j], acc_o[i][j], 0, 0, 0);
    }
  }

  #pragma unroll
  for (int i = 0; i < 2; ++i) {
    #pragma unroll
    for (int p = 0; p < 4; ++p) {
      const float rl = (lrow[i][p] > 0.f) ? 1.f / lrow[i][p] : 0.f;
      const int row = nc * CHUNK + wave * 32 + i * 16 + g * 4 + p;
      if (row == 0) continue;  // row 0 owned by the global branch
      #pragma unroll
      for (int j = 0; j < 4; ++j)
        outb[(size_t)row * DMODEL + h * DHEAD + j * 16 + c] = f2b(acc_o[i][j][p] * rl);
    }
  }
}

// ================= split-k GEMV (head MLP only) =================
__global__ __launch_bounds__(256) void gemv_partial_kernel(
    const float* __restrict__ xrow, const float* __restrict__ W, float* __restrict__ part)
{
  const int b = blockIdx.x, t = threadIdx.x;
  float s0 = 0.f, s1 = 0.f, s2 = 0.f;
  for (int kk = 0; kk < 48; ++kk) {
    const int k = b * 48 + kk;
    const float xv = xrow[k];
    const float* wr = W + (size_t)k * DMODEL;
    s0 = fmaf(xv, wr[t], s0);
    s1 = fmaf(xv, wr[t + 256], s1);
    s2 = fmaf(xv, wr[t + 512], s2);
  }
  part[b * DMODEL + t] = s0;
  part[b * DMODEL + t + 256] = s1;
  part[b * DMODEL + t + 512] = s2;
}

__global__ __launch_bounds__(256) void gemv_reduce_kernel(
    const float* __restrict__ part, const float* __restrict__ bias,
    float* __restrict__ y, int act)
{
  const int n = blockIdx.x * 256 + threadIdx.x;
  float s = bias[n];
  #pragma unroll
  for (int b = 0; b < 16; ++b) s += part[b * DMODEL + n];
  if (act) s = gelu_f(s);
  y[n] = s;
}

// ================= final head =================
__global__ __launch_bounds__(256) void head_final_kernel(
    const float* __restrict__ h2, const float* __restrict__ Wout,
    const float* __restrict__ bout, float* __restrict__ out)
{
  const int tid = threadIdx.x;
  __shared__ float red[4];
  float p = h2[tid]*Wout[tid] + h2[tid+256]*Wout[tid+256] + h2[tid+512]*Wout[tid+512];
  #pragma unroll
  for (int off = 32; off; off >>= 1) p += __shfl_down(p, off);
  if ((tid & 63) == 0) red[tid >> 6] = p;
  __syncthreads();
  if (tid == 0) {
    const float logit = red[0] + red[1] + red[2] + red[3] + bout[0];
    const float sig = 1.0f / (1.0f + expf(-logit));
    const unsigned int bits = __float_as_uint(sig);
    const unsigned int bf = (bits + 0x7FFFu + ((bits >> 16) & 1u)) >> 16;
    out[0] = __uint_as_float((bits & 0xFFFF0000u) | (bf & 0xFFFFu));
  }
}

extern "C" void kernel_launch(void* const* d_in, const int* in_sizes, int n_in,
                              void* d_out, int out_size, void* d_ws, size_t ws_size,
                              hipStream_t stream)
{
  const int*   ids  = (const int*)d_in[0];
  const int*   am   = (const int*)d_in[1];
  const float* wemb = (const float*)d_in[2];
  const float* pemb = (const float*)d_in[3];
  const float* emb_g = (const float*)d_in[4];
  const float* emb_b = (const float*)d_in[5];
  const float* Wq  = (const float*)d_in[6];
  const float* bq  = (const float*)d_in[7];
  const float* Wk  = (const float*)d_in[8];
  const float* bk  = (const float*)d_in[9];
  const float* Wv  = (const float*)d_in[10];
  const float* bv  = (const float*)d_in[11];
  const float* Wqg = (const float*)d_in[12];
  const float* bqg = (const float*)d_in[13];
  const float* Wkg = (const float*)d_in[14];
  const float* bkg = (const float*)d_in[15];
  const float* Wvg = (const float*)d_in[16];
  const float* bvg = (const float*)d_in[17];
  const float* Wo  = (const float*)d_in[18];
  const float* bo  = (const float*)d_in[19];
  const float* ln1g = (const float*)d_in[20];
  const float* ln1b = (const float*)d_in[21];
  const float* Wf1 = (const float*)d_in[22];
  const float* bf1 = (const float*)d_in[23];
  const float* Wf2 = (const float*)d_in[24];
  const float* bf2 = (const float*)d_in[25];
  const float* ln2g = (const float*)d_in[26];
  const float* ln2b = (const float*)d_in[27];
  const float* hng = (const float*)d_in[28];
  const float* hnb = (const float*)d_in[29];
  const float* W1  = (const float*)d_in[30];
  const float* b1  = (const float*)d_in[31];
  const float* W2  = (const float*)d_in[32];
  const float* b2  = (const float*)d_in[33];
  const float* Wout = (const float*)d_in[34];
  const float* bout = (const float*)d_in[35];

  char* wp = (char*)d_ws;
  auto alloc = [&](size_t bytes) -> void* {
    void* r = (void*)wp;
    wp += (bytes + 255) & ~(size_t)255;
    return r;
  };
  float*          x         = (float*)alloc((size_t)S_LEN * DMODEL * 4);
  unsigned short* xb        = (unsigned short*)alloc((size_t)S_LEN * DMODEL * 2);
  unsigned short* qkvb      = (unsigned short*)alloc((size_t)S_LEN * QKV_N * 2);
  unsigned short* attnb     = (unsigned short*)alloc((size_t)S_LEN * DMODEL * 2);
  unsigned short* tmpb      = (unsigned short*)alloc((size_t)S_LEN * FFDIM * 2);
  float*          tmpf      = (float*)alloc((size_t)S_LEN * DMODEL * 4);
  unsigned short* WqkvT_all = (unsigned short*)alloc((size_t)NLAYER * 5 * DD * 2);
  unsigned short* WoT_all   = (unsigned short*)alloc((size_t)NLAYER * DD * 2);
  unsigned short* Wf1T_all  = (unsigned short*)alloc((size_t)NLAYER * DF * 2);
  unsigned short* Wf2T_all  = (unsigned short*)alloc((size_t)NLAYER * DF * 2);
  float*          bqkv_all  = (float*)alloc((size_t)NLAYER * QKV_N * 4);
  float*          gpart     = (float*)alloc((size_t)16 * DMODEL * 4);
  float*          hb        = (float*)alloc((size_t)3 * DMODEL * 4);

  // one-shot weight conversion for all layers (BW-bound, 2 launches)
  conv_all_dd_kernel<<<dim3(12, 12, 6 * NLAYER), 256, 0, stream>>>(
      Wq, Wk, Wv, Wkg, Wvg, Wo, bq, bk, bv, bkg, bvg, WqkvT_all, WoT_all, bqkv_all);
  conv_all_ffn_kernel<<<dim3(48, 12, 2 * NLAYER), 256, 0, stream>>>(
      Wf1, Wf2, Wf1T_all, Wf2T_all);

  embed_ln_kernel<<<S_LEN, 256, 0, stream>>>(ids, wemb, pemb, emb_g, emb_b, x, xb);

  for (int l = 0; l < NLAYER; ++l) {
    const size_t wdd = (size_t)l * DD;
    const size_t vd  = (size_t)l * DMODEL;
    const size_t vf  = (size_t)l * FFDIM;
    const unsigned short* WqkvT = WqkvT_all + (size_t)l * 5 * DD;
    const unsigned short* WoT   = WoT_all + wdd;
    const unsigned short* Wf1T  = Wf1T_all + (size_t)l * DF;
    const unsigned short* Wf2T  = Wf2T_all + (size_t)l * DF;
    const float* bqkv = bqkv_all + (size_t)l * QKV_N;

    // fused q|k|v|kg|vg projection: [2048,768] @ [768,3840] -> bf16
    gemm_mfma_kernel<128><<<dim3(16, 30), 256, 0, stream>>>(
        xb, WqkvT, bqkv, (const float*)nullptr, (float*)nullptr, qkvb, QKV_N, DMODEL, 0);

    // banded flash + global CLS row (incl. qg0) in one launch
    attn_fused_kernel<<<dim3(NHEAD, NCHUNK + 1), 256, 0, stream>>>(
        qkvb, x, Wqg + wdd, bqg + vd, am, attnb);

    // Wo projection + residual add fused
    gemm_mfma_kernel<64><<<dim3(32, 6), 256, 0, stream>>>(
        attnb, WoT, bo + vd, x, tmpf, (unsigned short*)nullptr, DMODEL, DMODEL, 0);
    ln_fused_kernel<<<S_LEN, 256, 0, stream>>>(tmpf, ln1g + vd, ln1b + vd, x, xb);

    gemm_mfma_kernel<128><<<dim3(16, 24), 256, 0, stream>>>(
        xb, Wf1T, bf1 + vf, (const float*)nullptr, (float*)nullptr, tmpb, FFDIM, DMODEL, 1);
    gemm_mfma_kernel<64><<<dim3(32, 6), 256, 0, stream>>>(
        tmpb, Wf2T, bf2 + vd, x, tmpf, (unsigned short*)nullptr, DMODEL, FFDIM, 0);
    ln_fused_kernel<<<S_LEN, 256, 0, stream>>>(tmpf, ln2g + vd, ln2b + vd, x, xb);
  }

  ln_vec_kernel<<<1, 256, 0, stream>>>(x, hng, hnb, hb);
  gemv_partial_kernel<<<16, 256, 0, stream>>>(hb, W1, gpart);
  gemv_reduce_kernel<<<3, 256, 0, stream>>>(gpart, b1, hb + DMODEL, 1);
  gemv_partial_kernel<<<16, 256, 0, stream>>>(hb + DMODEL, W2, gpart);
  gemv_reduce_kernel<<<3, 256, 0, stream>>>(gpart, b2, hb + 2 * DMODEL, 1);
  head_final_kernel<<<1, 256, 0, stream>>>(hb + 2 * DMODEL, Wout, bout, (float*)d_out);
}

// Round 6
// 2699.245 us; speedup vs baseline: 1.5055x; 1.5055x over previous
//
#include <hip/hip_runtime.h>
#include <math.h>

#define S_LEN 2048
#define DMODEL 768
#define NHEAD 12
#define DHEAD 64
#define NLAYER 12
#define FFDIM 3072
#define CHUNK 128
#define NCHUNK 16
#define QKV_N 3840   // q|k|v|kg|vg concatenated
#define DD (DMODEL * DMODEL)
#define DF (DMODEL * FFDIM)

typedef __attribute__((ext_vector_type(8))) short short8;
typedef __attribute__((ext_vector_type(4))) float f32x4;

__device__ __forceinline__ float gelu_f(float x) {
  return 0.5f * x * (1.0f + erff(x * 0.7071067811865476f));
}
// float -> bf16 bits (RNE)
__device__ __forceinline__ unsigned short f2b(float f) {
  unsigned int u = __float_as_uint(f);
  return (unsigned short)((u + 0x7FFFu + ((u >> 16) & 1u)) >> 16);
}
__device__ __forceinline__ float b2f(unsigned short u) {
  return __uint_as_float((unsigned int)u << 16);
}

// ================= embedding + LN =================
__global__ __launch_bounds__(256) void embed_ln_kernel(
    const int* __restrict__ ids, const float* __restrict__ wemb,
    const float* __restrict__ pemb, const float* __restrict__ g,
    const float* __restrict__ b, float* __restrict__ x, unsigned short* __restrict__ xb)
{
  const int s = blockIdx.x, tid = threadIdx.x;
  __shared__ float red[4];
  const size_t wbase = (size_t)ids[s] * DMODEL;
  const size_t pbase = (size_t)s * DMODEL;
  float y0 = wemb[wbase + tid]       + pemb[pbase + tid];
  float y1 = wemb[wbase + tid + 256] + pemb[pbase + tid + 256];
  float y2 = wemb[wbase + tid + 512] + pemb[pbase + tid + 512];
  float sum = y0 + y1 + y2;
  #pragma unroll
  for (int off = 32; off; off >>= 1) sum += __shfl_down(sum, off);
  if ((tid & 63) == 0) red[tid >> 6] = sum;
  __syncthreads();
  const float mean = (red[0] + red[1] + red[2] + red[3]) * (1.0f / 768.0f);
  __syncthreads();
  float d0 = y0 - mean, d1 = y1 - mean, d2 = y2 - mean;
  float vs = d0*d0 + d1*d1 + d2*d2;
  #pragma unroll
  for (int off = 32; off; off >>= 1) vs += __shfl_down(vs, off);
  if ((tid & 63) == 0) red[tid >> 6] = vs;
  __syncthreads();
  const float rstd = rsqrtf((red[0]+red[1]+red[2]+red[3]) * (1.0f/768.0f) + 1e-5f);
  float o0 = d0 * rstd * g[tid]       + b[tid];
  float o1 = d1 * rstd * g[tid + 256] + b[tid + 256];
  float o2 = d2 * rstd * g[tid + 512] + b[tid + 512];
  x[pbase + tid] = o0; x[pbase + tid + 256] = o1; x[pbase + tid + 512] = o2;
  xb[pbase + tid] = f2b(o0); xb[pbase + tid + 256] = f2b(o1); xb[pbase + tid + 512] = f2b(o2);
}

// ================= LN of t (t already holds residual sum) -> x (f32) + xb (bf16) ======
__global__ __launch_bounds__(256) void ln_fused_kernel(
    const float* __restrict__ t, const float* __restrict__ g,
    const float* __restrict__ b, float* __restrict__ x, unsigned short* __restrict__ xb)
{
  const int s = blockIdx.x, tid = threadIdx.x;
  __shared__ float red[4];
  const size_t base = (size_t)s * DMODEL;
  float y0 = t[base + tid], y1 = t[base + tid + 256], y2 = t[base + tid + 512];
  float sum = y0 + y1 + y2;
  #pragma unroll
  for (int off = 32; off; off >>= 1) sum += __shfl_down(sum, off);
  if ((tid & 63) == 0) red[tid >> 6] = sum;
  __syncthreads();
  const float mean = (red[0] + red[1] + red[2] + red[3]) * (1.0f / 768.0f);
  __syncthreads();
  float d0 = y0 - mean, d1 = y1 - mean, d2 = y2 - mean;
  float vs = d0*d0 + d1*d1 + d2*d2;
  #pragma unroll
  for (int off = 32; off; off >>= 1) vs += __shfl_down(vs, off);
  if ((tid & 63) == 0) red[tid >> 6] = vs;
  __syncthreads();
  const float rstd = rsqrtf((red[0]+red[1]+red[2]+red[3]) * (1.0f/768.0f) + 1e-5f);
  float o0 = d0 * rstd * g[tid]       + b[tid];
  float o1 = d1 * rstd * g[tid + 256] + b[tid + 256];
  float o2 = d2 * rstd * g[tid + 512] + b[tid + 512];
  x[base + tid] = o0; x[base + tid + 256] = o1; x[base + tid + 512] = o2;
  xb[base + tid] = f2b(o0); xb[base + tid + 256] = f2b(o1); xb[base + tid + 512] = f2b(o2);
}

__global__ __launch_bounds__(256) void ln_vec_kernel(
    const float* __restrict__ in, const float* __restrict__ g,
    const float* __restrict__ b, float* __restrict__ out)
{
  const int tid = threadIdx.x;
  __shared__ float red[4];
  float y0 = in[tid], y1 = in[tid + 256], y2 = in[tid + 512];
  float sum = y0 + y1 + y2;
  #pragma unroll
  for (int off = 32; off; off >>= 1) sum += __shfl_down(sum, off);
  if ((tid & 63) == 0) red[tid >> 6] = sum;
  __syncthreads();
  const float mean = (red[0] + red[1] + red[2] + red[3]) * (1.0f / 768.0f);
  __syncthreads();
  float d0 = y0 - mean, d1 = y1 - mean, d2 = y2 - mean;
  float vs = d0*d0 + d1*d1 + d2*d2;
  #pragma unroll
  for (int off = 32; off; off >>= 1) vs += __shfl_down(vs, off);
  if ((tid & 63) == 0) red[tid >> 6] = vs;
  __syncthreads();
  const float rstd = rsqrtf((red[0]+red[1]+red[2]+red[3]) * (1.0f/768.0f) + 1e-5f);
  out[tid]       = d0 * rstd * g[tid]       + b[tid];
  out[tid + 256] = d1 * rstd * g[tid + 256] + b[tid + 256];
  out[tid + 512] = d2 * rstd * g[tid + 512] + b[tid + 512];
}

// ====== one-shot weight convert+transpose, 64x64 tiles (f32 [K][N] -> bf16 [N][K]) ====
__global__ __launch_bounds__(256) void conv_all_dd_kernel(
    const float* __restrict__ Wq, const float* __restrict__ Wk, const float* __restrict__ Wv,
    const float* __restrict__ Wkg, const float* __restrict__ Wvg, const float* __restrict__ Wo,
    const float* __restrict__ bq, const float* __restrict__ bk, const float* __restrict__ bv,
    const float* __restrict__ bkg, const float* __restrict__ bvg,
    unsigned short* __restrict__ WqkvT, unsigned short* __restrict__ WoT,
    float* __restrict__ bqkv)
{
  const int z = blockIdx.z, layer = z / 6, mat = z % 6;
  const size_t off = (size_t)layer * DD;
  const float* src = (mat==0?Wq: mat==1?Wk: mat==2?Wv: mat==3?Wkg: mat==4?Wvg: Wo) + off;
  unsigned short* dst = (mat < 5)
      ? (WqkvT + (size_t)layer * 5 * DD + (size_t)mat * DD)
      : (WoT + off);
  __shared__ float tbuf[64][65];
  const int n0 = blockIdx.x * 64, k0 = blockIdx.y * 64;
  const int t = threadIdx.x;
  #pragma unroll
  for (int i = 0; i < 4; ++i) {
    const int idx = i * 256 + t;
    const int r = idx >> 4, c4 = (idx & 15) * 4;
    const float4 v = *(const float4*)&src[(size_t)(k0 + r) * DMODEL + n0 + c4];
    tbuf[r][c4] = v.x; tbuf[r][c4+1] = v.y; tbuf[r][c4+2] = v.z; tbuf[r][c4+3] = v.w;
  }
  __syncthreads();
  const int n = t >> 2, seg = (t & 3) * 16;
  unsigned short o[16];
  #pragma unroll
  for (int i = 0; i < 16; ++i) o[i] = f2b(tbuf[seg + i][n]);
  unsigned short* dp = &dst[(size_t)(n0 + n) * DMODEL + k0 + seg];
  *(short8*)dp = *(const short8*)&o[0];
  *(short8*)(dp + 8) = *(const short8*)&o[8];
  if (mat < 5 && blockIdx.x == 0 && blockIdx.y == 0) {
    const float* bs = (mat==0?bq: mat==1?bk: mat==2?bv: mat==3?bkg: bvg) + (size_t)layer * DMODEL;
    for (int i = t; i < DMODEL; i += 256) bqkv[(size_t)layer * QKV_N + mat * DMODEL + i] = bs[i];
  }
}

__global__ __launch_bounds__(256) void conv_all_ffn_kernel(
    const float* __restrict__ Wf1, const float* __restrict__ Wf2,
    unsigned short* __restrict__ Wf1T, unsigned short* __restrict__ Wf2T)
{
  const int z = blockIdx.z, layer = z / 2, which = z % 2;
  __shared__ float tbuf[64][65];
  const float* src; unsigned short* dst; int Kd, Nd, n0, k0;
  if (which == 0) { src = Wf1 + (size_t)layer * DF; dst = Wf1T + (size_t)layer * DF;
                    Kd = DMODEL; Nd = FFDIM; n0 = blockIdx.x * 64; k0 = blockIdx.y * 64; }
  else            { src = Wf2 + (size_t)layer * DF; dst = Wf2T + (size_t)layer * DF;
                    Kd = FFDIM; Nd = DMODEL; n0 = blockIdx.y * 64; k0 = blockIdx.x * 64; }
  const int t = threadIdx.x;
  #pragma unroll
  for (int i = 0; i < 4; ++i) {
    const int idx = i * 256 + t;
    const int r = idx >> 4, c4 = (idx & 15) * 4;
    const float4 v = *(const float4*)&src[(size_t)(k0 + r) * Nd + n0 + c4];
    tbuf[r][c4] = v.x; tbuf[r][c4+1] = v.y; tbuf[r][c4+2] = v.z; tbuf[r][c4+3] = v.w;
  }
  __syncthreads();
  const int n = t >> 2, seg = (t & 3) * 16;
  unsigned short o[16];
  #pragma unroll
  for (int i = 0; i < 16; ++i) o[i] = f2b(tbuf[seg + i][n]);
  unsigned short* dp = &dst[(size_t)(n0 + n) * Kd + k0 + seg];
  *(short8*)dp = *(const short8*)&o[0];
  *(short8*)(dp + 8) = *(const short8*)&o[8];
}

// ======= bf16 MFMA GEMM (BMx128 tile, BK=64, swizzled LDS, XCD swizzle, residual) =====
template <int BM>
__global__ __launch_bounds__(256) void gemm_mfma_kernel(
    const unsigned short* __restrict__ A, const unsigned short* __restrict__ Bt,
    const float* __restrict__ bias, const float* __restrict__ Res,
    float* __restrict__ Cf, unsigned short* __restrict__ Cb, int N, int K, int act)
{
  constexpr int ASLOTS = BM * 8;
  constexpr int MI = BM / 32;
  __shared__ unsigned short As[ASLOTS * 8];
  __shared__ unsigned short Bs[8192];
  const int tid = threadIdx.x, wave = tid >> 6, lane = tid & 63;
  const int gx = gridDim.x, nwg = gx * gridDim.y;
  int flat = blockIdx.y * gx + blockIdx.x;
  flat = (flat & 7) * (nwg >> 3) + (flat >> 3);
  const int bm = (flat % gx) * BM, bn = (flat / gx) * 128;
  const int wr = (wave >> 1) * (BM / 2), wc = (wave & 1) * 64;
  f32x4 acc[MI][4];
  const f32x4 zz = {0.f, 0.f, 0.f, 0.f};
  #pragma unroll
  for (int i = 0; i < MI; ++i)
    #pragma unroll
    for (int j = 0; j < 4; ++j) acc[i][j] = zz;

  for (int k0 = 0; k0 < K; k0 += 64) {
    #pragma unroll
    for (int it = 0; it < ASLOTS / 256; ++it) {
      const int s = it * 256 + tid;
      const int mr = s >> 3;
      const int kg = (s & 7) ^ (mr & 7);
      const unsigned short* src = A + (size_t)(bm + mr) * K + k0 + kg * 8;
      __builtin_amdgcn_global_load_lds(
          (const __attribute__((address_space(1))) void*)src,
          (__attribute__((address_space(3))) void*)&As[(size_t)(it * 256 + wave * 64) * 8], 16, 0, 0);
    }
    #pragma unroll
    for (int it = 0; it < 4; ++it) {
      const int s = it * 256 + tid;
      const int mr = s >> 3;
      const int kg = (s & 7) ^ (mr & 7);
      const unsigned short* src = Bt + (size_t)(bn + mr) * K + k0 + kg * 8;
      __builtin_amdgcn_global_load_lds(
          (const __attribute__((address_space(1))) void*)src,
          (__attribute__((address_space(3))) void*)&Bs[(size_t)(it * 256 + wave * 64) * 8], 16, 0, 0);
    }
    __syncthreads();
    #pragma unroll
    for (int ks = 0; ks < 2; ++ks) {
      const int kg = ks * 4 + (lane >> 4);
      short8 af[MI], bfr[4];
      #pragma unroll
      for (int i = 0; i < MI; ++i) {
        const int m = wr + i * 16 + (lane & 15);
        af[i] = *(const short8*)&As[(m * 8 + (kg ^ (m & 7))) * 8];
      }
      #pragma unroll
      for (int j = 0; j < 4; ++j) {
        const int n = wc + j * 16 + (lane & 15);
        bfr[j] = *(const short8*)&Bs[(n * 8 + (kg ^ (n & 7))) * 8];
      }
      #pragma unroll
      for (int i = 0; i < MI; ++i)
        #pragma unroll
        for (int j = 0; j < 4; ++j)
          acc[i][j] = __builtin_amdgcn_mfma_f32_16x16x32_bf16(af[i], bfr[j], acc[i][j], 0, 0, 0);
    }
    __syncthreads();
  }

  const int lr = (lane >> 4) * 4, lc = lane & 15;
  #pragma unroll
  for (int i = 0; i < MI; ++i) {
    #pragma unroll
    for (int j = 0; j < 4; ++j) {
      const int n = bn + wc + j * 16 + lc;
      const float bv = bias[n];
      #pragma unroll
      for (int p = 0; p < 4; ++p) {
        const int m = bm + wr + i * 16 + lr + p;
        float val = acc[i][j][p] + bv;
        if (Res) val += Res[(size_t)m * N + n];
        if (act) val = gelu_f(val);
        if (Cf) Cf[(size_t)m * N + n] = val;
        if (Cb) Cb[(size_t)m * N + n] = f2b(val);
      }
    }
  }
}

// ============ fused attention: banded flash (y<16) + global CLS row (y==16) ==========
__global__ __launch_bounds__(256) void attn_fused_kernel(
    const unsigned short* __restrict__ qkvb, const float* __restrict__ xf,
    const float* __restrict__ Wqg, const float* __restrict__ bqg,
    const int* __restrict__ am, unsigned short* __restrict__ outb)
{
  __shared__ __align__(16) unsigned char smem[67072];
  const int h = blockIdx.x, tid = threadIdx.x;

  if (blockIdx.y == NCHUNK) {
    // ---------------- global CLS query row ----------------
    float* sc  = (float*)smem;            // 2048 f32 (8 KB)
    float* qs  = (float*)(smem + 8192);   // 64
    float* red = (float*)(smem + 8448);   // 4
    float* pqg = (float*)(smem + 8464);   // 4*64 (1 KB)
    float* pb  = (float*)(smem + 9488);   // 32*64 f32 (8 KB)
    const int d = tid & 63, grp = tid >> 6;
    // qg0 slice for this head: x[0] @ Wqg[:, h*64+d]  (4-way k-split)
    {
      float p = 0.f;
      const float* wcol = Wqg + (size_t)(grp * 192) * DMODEL + h * DHEAD + d;
      #pragma unroll 4
      for (int k = 0; k < 192; ++k)
        p = fmaf(xf[grp * 192 + k], wcol[(size_t)k * DMODEL], p);
      pqg[grp * 64 + d] = p;
    }
    __syncthreads();
    if (tid < 64)
      qs[tid] = (pqg[tid] + pqg[64 + tid] + pqg[128 + tid] + pqg[192 + tid]
                 + bqg[h * DHEAD + tid]) * 0.125f;
    __syncthreads();
    const unsigned short* kg = qkvb + 3 * DMODEL + h * DHEAD;
    const unsigned short* vg = qkvb + 4 * DMODEL + h * DHEAD;
    for (int s0 = tid; s0 < S_LEN; s0 += 256) {
      const unsigned short* kr = kg + (size_t)s0 * QKV_N;
      float dd = 0.f;
      #pragma unroll
      for (int d0 = 0; d0 < DHEAD; d0 += 8) {
        const short8 k8 = *(const short8*)(kr + d0);
        #pragma unroll
        for (int e = 0; e < 8; ++e) dd += qs[d0 + e] * b2f((unsigned short)k8[e]);
      }
      sc[s0] = (am[s0] > 0) ? dd : -1e9f;
    }
    __syncthreads();
    float mx = -1e30f;
    for (int s0 = tid; s0 < S_LEN; s0 += 256) mx = fmaxf(mx, sc[s0]);
    #pragma unroll
    for (int off = 32; off; off >>= 1) mx = fmaxf(mx, __shfl_down(mx, off));
    if ((tid & 63) == 0) red[tid >> 6] = mx;
    __syncthreads();
    mx = fmaxf(fmaxf(red[0], red[1]), fmaxf(red[2], red[3]));
    __syncthreads();
    float sum = 0.f;
    for (int s0 = tid; s0 < S_LEN; s0 += 256) {
      const float e = __expf(sc[s0] - mx);
      sc[s0] = e;
      sum += e;
    }
    #pragma unroll
    for (int off = 32; off; off >>= 1) sum += __shfl_down(sum, off);
    if ((tid & 63) == 0) red[tid >> 6] = sum;
    __syncthreads();
    const float total = red[0] + red[1] + red[2] + red[3];
    // ---- PV: 32-way key split x 8 dims per thread, short8 loads, LDS reduce ----
    const int d8 = (tid & 7) * 8, kgrp = tid >> 3;
    float a8[8] = {};
    for (int s0 = kgrp; s0 < S_LEN; s0 += 32) {
      const float p = sc[s0];
      const short8 v8 = *(const short8*)(vg + (size_t)s0 * QKV_N + d8);
      #pragma unroll
      for (int e = 0; e < 8; ++e) a8[e] = fmaf(p, b2f((unsigned short)v8[e]), a8[e]);
    }
    #pragma unroll
    for (int e = 0; e < 8; ++e) pb[kgrp * 64 + d8 + e] = a8[e];
    __syncthreads();
    if (tid < 64) {
      float o = 0.f;
      #pragma unroll
      for (int k = 0; k < 32; ++k) o += pb[k * 64 + tid];
      outb[h * DHEAD + tid] = f2b(o / total);
    }
    return;
  }

  // ---------------- banded sliding-window flash ----------------
  const int nc = blockIdx.y;
  const int wave = tid >> 6, lane = tid & 63;
  const int c = lane & 15, g = lane >> 4;
  unsigned short* Ks = (unsigned short*)smem;             // 16 KB
  unsigned short* Vt = (unsigned short*)(smem + 16384);   // 16 KB
  unsigned short* Ps = (unsigned short*)(smem + 32768);   // 32 KB
  float* smcls = (float*)(smem + 65536);                  // 512 B
  float* sv0   = (float*)(smem + 66048);                  // 256 B
  int*   sam   = (int*)(smem + 66304);                    // 512 B

  if (tid < 64) sv0[tid] = b2f(qkvb[2 * DMODEL + h * DHEAD + tid]);
  if (tid < 128) {
    const int qrow = nc * CHUNK + tid;
    const unsigned short* qp = qkvb + (size_t)qrow * QKV_N + h * DHEAD;
    const unsigned short* k0 = qkvb + DMODEL + h * DHEAD;
    float d = 0.f;
    #pragma unroll
    for (int dd = 0; dd < 64; dd += 8) {
      const short8 a8 = *(const short8*)(qp + dd);
      const short8 b8 = *(const short8*)(k0 + dd);
      #pragma unroll
      for (int e = 0; e < 8; ++e)
        d += b2f((unsigned short)a8[e]) * b2f((unsigned short)b8[e]);
    }
    smcls[tid] = (am[0] > 0) ? d * 0.125f : -1e9f;
  }

  short8 af[2][2];
  #pragma unroll
  for (int i = 0; i < 2; ++i)
    #pragma unroll
    for (int ks = 0; ks < 2; ++ks) {
      const int qrow = nc * CHUNK + wave * 32 + i * 16 + c;
      af[i][ks] = *(const short8*)(qkvb + (size_t)qrow * QKV_N + h * DHEAD + (ks * 4 + g) * 8);
    }

  __syncthreads();

  float mrow[2][4], lrow[2][4];
  f32x4 acc_o[2][4];
  #pragma unroll
  for (int i = 0; i < 2; ++i)
    #pragma unroll
    for (int p = 0; p < 4; ++p) {
      mrow[i][p] = smcls[wave * 32 + i * 16 + g * 4 + p];
      lrow[i][p] = 1.f;
    }
  #pragma unroll
  for (int i = 0; i < 2; ++i)
    #pragma unroll
    for (int j = 0; j < 4; ++j) {
      const float v0 = sv0[j * 16 + c];
      acc_o[i][j][0] = v0; acc_o[i][j][1] = v0; acc_o[i][j][2] = v0; acc_o[i][j][3] = v0;
    }

  for (int kci = 0; kci < 3; ++kci) {
    const int ck = nc - 1 + kci;
    if (ck < 0 || ck > 15) continue;
    __syncthreads();

    #pragma unroll
    for (int it = 0; it < 4; ++it) {
      const int sidx = it * 256 + tid;
      const int mr = sidx >> 3;
      const int kg = (sidx & 7) ^ (mr & 7);
      const unsigned short* src = qkvb + (size_t)(ck * CHUNK + mr) * QKV_N + DMODEL + h * DHEAD + kg * 8;
      __builtin_amdgcn_global_load_lds(
          (const __attribute__((address_space(1))) void*)src,
          (__attribute__((address_space(3))) void*)&Ks[(size_t)(it * 256 + wave * 64) * 8], 16, 0, 0);
    }
    {
      const int kp = tid & 63, dh = tid >> 6;
      const unsigned short* v0p = qkvb + (size_t)(ck * CHUNK + 2 * kp) * QKV_N + 2 * DMODEL + h * DHEAD + dh * 16;
      const short8 a0 = *(const short8*)(v0p);
      const short8 a1 = *(const short8*)(v0p + 8);
      const short8 b0 = *(const short8*)(v0p + QKV_N);
      const short8 b1 = *(const short8*)(v0p + QKV_N + 8);
      #pragma unroll
      for (int dd = 0; dd < 16; ++dd) {
        const int dim = dh * 16 + dd;
        const unsigned short lo = (unsigned short)(dd < 8 ? a0[dd] : a1[dd - 8]);
        const unsigned short hi = (unsigned short)(dd < 8 ? b0[dd] : b1[dd - 8]);
        const unsigned int w = (unsigned int)lo | ((unsigned int)hi << 16);
        const int si = dim * 128 + (((kp >> 2) ^ (dim & 7)) << 3) + ((kp & 3) << 1);
        *(unsigned int*)&Vt[si] = w;
      }
    }
    if (tid < 128) sam[tid] = am[ck * CHUNK + tid];
    __syncthreads();

    f32x4 accs[2][8];
    const f32x4 zz = {0.f, 0.f, 0.f, 0.f};
    #pragma unroll
    for (int i = 0; i < 2; ++i)
      #pragma unroll
      for (int j = 0; j < 8; ++j) accs[i][j] = zz;
    #pragma unroll
    for (int ks = 0; ks < 2; ++ks) {
      const int kg = ks * 4 + g;
      short8 bfr[8];
      #pragma unroll
      for (int j = 0; j < 8; ++j) {
        const int jj = j * 16 + c;
        bfr[j] = *(const short8*)&Ks[(jj * 8 + (kg ^ (jj & 7))) * 8];
      }
      #pragma unroll
      for (int i = 0; i < 2; ++i)
        #pragma unroll
        for (int j = 0; j < 8; ++j)
          accs[i][j] = __builtin_amdgcn_mfma_f32_16x16x32_bf16(af[i][ks], bfr[j], accs[i][j], 0, 0, 0);
    }

    #pragma unroll
    for (int i = 0; i < 2; ++i) {
      #pragma unroll
      for (int p = 0; p < 4; ++p) {
        const int mloc = wave * 32 + i * 16 + g * 4 + p;
        const int qi = nc * CHUNK + mloc;
        float sv[8];
        float rmax = -1e30f;
        #pragma unroll
        for (int j = 0; j < 8; ++j) {
          const int jj = j * 16 + c;
          const int kj = ck * CHUNK + jj;
          const int diff = qi - kj;
          const bool ok = (diff <= 128) && (diff >= -128) && (kj != 0) && (sam[jj] > 0);
          const float s = ok ? accs[i][j][p] * 0.125f : -1e9f;
          sv[j] = s;
          rmax = fmaxf(rmax, s);
        }
        rmax = fmaxf(rmax, __shfl_xor(rmax, 1));
        rmax = fmaxf(rmax, __shfl_xor(rmax, 2));
        rmax = fmaxf(rmax, __shfl_xor(rmax, 4));
        rmax = fmaxf(rmax, __shfl_xor(rmax, 8));
        const float mnew = fmaxf(mrow[i][p], rmax);
        const float corr = __expf(mrow[i][p] - mnew);
        float psum = 0.f;
        #pragma unroll
        for (int j = 0; j < 8; ++j) {
          const float pv = __expf(sv[j] - mnew);
          sv[j] = pv;
          psum += pv;
        }
        psum += __shfl_xor(psum, 1);
        psum += __shfl_xor(psum, 2);
        psum += __shfl_xor(psum, 4);
        psum += __shfl_xor(psum, 8);
        lrow[i][p] = lrow[i][p] * corr + psum;
        mrow[i][p] = mnew;
        #pragma unroll
        for (int j = 0; j < 4; ++j) acc_o[i][j][p] *= corr;
        #pragma unroll
        for (int j = 0; j < 8; ++j) {
          const int key = j * 16 + c;
          const int kslot = key >> 3;
          Ps[mloc * 128 + ((kslot ^ (mloc & 7)) << 3) + (key & 7)] = f2b(sv[j]);
        }
      }
    }
    asm volatile("s_waitcnt lgkmcnt(0)" ::: "memory");

    #pragma unroll
    for (int ks2 = 0; ks2 < 4; ++ks2) {
      const int kg2 = ks2 * 4 + g;
      short8 pa[2], vb[4];
      #pragma unroll
      for (int i = 0; i < 2; ++i) {
        const int row = wave * 32 + i * 16 + c;
        pa[i] = *(const short8*)&Ps[row * 128 + ((kg2 ^ (row & 7)) << 3)];
      }
      #pragma unroll
      for (int j = 0; j < 4; ++j) {
        const int n = j * 16 + c;
        vb[j] = *(const short8*)&Vt[n * 128 + ((kg2 ^ (n & 7)) << 3)];
      }
      #pragma unroll
      for (int i = 0; i < 2; ++i)
        #pragma unroll
        for (int j = 0; j < 4; ++j)
          acc_o[i][j] = __builtin_amdgcn_mfma_f32_16x16x32_bf16(pa[i], vb[j], acc_o[i][j], 0, 0, 0);
    }
  }

  #pragma unroll
  for (int i = 0; i < 2; ++i) {
    #pragma unroll
    for (int p = 0; p < 4; ++p) {
      const float rl = (lrow[i][p] > 0.f) ? 1.f / lrow[i][p] : 0.f;
      const int row = nc * CHUNK + wave * 32 + i * 16 + g * 4 + p;
      if (row == 0) continue;  // row 0 owned by the global branch
      #pragma unroll
      for (int j = 0; j < 4; ++j)
        outb[(size_t)row * DMODEL + h * DHEAD + j * 16 + c] = f2b(acc_o[i][j][p] * rl);
    }
  }
}

// ================= split-k GEMV (head MLP only) =================
__global__ __launch_bounds__(256) void gemv_partial_kernel(
    const float* __restrict__ xrow, const float* __restrict__ W, float* __restrict__ part)
{
  const int b = blockIdx.x, t = threadIdx.x;
  float s0 = 0.f, s1 = 0.f, s2 = 0.f;
  for (int kk = 0; kk < 48; ++kk) {
    const int k = b * 48 + kk;
    const float xv = xrow[k];
    const float* wr = W + (size_t)k * DMODEL;
    s0 = fmaf(xv, wr[t], s0);
    s1 = fmaf(xv, wr[t + 256], s1);
    s2 = fmaf(xv, wr[t + 512], s2);
  }
  part[b * DMODEL + t] = s0;
  part[b * DMODEL + t + 256] = s1;
  part[b * DMODEL + t + 512] = s2;
}

__global__ __launch_bounds__(256) void gemv_reduce_kernel(
    const float* __restrict__ part, const float* __restrict__ bias,
    float* __restrict__ y, int act)
{
  const int n = blockIdx.x * 256 + threadIdx.x;
  float s = bias[n];
  #pragma unroll
  for (int b = 0; b < 16; ++b) s += part[b * DMODEL + n];
  if (act) s = gelu_f(s);
  y[n] = s;
}

// ================= final head =================
__global__ __launch_bounds__(256) void head_final_kernel(
    const float* __restrict__ h2, const float* __restrict__ Wout,
    const float* __restrict__ bout, float* __restrict__ out)
{
  const int tid = threadIdx.x;
  __shared__ float red[4];
  float p = h2[tid]*Wout[tid] + h2[tid+256]*Wout[tid+256] + h2[tid+512]*Wout[tid+512];
  #pragma unroll
  for (int off = 32; off; off >>= 1) p += __shfl_down(p, off);
  if ((tid & 63) == 0) red[tid >> 6] = p;
  __syncthreads();
  if (tid == 0) {
    const float logit = red[0] + red[1] + red[2] + red[3] + bout[0];
    const float sig = 1.0f / (1.0f + expf(-logit));
    const unsigned int bits = __float_as_uint(sig);
    const unsigned int bf = (bits + 0x7FFFu + ((bits >> 16) & 1u)) >> 16;
    out[0] = __uint_as_float((bits & 0xFFFF0000u) | (bf & 0xFFFFu));
  }
}

extern "C" void kernel_launch(void* const* d_in, const int* in_sizes, int n_in,
                              void* d_out, int out_size, void* d_ws, size_t ws_size,
                              hipStream_t stream)
{
  const int*   ids  = (const int*)d_in[0];
  const int*   am   = (const int*)d_in[1];
  const float* wemb = (const float*)d_in[2];
  const float* pemb = (const float*)d_in[3];
  const float* emb_g = (const float*)d_in[4];
  const float* emb_b = (const float*)d_in[5];
  const float* Wq  = (const float*)d_in[6];
  const float* bq  = (const float*)d_in[7];
  const float* Wk  = (const float*)d_in[8];
  const float* bk  = (const float*)d_in[9];
  const float* Wv  = (const float*)d_in[10];
  const float* bv  = (const float*)d_in[11];
  const float* Wqg = (const float*)d_in[12];
  const float* bqg = (const float*)d_in[13];
  const float* Wkg = (const float*)d_in[14];
  const float* bkg = (const float*)d_in[15];
  const float* Wvg = (const float*)d_in[16];
  const float* bvg = (const float*)d_in[17];
  const float* Wo  = (const float*)d_in[18];
  const float* bo  = (const float*)d_in[19];
  const float* ln1g = (const float*)d_in[20];
  const float* ln1b = (const float*)d_in[21];
  const float* Wf1 = (const float*)d_in[22];
  const float* bf1 = (const float*)d_in[23];
  const float* Wf2 = (const float*)d_in[24];
  const float* bf2 = (const float*)d_in[25];
  const float* ln2g = (const float*)d_in[26];
  const float* ln2b = (const float*)d_in[27];
  const float* hng = (const float*)d_in[28];
  const float* hnb = (const float*)d_in[29];
  const float* W1  = (const float*)d_in[30];
  const float* b1  = (const float*)d_in[31];
  const float* W2  = (const float*)d_in[32];
  const float* b2  = (const float*)d_in[33];
  const float* Wout = (const float*)d_in[34];
  const float* bout = (const float*)d_in[35];

  char* wp = (char*)d_ws;
  auto alloc = [&](size_t bytes) -> void* {
    void* r = (void*)wp;
    wp += (bytes + 255) & ~(size_t)255;
    return r;
  };
  float*          x         = (float*)alloc((size_t)S_LEN * DMODEL * 4);
  unsigned short* xb        = (unsigned short*)alloc((size_t)S_LEN * DMODEL * 2);
  unsigned short* qkvb      = (unsigned short*)alloc((size_t)S_LEN * QKV_N * 2);
  unsigned short* attnb     = (unsigned short*)alloc((size_t)S_LEN * DMODEL * 2);
  unsigned short* tmpb      = (unsigned short*)alloc((size_t)S_LEN * FFDIM * 2);
  float*          tmpf      = (float*)alloc((size_t)S_LEN * DMODEL * 4);
  unsigned short* WqkvT_all = (unsigned short*)alloc((size_t)NLAYER * 5 * DD * 2);
  unsigned short* WoT_all   = (unsigned short*)alloc((size_t)NLAYER * DD * 2);
  unsigned short* Wf1T_all  = (unsigned short*)alloc((size_t)NLAYER * DF * 2);
  unsigned short* Wf2T_all  = (unsigned short*)alloc((size_t)NLAYER * DF * 2);
  float*          bqkv_all  = (float*)alloc((size_t)NLAYER * QKV_N * 4);
  float*          gpart     = (float*)alloc((size_t)16 * DMODEL * 4);
  float*          hb        = (float*)alloc((size_t)3 * DMODEL * 4);

  // one-shot weight conversion for all layers (BW-bound, 2 launches)
  conv_all_dd_kernel<<<dim3(12, 12, 6 * NLAYER), 256, 0, stream>>>(
      Wq, Wk, Wv, Wkg, Wvg, Wo, bq, bk, bv, bkg, bvg, WqkvT_all, WoT_all, bqkv_all);
  conv_all_ffn_kernel<<<dim3(48, 12, 2 * NLAYER), 256, 0, stream>>>(
      Wf1, Wf2, Wf1T_all, Wf2T_all);

  embed_ln_kernel<<<S_LEN, 256, 0, stream>>>(ids, wemb, pemb, emb_g, emb_b, x, xb);

  for (int l = 0; l < NLAYER; ++l) {
    const size_t wdd = (size_t)l * DD;
    const size_t vd  = (size_t)l * DMODEL;
    const size_t vf  = (size_t)l * FFDIM;
    const unsigned short* WqkvT = WqkvT_all + (size_t)l * 5 * DD;
    const unsigned short* WoT   = WoT_all + wdd;
    const unsigned short* Wf1T  = Wf1T_all + (size_t)l * DF;
    const unsigned short* Wf2T  = Wf2T_all + (size_t)l * DF;
    const float* bqkv = bqkv_all + (size_t)l * QKV_N;

    // fused q|k|v|kg|vg projection: [2048,768] @ [768,3840] -> bf16
    gemm_mfma_kernel<128><<<dim3(16, 30), 256, 0, stream>>>(
        xb, WqkvT, bqkv, (const float*)nullptr, (float*)nullptr, qkvb, QKV_N, DMODEL, 0);

    // banded flash + global CLS row (incl. qg0) in one launch
    attn_fused_kernel<<<dim3(NHEAD, NCHUNK + 1), 256, 0, stream>>>(
        qkvb, x, Wqg + wdd, bqg + vd, am, attnb);

    // Wo projection + residual add fused
    gemm_mfma_kernel<64><<<dim3(32, 6), 256, 0, stream>>>(
        attnb, WoT, bo + vd, x, tmpf, (unsigned short*)nullptr, DMODEL, DMODEL, 0);
    ln_fused_kernel<<<S_LEN, 256, 0, stream>>>(tmpf, ln1g + vd, ln1b + vd, x, xb);

    gemm_mfma_kernel<128><<<dim3(16, 24), 256, 0, stream>>>(
        xb, Wf1T, bf1 + vf, (const float*)nullptr, (float*)nullptr, tmpb, FFDIM, DMODEL, 1);
    gemm_mfma_kernel<64><<<dim3(32, 6), 256, 0, stream>>>(
        tmpb, Wf2T, bf2 + vd, x, tmpf, (unsigned short*)nullptr, DMODEL, FFDIM, 0);
    ln_fused_kernel<<<S_LEN, 256, 0, stream>>>(tmpf, ln2g + vd, ln2b + vd, x, xb);
  }

  ln_vec_kernel<<<1, 256, 0, stream>>>(x, hng, hnb, hb);
  gemv_partial_kernel<<<16, 256, 0, stream>>>(hb, W1, gpart);
  gemv_reduce_kernel<<<3, 256, 0, stream>>>(gpart, b1, hb + DMODEL, 1);
  gemv_partial_kernel<<<16, 256, 0, stream>>>(hb + DMODEL, W2, gpart);
  gemv_reduce_kernel<<<3, 256, 0, stream>>>(gpart, b2, hb + 2 * DMODEL, 1);
  head_final_kernel<<<1, 256, 0, stream>>>(hb + 2 * DMODEL, Wout, bout, (float*)d_out);
}

// Round 7
// 2512.192 us; speedup vs baseline: 1.6175x; 1.0745x over previous
//
#include <hip/hip_runtime.h>
#include <math.h>

#define S_LEN 2048
#define DMODEL 768
#define NHEAD 12
#define DHEAD 64
#define NLAYER 12
#define FFDIM 3072
#define CHUNK 128
#define NCHUNK 16
#define QKV_N 3840   // q|k|v|kg|vg concatenated
#define DD (DMODEL * DMODEL)
#define DF (DMODEL * FFDIM)

typedef __attribute__((ext_vector_type(8))) short short8;
typedef __attribute__((ext_vector_type(4))) float f32x4;

__device__ __forceinline__ float gelu_f(float x) {
  return 0.5f * x * (1.0f + erff(x * 0.7071067811865476f));
}
// float -> bf16 bits (RNE)
__device__ __forceinline__ unsigned short f2b(float f) {
  unsigned int u = __float_as_uint(f);
  return (unsigned short)((u + 0x7FFFu + ((u >> 16) & 1u)) >> 16);
}
__device__ __forceinline__ float b2f(unsigned short u) {
  return __uint_as_float((unsigned int)u << 16);
}

// ================= embedding + LN =================
__global__ __launch_bounds__(256) void embed_ln_kernel(
    const int* __restrict__ ids, const float* __restrict__ wemb,
    const float* __restrict__ pemb, const float* __restrict__ g,
    const float* __restrict__ b, float* __restrict__ x, unsigned short* __restrict__ xb)
{
  const int s = blockIdx.x, tid = threadIdx.x;
  __shared__ float red[4];
  const size_t wbase = (size_t)ids[s] * DMODEL;
  const size_t pbase = (size_t)s * DMODEL;
  float y0 = wemb[wbase + tid]       + pemb[pbase + tid];
  float y1 = wemb[wbase + tid + 256] + pemb[pbase + tid + 256];
  float y2 = wemb[wbase + tid + 512] + pemb[pbase + tid + 512];
  float sum = y0 + y1 + y2;
  #pragma unroll
  for (int off = 32; off; off >>= 1) sum += __shfl_down(sum, off);
  if ((tid & 63) == 0) red[tid >> 6] = sum;
  __syncthreads();
  const float mean = (red[0] + red[1] + red[2] + red[3]) * (1.0f / 768.0f);
  __syncthreads();
  float d0 = y0 - mean, d1 = y1 - mean, d2 = y2 - mean;
  float vs = d0*d0 + d1*d1 + d2*d2;
  #pragma unroll
  for (int off = 32; off; off >>= 1) vs += __shfl_down(vs, off);
  if ((tid & 63) == 0) red[tid >> 6] = vs;
  __syncthreads();
  const float rstd = rsqrtf((red[0]+red[1]+red[2]+red[3]) * (1.0f/768.0f) + 1e-5f);
  float o0 = d0 * rstd * g[tid]       + b[tid];
  float o1 = d1 * rstd * g[tid + 256] + b[tid + 256];
  float o2 = d2 * rstd * g[tid + 512] + b[tid + 512];
  x[pbase + tid] = o0; x[pbase + tid + 256] = o1; x[pbase + tid + 512] = o2;
  xb[pbase + tid] = f2b(o0); xb[pbase + tid + 256] = f2b(o1); xb[pbase + tid + 512] = f2b(o2);
}

// ================= LN of t (t already holds residual sum) -> x (f32) + xb (bf16) ======
__global__ __launch_bounds__(256) void ln_fused_kernel(
    const float* __restrict__ t, const float* __restrict__ g,
    const float* __restrict__ b, float* __restrict__ x, unsigned short* __restrict__ xb)
{
  const int s = blockIdx.x, tid = threadIdx.x;
  __shared__ float red[4];
  const size_t base = (size_t)s * DMODEL;
  float y0 = t[base + tid], y1 = t[base + tid + 256], y2 = t[base + tid + 512];
  float sum = y0 + y1 + y2;
  #pragma unroll
  for (int off = 32; off; off >>= 1) sum += __shfl_down(sum, off);
  if ((tid & 63) == 0) red[tid >> 6] = sum;
  __syncthreads();
  const float mean = (red[0] + red[1] + red[2] + red[3]) * (1.0f / 768.0f);
  __syncthreads();
  float d0 = y0 - mean, d1 = y1 - mean, d2 = y2 - mean;
  float vs = d0*d0 + d1*d1 + d2*d2;
  #pragma unroll
  for (int off = 32; off; off >>= 1) vs += __shfl_down(vs, off);
  if ((tid & 63) == 0) red[tid >> 6] = vs;
  __syncthreads();
  const float rstd = rsqrtf((red[0]+red[1]+red[2]+red[3]) * (1.0f/768.0f) + 1e-5f);
  float o0 = d0 * rstd * g[tid]       + b[tid];
  float o1 = d1 * rstd * g[tid + 256] + b[tid + 256];
  float o2 = d2 * rstd * g[tid + 512] + b[tid + 512];
  x[base + tid] = o0; x[base + tid + 256] = o1; x[base + tid + 512] = o2;
  xb[base + tid] = f2b(o0); xb[base + tid + 256] = f2b(o1); xb[base + tid + 512] = f2b(o2);
}

__global__ __launch_bounds__(256) void ln_vec_kernel(
    const float* __restrict__ in, const float* __restrict__ g,
    const float* __restrict__ b, float* __restrict__ out)
{
  const int tid = threadIdx.x;
  __shared__ float red[4];
  float y0 = in[tid], y1 = in[tid + 256], y2 = in[tid + 512];
  float sum = y0 + y1 + y2;
  #pragma unroll
  for (int off = 32; off; off >>= 1) sum += __shfl_down(sum, off);
  if ((tid & 63) == 0) red[tid >> 6] = sum;
  __syncthreads();
  const float mean = (red[0] + red[1] + red[2] + red[3]) * (1.0f / 768.0f);
  __syncthreads();
  float d0 = y0 - mean, d1 = y1 - mean, d2 = y2 - mean;
  float vs = d0*d0 + d1*d1 + d2*d2;
  #pragma unroll
  for (int off = 32; off; off >>= 1) vs += __shfl_down(vs, off);
  if ((tid & 63) == 0) red[tid >> 6] = vs;
  __syncthreads();
  const float rstd = rsqrtf((red[0]+red[1]+red[2]+red[3]) * (1.0f/768.0f) + 1e-5f);
  out[tid]       = d0 * rstd * g[tid]       + b[tid];
  out[tid + 256] = d1 * rstd * g[tid + 256] + b[tid + 256];
  out[tid + 512] = d2 * rstd * g[tid + 512] + b[tid + 512];
}

// ====== one-shot weight convert+transpose, 64x64 tiles (f32 [K][N] -> bf16 [N][K]) ====
__global__ __launch_bounds__(256) void conv_all_dd_kernel(
    const float* __restrict__ Wq, const float* __restrict__ Wk, const float* __restrict__ Wv,
    const float* __restrict__ Wkg, const float* __restrict__ Wvg, const float* __restrict__ Wo,
    const float* __restrict__ bq, const float* __restrict__ bk, const float* __restrict__ bv,
    const float* __restrict__ bkg, const float* __restrict__ bvg,
    unsigned short* __restrict__ WqkvT, unsigned short* __restrict__ WoT,
    float* __restrict__ bqkv)
{
  const int z = blockIdx.z, layer = z / 6, mat = z % 6;
  const size_t off = (size_t)layer * DD;
  const float* src = (mat==0?Wq: mat==1?Wk: mat==2?Wv: mat==3?Wkg: mat==4?Wvg: Wo) + off;
  unsigned short* dst = (mat < 5)
      ? (WqkvT + (size_t)layer * 5 * DD + (size_t)mat * DD)
      : (WoT + off);
  __shared__ float tbuf[64][65];
  const int n0 = blockIdx.x * 64, k0 = blockIdx.y * 64;
  const int t = threadIdx.x;
  #pragma unroll
  for (int i = 0; i < 4; ++i) {
    const int idx = i * 256 + t;
    const int r = idx >> 4, c4 = (idx & 15) * 4;
    const float4 v = *(const float4*)&src[(size_t)(k0 + r) * DMODEL + n0 + c4];
    tbuf[r][c4] = v.x; tbuf[r][c4+1] = v.y; tbuf[r][c4+2] = v.z; tbuf[r][c4+3] = v.w;
  }
  __syncthreads();
  const int n = t >> 2, seg = (t & 3) * 16;
  unsigned short o[16];
  #pragma unroll
  for (int i = 0; i < 16; ++i) o[i] = f2b(tbuf[seg + i][n]);
  unsigned short* dp = &dst[(size_t)(n0 + n) * DMODEL + k0 + seg];
  *(short8*)dp = *(const short8*)&o[0];
  *(short8*)(dp + 8) = *(const short8*)&o[8];
  if (mat < 5 && blockIdx.x == 0 && blockIdx.y == 0) {
    const float* bs = (mat==0?bq: mat==1?bk: mat==2?bv: mat==3?bkg: bvg) + (size_t)layer * DMODEL;
    for (int i = t; i < DMODEL; i += 256) bqkv[(size_t)layer * QKV_N + mat * DMODEL + i] = bs[i];
  }
}

__global__ __launch_bounds__(256) void conv_all_ffn_kernel(
    const float* __restrict__ Wf1, const float* __restrict__ Wf2,
    unsigned short* __restrict__ Wf1T, unsigned short* __restrict__ Wf2T)
{
  const int z = blockIdx.z, layer = z / 2, which = z % 2;
  __shared__ float tbuf[64][65];
  const float* src; unsigned short* dst; int Kd, Nd, n0, k0;
  if (which == 0) { src = Wf1 + (size_t)layer * DF; dst = Wf1T + (size_t)layer * DF;
                    Kd = DMODEL; Nd = FFDIM; n0 = blockIdx.x * 64; k0 = blockIdx.y * 64; }
  else            { src = Wf2 + (size_t)layer * DF; dst = Wf2T + (size_t)layer * DF;
                    Kd = FFDIM; Nd = DMODEL; n0 = blockIdx.y * 64; k0 = blockIdx.x * 64; }
  const int t = threadIdx.x;
  #pragma unroll
  for (int i = 0; i < 4; ++i) {
    const int idx = i * 256 + t;
    const int r = idx >> 4, c4 = (idx & 15) * 4;
    const float4 v = *(const float4*)&src[(size_t)(k0 + r) * Nd + n0 + c4];
    tbuf[r][c4] = v.x; tbuf[r][c4+1] = v.y; tbuf[r][c4+2] = v.z; tbuf[r][c4+3] = v.w;
  }
  __syncthreads();
  const int n = t >> 2, seg = (t & 3) * 16;
  unsigned short o[16];
  #pragma unroll
  for (int i = 0; i < 16; ++i) o[i] = f2b(tbuf[seg + i][n]);
  unsigned short* dp = &dst[(size_t)(n0 + n) * Kd + k0 + seg];
  *(short8*)dp = *(const short8*)&o[0];
  *(short8*)(dp + 8) = *(const short8*)&o[8];
}

// ======= bf16 MFMA GEMM (BMx128 tile, BK=64, swizzled LDS, XCD swizzle, residual) =====
template <int BM>
__global__ __launch_bounds__(256) void gemm_mfma_kernel(
    const unsigned short* __restrict__ A, const unsigned short* __restrict__ Bt,
    const float* __restrict__ bias, const float* __restrict__ Res,
    float* __restrict__ Cf, unsigned short* __restrict__ Cb, int N, int K, int act)
{
  constexpr int ASLOTS = BM * 8;
  constexpr int MI = BM / 32;
  __shared__ unsigned short As[ASLOTS * 8];
  __shared__ unsigned short Bs[8192];
  const int tid = threadIdx.x, wave = tid >> 6, lane = tid & 63;
  const int gx = gridDim.x, nwg = gx * gridDim.y;
  int flat = blockIdx.y * gx + blockIdx.x;
  flat = (flat & 7) * (nwg >> 3) + (flat >> 3);
  const int bm = (flat % gx) * BM, bn = (flat / gx) * 128;
  const int wr = (wave >> 1) * (BM / 2), wc = (wave & 1) * 64;
  f32x4 acc[MI][4];
  const f32x4 zz = {0.f, 0.f, 0.f, 0.f};
  #pragma unroll
  for (int i = 0; i < MI; ++i)
    #pragma unroll
    for (int j = 0; j < 4; ++j) acc[i][j] = zz;

  for (int k0 = 0; k0 < K; k0 += 64) {
    #pragma unroll
    for (int it = 0; it < ASLOTS / 256; ++it) {
      const int s = it * 256 + tid;
      const int mr = s >> 3;
      const int kg = (s & 7) ^ (mr & 7);
      const unsigned short* src = A + (size_t)(bm + mr) * K + k0 + kg * 8;
      __builtin_amdgcn_global_load_lds(
          (const __attribute__((address_space(1))) void*)src,
          (__attribute__((address_space(3))) void*)&As[(size_t)(it * 256 + wave * 64) * 8], 16, 0, 0);
    }
    #pragma unroll
    for (int it = 0; it < 4; ++it) {
      const int s = it * 256 + tid;
      const int mr = s >> 3;
      const int kg = (s & 7) ^ (mr & 7);
      const unsigned short* src = Bt + (size_t)(bn + mr) * K + k0 + kg * 8;
      __builtin_amdgcn_global_load_lds(
          (const __attribute__((address_space(1))) void*)src,
          (__attribute__((address_space(3))) void*)&Bs[(size_t)(it * 256 + wave * 64) * 8], 16, 0, 0);
    }
    __syncthreads();
    #pragma unroll
    for (int ks = 0; ks < 2; ++ks) {
      const int kg = ks * 4 + (lane >> 4);
      short8 af[MI], bfr[4];
      #pragma unroll
      for (int i = 0; i < MI; ++i) {
        const int m = wr + i * 16 + (lane & 15);
        af[i] = *(const short8*)&As[(m * 8 + (kg ^ (m & 7))) * 8];
      }
      #pragma unroll
      for (int j = 0; j < 4; ++j) {
        const int n = wc + j * 16 + (lane & 15);
        bfr[j] = *(const short8*)&Bs[(n * 8 + (kg ^ (n & 7))) * 8];
      }
      #pragma unroll
      for (int i = 0; i < MI; ++i)
        #pragma unroll
        for (int j = 0; j < 4; ++j)
          acc[i][j] = __builtin_amdgcn_mfma_f32_16x16x32_bf16(af[i], bfr[j], acc[i][j], 0, 0, 0);
    }
    __syncthreads();
  }

  const int lr = (lane >> 4) * 4, lc = lane & 15;
  #pragma unroll
  for (int i = 0; i < MI; ++i) {
    #pragma unroll
    for (int j = 0; j < 4; ++j) {
      const int n = bn + wc + j * 16 + lc;
      const float bv = bias[n];
      #pragma unroll
      for (int p = 0; p < 4; ++p) {
        const int m = bm + wr + i * 16 + lr + p;
        float val = acc[i][j][p] + bv;
        if (Res) val += Res[(size_t)m * N + n];
        if (act) val = gelu_f(val);
        if (Cf) Cf[(size_t)m * N + n] = val;
        if (Cb) Cb[(size_t)m * N + n] = f2b(val);
      }
    }
  }
}

// == fused attention: banded flash (y<16) + global CLS row 8-way segments (y in 16..23) ==
__global__ __launch_bounds__(256) void attn_fused_kernel(
    const unsigned short* __restrict__ qkvb, const float* __restrict__ xf,
    const float* __restrict__ Wqg, const float* __restrict__ bqg,
    const int* __restrict__ am, unsigned short* __restrict__ outb,
    float* __restrict__ glbp)
{
  __shared__ __align__(16) unsigned char smem[67072];
  const int h = blockIdx.x, tid = threadIdx.x;

  if (blockIdx.y >= NCHUNK) {
    // ---------------- global CLS query row: segment g of 256 keys ----------------
    const int g = blockIdx.y - NCHUNK;    // 0..7
    float* sc  = (float*)smem;            // 256 f32
    float* qs  = (float*)(smem + 1024);   // 64
    float* red = (float*)(smem + 1280);   // 4
    float* pqg = (float*)(smem + 1296);   // 4*64
    float* pb  = (float*)(smem + 2320);   // 32*64 f32 (8 KB)
    const int d = tid & 63, grp = tid >> 6;
    // qg0 slice for this head (redundant per segment block; cheap, concurrent)
    {
      float p = 0.f;
      const float* wcol = Wqg + (size_t)(grp * 192) * DMODEL + h * DHEAD + d;
      #pragma unroll 4
      for (int k = 0; k < 192; ++k)
        p = fmaf(xf[grp * 192 + k], wcol[(size_t)k * DMODEL], p);
      pqg[grp * 64 + d] = p;
    }
    __syncthreads();
    if (tid < 64)
      qs[tid] = (pqg[tid] + pqg[64 + tid] + pqg[128 + tid] + pqg[192 + tid]
                 + bqg[h * DHEAD + tid]) * 0.125f;
    __syncthreads();
    const unsigned short* kg = qkvb + 3 * DMODEL + h * DHEAD;
    const unsigned short* vg = qkvb + 4 * DMODEL + h * DHEAD;
    const int s0 = g * 256 + tid;
    float dd = 0.f;
    {
      const unsigned short* kr = kg + (size_t)s0 * QKV_N;
      #pragma unroll
      for (int d0 = 0; d0 < DHEAD; d0 += 8) {
        const short8 k8 = *(const short8*)(kr + d0);
        #pragma unroll
        for (int e = 0; e < 8; ++e) dd += qs[d0 + e] * b2f((unsigned short)k8[e]);
      }
    }
    const float mysc = (am[s0] > 0) ? dd : -1e9f;
    float mx = mysc;
    #pragma unroll
    for (int off = 32; off; off >>= 1) mx = fmaxf(mx, __shfl_down(mx, off));
    if ((tid & 63) == 0) red[tid >> 6] = mx;
    __syncthreads();
    mx = fmaxf(fmaxf(red[0], red[1]), fmaxf(red[2], red[3]));
    __syncthreads();
    const float e = __expf(mysc - mx);
    sc[tid] = e;
    float sum = e;
    #pragma unroll
    for (int off = 32; off; off >>= 1) sum += __shfl_down(sum, off);
    if ((tid & 63) == 0) red[tid >> 6] = sum;
    __syncthreads();
    const float lsum = red[0] + red[1] + red[2] + red[3];
    // ---- PV over this segment (unnormalized): 32-key x 8-dim split, short8 loads ----
    const int d8 = (tid & 7) * 8, kgrp = tid >> 3;
    float a8[8] = {};
    #pragma unroll
    for (int ii = 0; ii < 8; ++ii) {
      const int loc = kgrp + ii * 32;
      const float p = sc[loc];
      const short8 v8 = *(const short8*)(vg + (size_t)(g * 256 + loc) * QKV_N + d8);
      #pragma unroll
      for (int ee = 0; ee < 8; ++ee) a8[ee] = fmaf(p, b2f((unsigned short)v8[ee]), a8[ee]);
    }
    #pragma unroll
    for (int ee = 0; ee < 8; ++ee) pb[kgrp * 64 + d8 + ee] = a8[ee];
    __syncthreads();
    float* pr = glbp + (size_t)(h * 8 + g) * 66;
    if (tid < 64) {
      float o = 0.f;
      #pragma unroll
      for (int k = 0; k < 32; ++k) o += pb[k * 64 + tid];
      pr[2 + tid] = o;
    }
    if (tid == 0) { pr[0] = mx; pr[1] = lsum; }
    return;
  }

  // ---------------- banded sliding-window flash ----------------
  const int nc = blockIdx.y;
  const int wave = tid >> 6, lane = tid & 63;
  const int c = lane & 15, g = lane >> 4;
  unsigned short* Ks = (unsigned short*)smem;             // 16 KB
  unsigned short* Vt = (unsigned short*)(smem + 16384);   // 16 KB
  unsigned short* Ps = (unsigned short*)(smem + 32768);   // 32 KB
  float* smcls = (float*)(smem + 65536);                  // 512 B
  float* sv0   = (float*)(smem + 66048);                  // 256 B
  int*   sam   = (int*)(smem + 66304);                    // 512 B

  if (tid < 64) sv0[tid] = b2f(qkvb[2 * DMODEL + h * DHEAD + tid]);
  if (tid < 128) {
    const int qrow = nc * CHUNK + tid;
    const unsigned short* qp = qkvb + (size_t)qrow * QKV_N + h * DHEAD;
    const unsigned short* k0 = qkvb + DMODEL + h * DHEAD;
    float d = 0.f;
    #pragma unroll
    for (int dd = 0; dd < 64; dd += 8) {
      const short8 a8 = *(const short8*)(qp + dd);
      const short8 b8 = *(const short8*)(k0 + dd);
      #pragma unroll
      for (int e = 0; e < 8; ++e)
        d += b2f((unsigned short)a8[e]) * b2f((unsigned short)b8[e]);
    }
    smcls[tid] = (am[0] > 0) ? d * 0.125f : -1e9f;
  }

  short8 af[2][2];
  #pragma unroll
  for (int i = 0; i < 2; ++i)
    #pragma unroll
    for (int ks = 0; ks < 2; ++ks) {
      const int qrow = nc * CHUNK + wave * 32 + i * 16 + c;
      af[i][ks] = *(const short8*)(qkvb + (size_t)qrow * QKV_N + h * DHEAD + (ks * 4 + g) * 8);
    }

  __syncthreads();

  float mrow[2][4], lrow[2][4];
  f32x4 acc_o[2][4];
  #pragma unroll
  for (int i = 0; i < 2; ++i)
    #pragma unroll
    for (int p = 0; p < 4; ++p) {
      mrow[i][p] = smcls[wave * 32 + i * 16 + g * 4 + p];
      lrow[i][p] = 1.f;
    }
  #pragma unroll
  for (int i = 0; i < 2; ++i)
    #pragma unroll
    for (int j = 0; j < 4; ++j) {
      const float v0 = sv0[j * 16 + c];
      acc_o[i][j][0] = v0; acc_o[i][j][1] = v0; acc_o[i][j][2] = v0; acc_o[i][j][3] = v0;
    }

  for (int kci = 0; kci < 3; ++kci) {
    const int ck = nc - 1 + kci;
    if (ck < 0 || ck > 15) continue;
    __syncthreads();

    #pragma unroll
    for (int it = 0; it < 4; ++it) {
      const int sidx = it * 256 + tid;
      const int mr = sidx >> 3;
      const int kg = (sidx & 7) ^ (mr & 7);
      const unsigned short* src = qkvb + (size_t)(ck * CHUNK + mr) * QKV_N + DMODEL + h * DHEAD + kg * 8;
      __builtin_amdgcn_global_load_lds(
          (const __attribute__((address_space(1))) void*)src,
          (__attribute__((address_space(3))) void*)&Ks[(size_t)(it * 256 + wave * 64) * 8], 16, 0, 0);
    }
    {
      const int kp = tid & 63, dh = tid >> 6;
      const unsigned short* v0p = qkvb + (size_t)(ck * CHUNK + 2 * kp) * QKV_N + 2 * DMODEL + h * DHEAD + dh * 16;
      const short8 a0 = *(const short8*)(v0p);
      const short8 a1 = *(const short8*)(v0p + 8);
      const short8 b0 = *(const short8*)(v0p + QKV_N);
      const short8 b1 = *(const short8*)(v0p + QKV_N + 8);
      #pragma unroll
      for (int dd = 0; dd < 16; ++dd) {
        const int dim = dh * 16 + dd;
        const unsigned short lo = (unsigned short)(dd < 8 ? a0[dd] : a1[dd - 8]);
        const unsigned short hi = (unsigned short)(dd < 8 ? b0[dd] : b1[dd - 8]);
        const unsigned int w = (unsigned int)lo | ((unsigned int)hi << 16);
        const int si = dim * 128 + (((kp >> 2) ^ (dim & 7)) << 3) + ((kp & 3) << 1);
        *(unsigned int*)&Vt[si] = w;
      }
    }
    if (tid < 128) sam[tid] = am[ck * CHUNK + tid];
    __syncthreads();

    f32x4 accs[2][8];
    const f32x4 zz = {0.f, 0.f, 0.f, 0.f};
    #pragma unroll
    for (int i = 0; i < 2; ++i)
      #pragma unroll
      for (int j = 0; j < 8; ++j) accs[i][j] = zz;
    #pragma unroll
    for (int ks = 0; ks < 2; ++ks) {
      const int kg = ks * 4 + g;
      short8 bfr[8];
      #pragma unroll
      for (int j = 0; j < 8; ++j) {
        const int jj = j * 16 + c;
        bfr[j] = *(const short8*)&Ks[(jj * 8 + (kg ^ (jj & 7))) * 8];
      }
      #pragma unroll
      for (int i = 0; i < 2; ++i)
        #pragma unroll
        for (int j = 0; j < 8; ++j)
          accs[i][j] = __builtin_amdgcn_mfma_f32_16x16x32_bf16(af[i][ks], bfr[j], accs[i][j], 0, 0, 0);
    }

    #pragma unroll
    for (int i = 0; i < 2; ++i) {
      #pragma unroll
      for (int p = 0; p < 4; ++p) {
        const int mloc = wave * 32 + i * 16 + g * 4 + p;
        const int qi = nc * CHUNK + mloc;
        float sv[8];
        float rmax = -1e30f;
        #pragma unroll
        for (int j = 0; j < 8; ++j) {
          const int jj = j * 16 + c;
          const int kj = ck * CHUNK + jj;
          const int diff = qi - kj;
          const bool ok = (diff <= 128) && (diff >= -128) && (kj != 0) && (sam[jj] > 0);
          const float s = ok ? accs[i][j][p] * 0.125f : -1e9f;
          sv[j] = s;
          rmax = fmaxf(rmax, s);
        }
        rmax = fmaxf(rmax, __shfl_xor(rmax, 1));
        rmax = fmaxf(rmax, __shfl_xor(rmax, 2));
        rmax = fmaxf(rmax, __shfl_xor(rmax, 4));
        rmax = fmaxf(rmax, __shfl_xor(rmax, 8));
        const float mnew = fmaxf(mrow[i][p], rmax);
        const float corr = __expf(mrow[i][p] - mnew);
        float psum = 0.f;
        #pragma unroll
        for (int j = 0; j < 8; ++j) {
          const float pv = __expf(sv[j] - mnew);
          sv[j] = pv;
          psum += pv;
        }
        psum += __shfl_xor(psum, 1);
        psum += __shfl_xor(psum, 2);
        psum += __shfl_xor(psum, 4);
        psum += __shfl_xor(psum, 8);
        lrow[i][p] = lrow[i][p] * corr + psum;
        mrow[i][p] = mnew;
        #pragma unroll
        for (int j = 0; j < 4; ++j) acc_o[i][j][p] *= corr;
        #pragma unroll
        for (int j = 0; j < 8; ++j) {
          const int key = j * 16 + c;
          const int kslot = key >> 3;
          Ps[mloc * 128 + ((kslot ^ (mloc & 7)) << 3) + (key & 7)] = f2b(sv[j]);
        }
      }
    }
    asm volatile("s_waitcnt lgkmcnt(0)" ::: "memory");

    #pragma unroll
    for (int ks2 = 0; ks2 < 4; ++ks2) {
      const int kg2 = ks2 * 4 + g;
      short8 pa[2], vb[4];
      #pragma unroll
      for (int i = 0; i < 2; ++i) {
        const int row = wave * 32 + i * 16 + c;
        pa[i] = *(const short8*)&Ps[row * 128 + ((kg2 ^ (row & 7)) << 3)];
      }
      #pragma unroll
      for (int j = 0; j < 4; ++j) {
        const int n = j * 16 + c;
        vb[j] = *(const short8*)&Vt[n * 128 + ((kg2 ^ (n & 7)) << 3)];
      }
      #pragma unroll
      for (int i = 0; i < 2; ++i)
        #pragma unroll
        for (int j = 0; j < 4; ++j)
          acc_o[i][j] = __builtin_amdgcn_mfma_f32_16x16x32_bf16(pa[i], vb[j], acc_o[i][j], 0, 0, 0);
    }
  }

  #pragma unroll
  for (int i = 0; i < 2; ++i) {
    #pragma unroll
    for (int p = 0; p < 4; ++p) {
      const float rl = (lrow[i][p] > 0.f) ? 1.f / lrow[i][p] : 0.f;
      const int row = nc * CHUNK + wave * 32 + i * 16 + g * 4 + p;
      if (row == 0) continue;  // row 0 owned by the global path
      #pragma unroll
      for (int j = 0; j < 4; ++j)
        outb[(size_t)row * DMODEL + h * DHEAD + j * 16 + c] = f2b(acc_o[i][j][p] * rl);
    }
  }
}

// ================= global CLS combine: merge 8 segment partials -> row 0 =============
__global__ __launch_bounds__(64) void glb_attn_combine_kernel(
    const float* __restrict__ part, unsigned short* __restrict__ outb)
{
  const int h = blockIdx.x, d = threadIdx.x;
  float M = -1e30f;
  for (int g = 0; g < 8; ++g) M = fmaxf(M, part[(size_t)(h * 8 + g) * 66]);
  float L = 0.f, o = 0.f;
  for (int g = 0; g < 8; ++g) {
    const float* pr = part + (size_t)(h * 8 + g) * 66;
    const float cc = (pr[0] > -1e8f) ? __expf(pr[0] - M) : 0.f;
    L += pr[1] * cc;
    o += pr[2 + d] * cc;
  }
  outb[h * DHEAD + d] = f2b(o / L);
}

// ================= split-k GEMV (head MLP only) =================
__global__ __launch_bounds__(256) void gemv_partial_kernel(
    const float* __restrict__ xrow, const float* __restrict__ W, float* __restrict__ part)
{
  const int b = blockIdx.x, t = threadIdx.x;
  float s0 = 0.f, s1 = 0.f, s2 = 0.f;
  for (int kk = 0; kk < 48; ++kk) {
    const int k = b * 48 + kk;
    const float xv = xrow[k];
    const float* wr = W + (size_t)k * DMODEL;
    s0 = fmaf(xv, wr[t], s0);
    s1 = fmaf(xv, wr[t + 256], s1);
    s2 = fmaf(xv, wr[t + 512], s2);
  }
  part[b * DMODEL + t] = s0;
  part[b * DMODEL + t + 256] = s1;
  part[b * DMODEL + t + 512] = s2;
}

__global__ __launch_bounds__(256) void gemv_reduce_kernel(
    const float* __restrict__ part, const float* __restrict__ bias,
    float* __restrict__ y, int act)
{
  const int n = blockIdx.x * 256 + threadIdx.x;
  float s = bias[n];
  #pragma unroll
  for (int b = 0; b < 16; ++b) s += part[b * DMODEL + n];
  if (act) s = gelu_f(s);
  y[n] = s;
}

// ================= final head =================
__global__ __launch_bounds__(256) void head_final_kernel(
    const float* __restrict__ h2, const float* __restrict__ Wout,
    const float* __restrict__ bout, float* __restrict__ out)
{
  const int tid = threadIdx.x;
  __shared__ float red[4];
  float p = h2[tid]*Wout[tid] + h2[tid+256]*Wout[tid+256] + h2[tid+512]*Wout[tid+512];
  #pragma unroll
  for (int off = 32; off; off >>= 1) p += __shfl_down(p, off);
  if ((tid & 63) == 0) red[tid >> 6] = p;
  __syncthreads();
  if (tid == 0) {
    const float logit = red[0] + red[1] + red[2] + red[3] + bout[0];
    const float sig = 1.0f / (1.0f + expf(-logit));
    const unsigned int bits = __float_as_uint(sig);
    const unsigned int bf = (bits + 0x7FFFu + ((bits >> 16) & 1u)) >> 16;
    out[0] = __uint_as_float((bits & 0xFFFF0000u) | (bf & 0xFFFFu));
  }
}

extern "C" void kernel_launch(void* const* d_in, const int* in_sizes, int n_in,
                              void* d_out, int out_size, void* d_ws, size_t ws_size,
                              hipStream_t stream)
{
  const int*   ids  = (const int*)d_in[0];
  const int*   am   = (const int*)d_in[1];
  const float* wemb = (const float*)d_in[2];
  const float* pemb = (const float*)d_in[3];
  const float* emb_g = (const float*)d_in[4];
  const float* emb_b = (const float*)d_in[5];
  const float* Wq  = (const float*)d_in[6];
  const float* bq  = (const float*)d_in[7];
  const float* Wk  = (const float*)d_in[8];
  const float* bk  = (const float*)d_in[9];
  const float* Wv  = (const float*)d_in[10];
  const float* bv  = (const float*)d_in[11];
  const float* Wqg = (const float*)d_in[12];
  const float* bqg = (const float*)d_in[13];
  const float* Wkg = (const float*)d_in[14];
  const float* bkg = (const float*)d_in[15];
  const float* Wvg = (const float*)d_in[16];
  const float* bvg = (const float*)d_in[17];
  const float* Wo  = (const float*)d_in[18];
  const float* bo  = (const float*)d_in[19];
  const float* ln1g = (const float*)d_in[20];
  const float* ln1b = (const float*)d_in[21];
  const float* Wf1 = (const float*)d_in[22];
  const float* bf1 = (const float*)d_in[23];
  const float* Wf2 = (const float*)d_in[24];
  const float* bf2 = (const float*)d_in[25];
  const float* ln2g = (const float*)d_in[26];
  const float* ln2b = (const float*)d_in[27];
  const float* hng = (const float*)d_in[28];
  const float* hnb = (const float*)d_in[29];
  const float* W1  = (const float*)d_in[30];
  const float* b1  = (const float*)d_in[31];
  const float* W2  = (const float*)d_in[32];
  const float* b2  = (const float*)d_in[33];
  const float* Wout = (const float*)d_in[34];
  const float* bout = (const float*)d_in[35];

  char* wp = (char*)d_ws;
  auto alloc = [&](size_t bytes) -> void* {
    void* r = (void*)wp;
    wp += (bytes + 255) & ~(size_t)255;
    return r;
  };
  float*          x         = (float*)alloc((size_t)S_LEN * DMODEL * 4);
  unsigned short* xb        = (unsigned short*)alloc((size_t)S_LEN * DMODEL * 2);
  unsigned short* qkvb      = (unsigned short*)alloc((size_t)S_LEN * QKV_N * 2);
  unsigned short* attnb     = (unsigned short*)alloc((size_t)S_LEN * DMODEL * 2);
  unsigned short* tmpb      = (unsigned short*)alloc((size_t)S_LEN * FFDIM * 2);
  float*          tmpf      = (float*)alloc((size_t)S_LEN * DMODEL * 4);
  unsigned short* WqkvT_all = (unsigned short*)alloc((size_t)NLAYER * 5 * DD * 2);
  unsigned short* WoT_all   = (unsigned short*)alloc((size_t)NLAYER * DD * 2);
  unsigned short* Wf1T_all  = (unsigned short*)alloc((size_t)NLAYER * DF * 2);
  unsigned short* Wf2T_all  = (unsigned short*)alloc((size_t)NLAYER * DF * 2);
  float*          bqkv_all  = (float*)alloc((size_t)NLAYER * QKV_N * 4);
  float*          glbp      = (float*)alloc((size_t)NHEAD * 8 * 66 * 4);
  float*          gpart     = (float*)alloc((size_t)16 * DMODEL * 4);
  float*          hb        = (float*)alloc((size_t)3 * DMODEL * 4);

  // one-shot weight conversion for all layers (BW-bound, 2 launches)
  conv_all_dd_kernel<<<dim3(12, 12, 6 * NLAYER), 256, 0, stream>>>(
      Wq, Wk, Wv, Wkg, Wvg, Wo, bq, bk, bv, bkg, bvg, WqkvT_all, WoT_all, bqkv_all);
  conv_all_ffn_kernel<<<dim3(48, 12, 2 * NLAYER), 256, 0, stream>>>(
      Wf1, Wf2, Wf1T_all, Wf2T_all);

  embed_ln_kernel<<<S_LEN, 256, 0, stream>>>(ids, wemb, pemb, emb_g, emb_b, x, xb);

  for (int l = 0; l < NLAYER; ++l) {
    const size_t wdd = (size_t)l * DD;
    const size_t vd  = (size_t)l * DMODEL;
    const size_t vf  = (size_t)l * FFDIM;
    const unsigned short* WqkvT = WqkvT_all + (size_t)l * 5 * DD;
    const unsigned short* WoT   = WoT_all + wdd;
    const unsigned short* Wf1T  = Wf1T_all + (size_t)l * DF;
    const unsigned short* Wf2T  = Wf2T_all + (size_t)l * DF;
    const float* bqkv = bqkv_all + (size_t)l * QKV_N;

    // fused q|k|v|kg|vg projection: [2048,768] @ [768,3840] -> bf16
    gemm_mfma_kernel<128><<<dim3(16, 30), 256, 0, stream>>>(
        xb, WqkvT, bqkv, (const float*)nullptr, (float*)nullptr, qkvb, QKV_N, DMODEL, 0);

    // banded flash (192 blocks) + global CLS segments (96 blocks) in one launch
    attn_fused_kernel<<<dim3(NHEAD, NCHUNK + 8), 256, 0, stream>>>(
        qkvb, x, Wqg + wdd, bqg + vd, am, attnb, glbp);
    glb_attn_combine_kernel<<<NHEAD, 64, 0, stream>>>(glbp, attnb);

    // Wo projection + residual add fused
    gemm_mfma_kernel<64><<<dim3(32, 6), 256, 0, stream>>>(
        attnb, WoT, bo + vd, x, tmpf, (unsigned short*)nullptr, DMODEL, DMODEL, 0);
    ln_fused_kernel<<<S_LEN, 256, 0, stream>>>(tmpf, ln1g + vd, ln1b + vd, x, xb);

    gemm_mfma_kernel<128><<<dim3(16, 24), 256, 0, stream>>>(
        xb, Wf1T, bf1 + vf, (const float*)nullptr, (float*)nullptr, tmpb, FFDIM, DMODEL, 1);
    gemm_mfma_kernel<64><<<dim3(32, 6), 256, 0, stream>>>(
        tmpb, Wf2T, bf2 + vd, x, tmpf, (unsigned short*)nullptr, DMODEL, FFDIM, 0);
    ln_fused_kernel<<<S_LEN, 256, 0, stream>>>(tmpf, ln2g + vd, ln2b + vd, x, xb);
  }

  ln_vec_kernel<<<1, 256, 0, stream>>>(x, hng, hnb, hb);
  gemv_partial_kernel<<<16, 256, 0, stream>>>(hb, W1, gpart);
  gemv_reduce_kernel<<<3, 256, 0, stream>>>(gpart, b1, hb + DMODEL, 1);
  gemv_partial_kernel<<<16, 256, 0, stream>>>(hb + DMODEL, W2, gpart);
  gemv_reduce_kernel<<<3, 256, 0, stream>>>(gpart, b2, hb + 2 * DMODEL, 1);
  head_final_kernel<<<1, 256, 0, stream>>>(hb + 2 * DMODEL, Wout, bout, (float*)d_out);
}

// Round 8
// 2415.760 us; speedup vs baseline: 1.6821x; 1.0399x over previous
//
#include <hip/hip_runtime.h>
#include <math.h>

#define S_LEN 2048
#define DMODEL 768
#define NHEAD 12
#define DHEAD 64
#define NLAYER 12
#define FFDIM 3072
#define CHUNK 128
#define NCHUNK 16
#define QKV_N 3840   // q|k|v|kg|vg concatenated
#define DD (DMODEL * DMODEL)
#define DF (DMODEL * FFDIM)

typedef __attribute__((ext_vector_type(8))) short short8;
typedef __attribute__((ext_vector_type(4))) float f32x4;

__device__ __forceinline__ float gelu_f(float x) {
  return 0.5f * x * (1.0f + erff(x * 0.7071067811865476f));
}
// float -> bf16 bits (RNE)
__device__ __forceinline__ unsigned short f2b(float f) {
  unsigned int u = __float_as_uint(f);
  return (unsigned short)((u + 0x7FFFu + ((u >> 16) & 1u)) >> 16);
}
__device__ __forceinline__ float b2f(unsigned short u) {
  return __uint_as_float((unsigned int)u << 16);
}

// ================= embedding + LN =================
__global__ __launch_bounds__(256) void embed_ln_kernel(
    const int* __restrict__ ids, const float* __restrict__ wemb,
    const float* __restrict__ pemb, const float* __restrict__ g,
    const float* __restrict__ b, float* __restrict__ x, unsigned short* __restrict__ xb)
{
  const int s = blockIdx.x, tid = threadIdx.x;
  __shared__ float red[4];
  const size_t wbase = (size_t)ids[s] * DMODEL;
  const size_t pbase = (size_t)s * DMODEL;
  float y0 = wemb[wbase + tid]       + pemb[pbase + tid];
  float y1 = wemb[wbase + tid + 256] + pemb[pbase + tid + 256];
  float y2 = wemb[wbase + tid + 512] + pemb[pbase + tid + 512];
  float sum = y0 + y1 + y2;
  #pragma unroll
  for (int off = 32; off; off >>= 1) sum += __shfl_down(sum, off);
  if ((tid & 63) == 0) red[tid >> 6] = sum;
  __syncthreads();
  const float mean = (red[0] + red[1] + red[2] + red[3]) * (1.0f / 768.0f);
  __syncthreads();
  float d0 = y0 - mean, d1 = y1 - mean, d2 = y2 - mean;
  float vs = d0*d0 + d1*d1 + d2*d2;
  #pragma unroll
  for (int off = 32; off; off >>= 1) vs += __shfl_down(vs, off);
  if ((tid & 63) == 0) red[tid >> 6] = vs;
  __syncthreads();
  const float rstd = rsqrtf((red[0]+red[1]+red[2]+red[3]) * (1.0f/768.0f) + 1e-5f);
  float o0 = d0 * rstd * g[tid]       + b[tid];
  float o1 = d1 * rstd * g[tid + 256] + b[tid + 256];
  float o2 = d2 * rstd * g[tid + 512] + b[tid + 512];
  x[pbase + tid] = o0; x[pbase + tid + 256] = o1; x[pbase + tid + 512] = o2;
  xb[pbase + tid] = f2b(o0); xb[pbase + tid + 256] = f2b(o1); xb[pbase + tid + 512] = f2b(o2);
}

// ================= LN of t (t already holds residual sum) -> x (f32) + xb (bf16) ======
__global__ __launch_bounds__(256) void ln_fused_kernel(
    const float* __restrict__ t, const float* __restrict__ g,
    const float* __restrict__ b, float* __restrict__ x, unsigned short* __restrict__ xb)
{
  const int s = blockIdx.x, tid = threadIdx.x;
  __shared__ float red[4];
  const size_t base = (size_t)s * DMODEL;
  float y0 = t[base + tid], y1 = t[base + tid + 256], y2 = t[base + tid + 512];
  float sum = y0 + y1 + y2;
  #pragma unroll
  for (int off = 32; off; off >>= 1) sum += __shfl_down(sum, off);
  if ((tid & 63) == 0) red[tid >> 6] = sum;
  __syncthreads();
  const float mean = (red[0] + red[1] + red[2] + red[3]) * (1.0f / 768.0f);
  __syncthreads();
  float d0 = y0 - mean, d1 = y1 - mean, d2 = y2 - mean;
  float vs = d0*d0 + d1*d1 + d2*d2;
  #pragma unroll
  for (int off = 32; off; off >>= 1) vs += __shfl_down(vs, off);
  if ((tid & 63) == 0) red[tid >> 6] = vs;
  __syncthreads();
  const float rstd = rsqrtf((red[0]+red[1]+red[2]+red[3]) * (1.0f/768.0f) + 1e-5f);
  float o0 = d0 * rstd * g[tid]       + b[tid];
  float o1 = d1 * rstd * g[tid + 256] + b[tid + 256];
  float o2 = d2 * rstd * g[tid + 512] + b[tid + 512];
  x[base + tid] = o0; x[base + tid + 256] = o1; x[base + tid + 512] = o2;
  xb[base + tid] = f2b(o0); xb[base + tid + 256] = f2b(o1); xb[base + tid + 512] = f2b(o2);
}

__global__ __launch_bounds__(256) void ln_vec_kernel(
    const float* __restrict__ in, const float* __restrict__ g,
    const float* __restrict__ b, float* __restrict__ out)
{
  const int tid = threadIdx.x;
  __shared__ float red[4];
  float y0 = in[tid], y1 = in[tid + 256], y2 = in[tid + 512];
  float sum = y0 + y1 + y2;
  #pragma unroll
  for (int off = 32; off; off >>= 1) sum += __shfl_down(sum, off);
  if ((tid & 63) == 0) red[tid >> 6] = sum;
  __syncthreads();
  const float mean = (red[0] + red[1] + red[2] + red[3]) * (1.0f / 768.0f);
  __syncthreads();
  float d0 = y0 - mean, d1 = y1 - mean, d2 = y2 - mean;
  float vs = d0*d0 + d1*d1 + d2*d2;
  #pragma unroll
  for (int off = 32; off; off >>= 1) vs += __shfl_down(vs, off);
  if ((tid & 63) == 0) red[tid >> 6] = vs;
  __syncthreads();
  const float rstd = rsqrtf((red[0]+red[1]+red[2]+red[3]) * (1.0f/768.0f) + 1e-5f);
  out[tid]       = d0 * rstd * g[tid]       + b[tid];
  out[tid + 256] = d1 * rstd * g[tid + 256] + b[tid + 256];
  out[tid + 512] = d2 * rstd * g[tid + 512] + b[tid + 512];
}

// ====== one-shot weight convert+transpose, 64x64 tiles (f32 [K][N] -> bf16 [N][K]) ====
__global__ __launch_bounds__(256) void conv_all_dd_kernel(
    const float* __restrict__ Wq, const float* __restrict__ Wk, const float* __restrict__ Wv,
    const float* __restrict__ Wkg, const float* __restrict__ Wvg, const float* __restrict__ Wo,
    const float* __restrict__ bq, const float* __restrict__ bk, const float* __restrict__ bv,
    const float* __restrict__ bkg, const float* __restrict__ bvg,
    unsigned short* __restrict__ WqkvT, unsigned short* __restrict__ WoT,
    float* __restrict__ bqkv)
{
  const int z = blockIdx.z, layer = z / 6, mat = z % 6;
  const size_t off = (size_t)layer * DD;
  const float* src = (mat==0?Wq: mat==1?Wk: mat==2?Wv: mat==3?Wkg: mat==4?Wvg: Wo) + off;
  unsigned short* dst = (mat < 5)
      ? (WqkvT + (size_t)layer * 5 * DD + (size_t)mat * DD)
      : (WoT + off);
  __shared__ float tbuf[64][65];
  const int n0 = blockIdx.x * 64, k0 = blockIdx.y * 64;
  const int t = threadIdx.x;
  #pragma unroll
  for (int i = 0; i < 4; ++i) {
    const int idx = i * 256 + t;
    const int r = idx >> 4, c4 = (idx & 15) * 4;
    const float4 v = *(const float4*)&src[(size_t)(k0 + r) * DMODEL + n0 + c4];
    tbuf[r][c4] = v.x; tbuf[r][c4+1] = v.y; tbuf[r][c4+2] = v.z; tbuf[r][c4+3] = v.w;
  }
  __syncthreads();
  const int n = t >> 2, seg = (t & 3) * 16;
  unsigned short o[16];
  #pragma unroll
  for (int i = 0; i < 16; ++i) o[i] = f2b(tbuf[seg + i][n]);
  unsigned short* dp = &dst[(size_t)(n0 + n) * DMODEL + k0 + seg];
  *(short8*)dp = *(const short8*)&o[0];
  *(short8*)(dp + 8) = *(const short8*)&o[8];
  if (mat < 5 && blockIdx.x == 0 && blockIdx.y == 0) {
    const float* bs = (mat==0?bq: mat==1?bk: mat==2?bv: mat==3?bkg: bvg) + (size_t)layer * DMODEL;
    for (int i = t; i < DMODEL; i += 256) bqkv[(size_t)layer * QKV_N + mat * DMODEL + i] = bs[i];
  }
}

__global__ __launch_bounds__(256) void conv_all_ffn_kernel(
    const float* __restrict__ Wf1, const float* __restrict__ Wf2,
    unsigned short* __restrict__ Wf1T, unsigned short* __restrict__ Wf2T)
{
  const int z = blockIdx.z, layer = z / 2, which = z % 2;
  __shared__ float tbuf[64][65];
  const float* src; unsigned short* dst; int Kd, Nd, n0, k0;
  if (which == 0) { src = Wf1 + (size_t)layer * DF; dst = Wf1T + (size_t)layer * DF;
                    Kd = DMODEL; Nd = FFDIM; n0 = blockIdx.x * 64; k0 = blockIdx.y * 64; }
  else            { src = Wf2 + (size_t)layer * DF; dst = Wf2T + (size_t)layer * DF;
                    Kd = FFDIM; Nd = DMODEL; n0 = blockIdx.y * 64; k0 = blockIdx.x * 64; }
  const int t = threadIdx.x;
  #pragma unroll
  for (int i = 0; i < 4; ++i) {
    const int idx = i * 256 + t;
    const int r = idx >> 4, c4 = (idx & 15) * 4;
    const float4 v = *(const float4*)&src[(size_t)(k0 + r) * Nd + n0 + c4];
    tbuf[r][c4] = v.x; tbuf[r][c4+1] = v.y; tbuf[r][c4+2] = v.z; tbuf[r][c4+3] = v.w;
  }
  __syncthreads();
  const int n = t >> 2, seg = (t & 3) * 16;
  unsigned short o[16];
  #pragma unroll
  for (int i = 0; i < 16; ++i) o[i] = f2b(tbuf[seg + i][n]);
  unsigned short* dp = &dst[(size_t)(n0 + n) * Kd + k0 + seg];
  *(short8*)dp = *(const short8*)&o[0];
  *(short8*)(dp + 8) = *(const short8*)&o[8];
}

// ======= bf16 MFMA GEMM (BMx128 tile, BK=64, swizzled LDS, XCD swizzle, residual) =====
template <int BM>
__global__ __launch_bounds__(256) void gemm_mfma_kernel(
    const unsigned short* __restrict__ A, const unsigned short* __restrict__ Bt,
    const float* __restrict__ bias, const float* __restrict__ Res,
    float* __restrict__ Cf, unsigned short* __restrict__ Cb, int N, int K, int act)
{
  constexpr int ASLOTS = BM * 8;
  constexpr int MI = BM / 32;
  __shared__ unsigned short As[ASLOTS * 8];
  __shared__ unsigned short Bs[8192];
  const int tid = threadIdx.x, wave = tid >> 6, lane = tid & 63;
  const int gx = gridDim.x, nwg = gx * gridDim.y;
  int flat = blockIdx.y * gx + blockIdx.x;
  flat = (flat & 7) * (nwg >> 3) + (flat >> 3);
  const int bm = (flat % gx) * BM, bn = (flat / gx) * 128;
  const int wr = (wave >> 1) * (BM / 2), wc = (wave & 1) * 64;
  f32x4 acc[MI][4];
  const f32x4 zz = {0.f, 0.f, 0.f, 0.f};
  #pragma unroll
  for (int i = 0; i < MI; ++i)
    #pragma unroll
    for (int j = 0; j < 4; ++j) acc[i][j] = zz;

  for (int k0 = 0; k0 < K; k0 += 64) {
    #pragma unroll
    for (int it = 0; it < ASLOTS / 256; ++it) {
      const int s = it * 256 + tid;
      const int mr = s >> 3;
      const int kg = (s & 7) ^ (mr & 7);
      const unsigned short* src = A + (size_t)(bm + mr) * K + k0 + kg * 8;
      __builtin_amdgcn_global_load_lds(
          (const __attribute__((address_space(1))) void*)src,
          (__attribute__((address_space(3))) void*)&As[(size_t)(it * 256 + wave * 64) * 8], 16, 0, 0);
    }
    #pragma unroll
    for (int it = 0; it < 4; ++it) {
      const int s = it * 256 + tid;
      const int mr = s >> 3;
      const int kg = (s & 7) ^ (mr & 7);
      const unsigned short* src = Bt + (size_t)(bn + mr) * K + k0 + kg * 8;
      __builtin_amdgcn_global_load_lds(
          (const __attribute__((address_space(1))) void*)src,
          (__attribute__((address_space(3))) void*)&Bs[(size_t)(it * 256 + wave * 64) * 8], 16, 0, 0);
    }
    __syncthreads();
    #pragma unroll
    for (int ks = 0; ks < 2; ++ks) {
      const int kg = ks * 4 + (lane >> 4);
      short8 af[MI], bfr[4];
      #pragma unroll
      for (int i = 0; i < MI; ++i) {
        const int m = wr + i * 16 + (lane & 15);
        af[i] = *(const short8*)&As[(m * 8 + (kg ^ (m & 7))) * 8];
      }
      #pragma unroll
      for (int j = 0; j < 4; ++j) {
        const int n = wc + j * 16 + (lane & 15);
        bfr[j] = *(const short8*)&Bs[(n * 8 + (kg ^ (n & 7))) * 8];
      }
      #pragma unroll
      for (int i = 0; i < MI; ++i)
        #pragma unroll
        for (int j = 0; j < 4; ++j)
          acc[i][j] = __builtin_amdgcn_mfma_f32_16x16x32_bf16(af[i], bfr[j], acc[i][j], 0, 0, 0);
    }
    __syncthreads();
  }

  const int lr = (lane >> 4) * 4, lc = lane & 15;
  #pragma unroll
  for (int i = 0; i < MI; ++i) {
    #pragma unroll
    for (int j = 0; j < 4; ++j) {
      const int n = bn + wc + j * 16 + lc;
      const float bv = bias[n];
      #pragma unroll
      for (int p = 0; p < 4; ++p) {
        const int m = bm + wr + i * 16 + lr + p;
        float val = acc[i][j][p] + bv;
        if (Res) val += Res[(size_t)m * N + n];
        if (act) val = gelu_f(val);
        if (Cf) Cf[(size_t)m * N + n] = val;
        if (Cb) Cb[(size_t)m * N + n] = f2b(val);
      }
    }
  }
}

// == fused attention: banded flash (y<16) + global CLS row 8-way segments (y in 16..23) ==
// LDS: Ks 16K | Vt 16K | Ps 16K (64-key half-tile) | smcls/sv0/sam -> 50.4 KB total
__global__ __launch_bounds__(256) void attn_fused_kernel(
    const unsigned short* __restrict__ qkvb, const float* __restrict__ xf,
    const float* __restrict__ Wqg, const float* __restrict__ bqg,
    const int* __restrict__ am, unsigned short* __restrict__ outb,
    float* __restrict__ glbp)
{
  __shared__ __align__(16) unsigned char smem[50432];
  const int h = blockIdx.x, tid = threadIdx.x;

  if (blockIdx.y >= NCHUNK) {
    // ---------------- global CLS query row: segment g of 256 keys ----------------
    const int g = blockIdx.y - NCHUNK;    // 0..7
    float* sc  = (float*)smem;            // 256 f32
    float* qs  = (float*)(smem + 1024);   // 64
    float* red = (float*)(smem + 1280);   // 4
    float* pqg = (float*)(smem + 1296);   // 4*64
    float* pb  = (float*)(smem + 2320);   // 32*64 f32 (8 KB)
    const int d = tid & 63, grp = tid >> 6;
    // qg0 slice for this head (redundant per segment block; cheap, concurrent)
    {
      float p = 0.f;
      const float* wcol = Wqg + (size_t)(grp * 192) * DMODEL + h * DHEAD + d;
      #pragma unroll 4
      for (int k = 0; k < 192; ++k)
        p = fmaf(xf[grp * 192 + k], wcol[(size_t)k * DMODEL], p);
      pqg[grp * 64 + d] = p;
    }
    __syncthreads();
    if (tid < 64)
      qs[tid] = (pqg[tid] + pqg[64 + tid] + pqg[128 + tid] + pqg[192 + tid]
                 + bqg[h * DHEAD + tid]) * 0.125f;
    __syncthreads();
    const unsigned short* kg = qkvb + 3 * DMODEL + h * DHEAD;
    const unsigned short* vg = qkvb + 4 * DMODEL + h * DHEAD;
    const int s0 = g * 256 + tid;
    float dd = 0.f;
    {
      const unsigned short* kr = kg + (size_t)s0 * QKV_N;
      #pragma unroll
      for (int d0 = 0; d0 < DHEAD; d0 += 8) {
        const short8 k8 = *(const short8*)(kr + d0);
        #pragma unroll
        for (int e = 0; e < 8; ++e) dd += qs[d0 + e] * b2f((unsigned short)k8[e]);
      }
    }
    const float mysc = (am[s0] > 0) ? dd : -1e9f;
    float mx = mysc;
    #pragma unroll
    for (int off = 32; off; off >>= 1) mx = fmaxf(mx, __shfl_down(mx, off));
    if ((tid & 63) == 0) red[tid >> 6] = mx;
    __syncthreads();
    mx = fmaxf(fmaxf(red[0], red[1]), fmaxf(red[2], red[3]));
    __syncthreads();
    const float e = __expf(mysc - mx);
    sc[tid] = e;
    float sum = e;
    #pragma unroll
    for (int off = 32; off; off >>= 1) sum += __shfl_down(sum, off);
    if ((tid & 63) == 0) red[tid >> 6] = sum;
    __syncthreads();
    const float lsum = red[0] + red[1] + red[2] + red[3];
    // ---- PV over this segment (unnormalized): 32-key x 8-dim split, short8 loads ----
    const int d8 = (tid & 7) * 8, kgrp = tid >> 3;
    float a8[8] = {};
    #pragma unroll
    for (int ii = 0; ii < 8; ++ii) {
      const int loc = kgrp + ii * 32;
      const float p = sc[loc];
      const short8 v8 = *(const short8*)(vg + (size_t)(g * 256 + loc) * QKV_N + d8);
      #pragma unroll
      for (int ee = 0; ee < 8; ++ee) a8[ee] = fmaf(p, b2f((unsigned short)v8[ee]), a8[ee]);
    }
    #pragma unroll
    for (int ee = 0; ee < 8; ++ee) pb[kgrp * 64 + d8 + ee] = a8[ee];
    __syncthreads();
    float* pr = glbp + (size_t)(h * 8 + g) * 66;
    if (tid < 64) {
      float o = 0.f;
      #pragma unroll
      for (int k = 0; k < 32; ++k) o += pb[k * 64 + tid];
      pr[2 + tid] = o;
    }
    if (tid == 0) { pr[0] = mx; pr[1] = lsum; }
    return;
  }

  // ---------------- banded sliding-window flash ----------------
  const int nc = blockIdx.y;
  const int wave = tid >> 6, lane = tid & 63;
  const int c = lane & 15, g = lane >> 4;
  unsigned short* Ks = (unsigned short*)smem;             // 16 KB
  unsigned short* Vt = (unsigned short*)(smem + 16384);   // 16 KB
  unsigned short* Ps = (unsigned short*)(smem + 32768);   // 16 KB ([128 rows][64 keys])
  float* smcls = (float*)(smem + 49152);                  // 512 B
  float* sv0   = (float*)(smem + 49664);                  // 256 B
  int*   sam   = (int*)(smem + 49920);                    // 512 B

  if (tid < 64) sv0[tid] = b2f(qkvb[2 * DMODEL + h * DHEAD + tid]);
  if (tid < 128) {
    const int qrow = nc * CHUNK + tid;
    const unsigned short* qp = qkvb + (size_t)qrow * QKV_N + h * DHEAD;
    const unsigned short* k0 = qkvb + DMODEL + h * DHEAD;
    float d = 0.f;
    #pragma unroll
    for (int dd = 0; dd < 64; dd += 8) {
      const short8 a8 = *(const short8*)(qp + dd);
      const short8 b8 = *(const short8*)(k0 + dd);
      #pragma unroll
      for (int e = 0; e < 8; ++e)
        d += b2f((unsigned short)a8[e]) * b2f((unsigned short)b8[e]);
    }
    smcls[tid] = (am[0] > 0) ? d * 0.125f : -1e9f;
  }

  short8 af[2][2];
  #pragma unroll
  for (int i = 0; i < 2; ++i)
    #pragma unroll
    for (int ks = 0; ks < 2; ++ks) {
      const int qrow = nc * CHUNK + wave * 32 + i * 16 + c;
      af[i][ks] = *(const short8*)(qkvb + (size_t)qrow * QKV_N + h * DHEAD + (ks * 4 + g) * 8);
    }

  __syncthreads();

  float mrow[2][4], lrow[2][4];
  f32x4 acc_o[2][4];
  #pragma unroll
  for (int i = 0; i < 2; ++i)
    #pragma unroll
    for (int p = 0; p < 4; ++p) {
      mrow[i][p] = smcls[wave * 32 + i * 16 + g * 4 + p];
      lrow[i][p] = 1.f;
    }
  #pragma unroll
  for (int i = 0; i < 2; ++i)
    #pragma unroll
    for (int j = 0; j < 4; ++j) {
      const float v0 = sv0[j * 16 + c];
      acc_o[i][j][0] = v0; acc_o[i][j][1] = v0; acc_o[i][j][2] = v0; acc_o[i][j][3] = v0;
    }

  for (int kci = 0; kci < 3; ++kci) {
    const int ck = nc - 1 + kci;
    if (ck < 0 || ck > 15) continue;
    __syncthreads();

    #pragma unroll
    for (int it = 0; it < 4; ++it) {
      const int sidx = it * 256 + tid;
      const int mr = sidx >> 3;
      const int kg = (sidx & 7) ^ (mr & 7);
      const unsigned short* src = qkvb + (size_t)(ck * CHUNK + mr) * QKV_N + DMODEL + h * DHEAD + kg * 8;
      __builtin_amdgcn_global_load_lds(
          (const __attribute__((address_space(1))) void*)src,
          (__attribute__((address_space(3))) void*)&Ks[(size_t)(it * 256 + wave * 64) * 8], 16, 0, 0);
    }
    {
      const int kp = tid & 63, dh = tid >> 6;
      const unsigned short* v0p = qkvb + (size_t)(ck * CHUNK + 2 * kp) * QKV_N + 2 * DMODEL + h * DHEAD + dh * 16;
      const short8 a0 = *(const short8*)(v0p);
      const short8 a1 = *(const short8*)(v0p + 8);
      const short8 b0 = *(const short8*)(v0p + QKV_N);
      const short8 b1 = *(const short8*)(v0p + QKV_N + 8);
      #pragma unroll
      for (int dd = 0; dd < 16; ++dd) {
        const int dim = dh * 16 + dd;
        const unsigned short lo = (unsigned short)(dd < 8 ? a0[dd] : a1[dd - 8]);
        const unsigned short hi = (unsigned short)(dd < 8 ? b0[dd] : b1[dd - 8]);
        const unsigned int w = (unsigned int)lo | ((unsigned int)hi << 16);
        const int si = dim * 128 + (((kp >> 2) ^ (dim & 7)) << 3) + ((kp & 3) << 1);
        *(unsigned int*)&Vt[si] = w;
      }
    }
    if (tid < 128) sam[tid] = am[ck * CHUNK + tid];
    __syncthreads();

    // preload this thread's am-mask values (one per key-frag column)
    int am8[8];
    #pragma unroll
    for (int j = 0; j < 8; ++j) am8[j] = sam[j * 16 + c];

    // ---- S = Q @ K^T (full 128-key tile) ----
    f32x4 accs[2][8];
    const f32x4 zz = {0.f, 0.f, 0.f, 0.f};
    #pragma unroll
    for (int i = 0; i < 2; ++i)
      #pragma unroll
      for (int j = 0; j < 8; ++j) accs[i][j] = zz;
    __builtin_amdgcn_s_setprio(1);
    #pragma unroll
    for (int ks = 0; ks < 2; ++ks) {
      const int kg = ks * 4 + g;
      short8 bfr[8];
      #pragma unroll
      for (int j = 0; j < 8; ++j) {
        const int jj = j * 16 + c;
        bfr[j] = *(const short8*)&Ks[(jj * 8 + (kg ^ (jj & 7))) * 8];
      }
      #pragma unroll
      for (int i = 0; i < 2; ++i)
        #pragma unroll
        for (int j = 0; j < 8; ++j)
          accs[i][j] = __builtin_amdgcn_mfma_f32_16x16x32_bf16(af[i][ks], bfr[j], accs[i][j], 0, 0, 0);
    }
    __builtin_amdgcn_s_setprio(0);

    // ---- two 64-key halves: mask + online softmax + P write + PV ----
    #pragma unroll
    for (int h2 = 0; h2 < 2; ++h2) {
      #pragma unroll
      for (int i = 0; i < 2; ++i) {
        #pragma unroll
        for (int p = 0; p < 4; ++p) {
          const int mloc = wave * 32 + i * 16 + g * 4 + p;
          const int qi = nc * CHUNK + mloc;
          float sv[4];
          float rmax = -1e30f;
          #pragma unroll
          for (int j = 0; j < 4; ++j) {
            const int jg = h2 * 4 + j;
            const int jj = jg * 16 + c;
            const int kj = ck * CHUNK + jj;
            const int diff = qi - kj;
            const bool ok = (diff <= 128) && (diff >= -128) && (kj != 0) && (am8[jg] > 0);
            const float s = ok ? accs[i][jg][p] * 0.125f : -1e9f;
            sv[j] = s;
            rmax = fmaxf(rmax, s);
          }
          rmax = fmaxf(rmax, __shfl_xor(rmax, 1));
          rmax = fmaxf(rmax, __shfl_xor(rmax, 2));
          rmax = fmaxf(rmax, __shfl_xor(rmax, 4));
          rmax = fmaxf(rmax, __shfl_xor(rmax, 8));
          const float mnew = fmaxf(mrow[i][p], rmax);
          const float corr = __expf(mrow[i][p] - mnew);
          float psum = 0.f;
          #pragma unroll
          for (int j = 0; j < 4; ++j) {
            const float pv = __expf(sv[j] - mnew);
            sv[j] = pv;
            psum += pv;
          }
          psum += __shfl_xor(psum, 1);
          psum += __shfl_xor(psum, 2);
          psum += __shfl_xor(psum, 4);
          psum += __shfl_xor(psum, 8);
          lrow[i][p] = lrow[i][p] * corr + psum;
          mrow[i][p] = mnew;
          #pragma unroll
          for (int j = 0; j < 4; ++j) acc_o[i][j][p] *= corr;
          #pragma unroll
          for (int j = 0; j < 4; ++j) {
            const int keyh = j * 16 + c;            // key within half
            const int kslot = keyh >> 3;            // 0..7
            Ps[mloc * 64 + ((kslot ^ (mloc & 7)) << 3) + (keyh & 7)] = f2b(sv[j]);
          }
        }
      }
      // wave-private P rows: drain LDS writes before cross-lane reads
      asm volatile("s_waitcnt lgkmcnt(0)" ::: "memory");

      __builtin_amdgcn_s_setprio(1);
      #pragma unroll
      for (int s2 = 0; s2 < 2; ++s2) {
        const int kslot = s2 * 4 + g;               // within half: 0..7
        const int kg2 = h2 * 8 + kslot;             // within tile: 0..15
        short8 pa[2], vb[4];
        #pragma unroll
        for (int i = 0; i < 2; ++i) {
          const int row = wave * 32 + i * 16 + c;
          pa[i] = *(const short8*)&Ps[row * 64 + ((kslot ^ (row & 7)) << 3)];
        }
        #pragma unroll
        for (int j = 0; j < 4; ++j) {
          const int n = j * 16 + c;
          vb[j] = *(const short8*)&Vt[n * 128 + ((kg2 ^ (n & 7)) << 3)];
        }
        #pragma unroll
        for (int i = 0; i < 2; ++i)
          #pragma unroll
          for (int j = 0; j < 4; ++j)
            acc_o[i][j] = __builtin_amdgcn_mfma_f32_16x16x32_bf16(pa[i], vb[j], acc_o[i][j], 0, 0, 0);
      }
      __builtin_amdgcn_s_setprio(0);
    }
  }

  #pragma unroll
  for (int i = 0; i < 2; ++i) {
    #pragma unroll
    for (int p = 0; p < 4; ++p) {
      const float rl = (lrow[i][p] > 0.f) ? 1.f / lrow[i][p] : 0.f;
      const int row = nc * CHUNK + wave * 32 + i * 16 + g * 4 + p;
      if (row == 0) continue;  // row 0 owned by the global path
      #pragma unroll
      for (int j = 0; j < 4; ++j)
        outb[(size_t)row * DMODEL + h * DHEAD + j * 16 + c] = f2b(acc_o[i][j][p] * rl);
    }
  }
}

// ================= global CLS combine: merge 8 segment partials -> row 0 =============
__global__ __launch_bounds__(64) void glb_attn_combine_kernel(
    const float* __restrict__ part, unsigned short* __restrict__ outb)
{
  const int h = blockIdx.x, d = threadIdx.x;
  float M = -1e30f;
  for (int g = 0; g < 8; ++g) M = fmaxf(M, part[(size_t)(h * 8 + g) * 66]);
  float L = 0.f, o = 0.f;
  for (int g = 0; g < 8; ++g) {
    const float* pr = part + (size_t)(h * 8 + g) * 66;
    const float cc = (pr[0] > -1e8f) ? __expf(pr[0] - M) : 0.f;
    L += pr[1] * cc;
    o += pr[2 + d] * cc;
  }
  outb[h * DHEAD + d] = f2b(o / L);
}

// ================= split-k GEMV (head MLP only) =================
__global__ __launch_bounds__(256) void gemv_partial_kernel(
    const float* __restrict__ xrow, const float* __restrict__ W, float* __restrict__ part)
{
  const int b = blockIdx.x, t = threadIdx.x;
  float s0 = 0.f, s1 = 0.f, s2 = 0.f;
  for (int kk = 0; kk < 48; ++kk) {
    const int k = b * 48 + kk;
    const float xv = xrow[k];
    const float* wr = W + (size_t)k * DMODEL;
    s0 = fmaf(xv, wr[t], s0);
    s1 = fmaf(xv, wr[t + 256], s1);
    s2 = fmaf(xv, wr[t + 512], s2);
  }
  part[b * DMODEL + t] = s0;
  part[b * DMODEL + t + 256] = s1;
  part[b * DMODEL + t + 512] = s2;
}

__global__ __launch_bounds__(256) void gemv_reduce_kernel(
    const float* __restrict__ part, const float* __restrict__ bias,
    float* __restrict__ y, int act)
{
  const int n = blockIdx.x * 256 + threadIdx.x;
  float s = bias[n];
  #pragma unroll
  for (int b = 0; b < 16; ++b) s += part[b * DMODEL + n];
  if (act) s = gelu_f(s);
  y[n] = s;
}

// ================= final head =================
__global__ __launch_bounds__(256) void head_final_kernel(
    const float* __restrict__ h2, const float* __restrict__ Wout,
    const float* __restrict__ bout, float* __restrict__ out)
{
  const int tid = threadIdx.x;
  __shared__ float red[4];
  float p = h2[tid]*Wout[tid] + h2[tid+256]*Wout[tid+256] + h2[tid+512]*Wout[tid+512];
  #pragma unroll
  for (int off = 32; off; off >>= 1) p += __shfl_down(p, off);
  if ((tid & 63) == 0) red[tid >> 6] = p;
  __syncthreads();
  if (tid == 0) {
    const float logit = red[0] + red[1] + red[2] + red[3] + bout[0];
    const float sig = 1.0f / (1.0f + expf(-logit));
    const unsigned int bits = __float_as_uint(sig);
    const unsigned int bf = (bits + 0x7FFFu + ((bits >> 16) & 1u)) >> 16;
    out[0] = __uint_as_float((bits & 0xFFFF0000u) | (bf & 0xFFFFu));
  }
}

extern "C" void kernel_launch(void* const* d_in, const int* in_sizes, int n_in,
                              void* d_out, int out_size, void* d_ws, size_t ws_size,
                              hipStream_t stream)
{
  const int*   ids  = (const int*)d_in[0];
  const int*   am   = (const int*)d_in[1];
  const float* wemb = (const float*)d_in[2];
  const float* pemb = (const float*)d_in[3];
  const float* emb_g = (const float*)d_in[4];
  const float* emb_b = (const float*)d_in[5];
  const float* Wq  = (const float*)d_in[6];
  const float* bq  = (const float*)d_in[7];
  const float* Wk  = (const float*)d_in[8];
  const float* bk  = (const float*)d_in[9];
  const float* Wv  = (const float*)d_in[10];
  const float* bv  = (const float*)d_in[11];
  const float* Wqg = (const float*)d_in[12];
  const float* bqg = (const float*)d_in[13];
  const float* Wkg = (const float*)d_in[14];
  const float* bkg = (const float*)d_in[15];
  const float* Wvg = (const float*)d_in[16];
  const float* bvg = (const float*)d_in[17];
  const float* Wo  = (const float*)d_in[18];
  const float* bo  = (const float*)d_in[19];
  const float* ln1g = (const float*)d_in[20];
  const float* ln1b = (const float*)d_in[21];
  const float* Wf1 = (const float*)d_in[22];
  const float* bf1 = (const float*)d_in[23];
  const float* Wf2 = (const float*)d_in[24];
  const float* bf2 = (const float*)d_in[25];
  const float* ln2g = (const float*)d_in[26];
  const float* ln2b = (const float*)d_in[27];
  const float* hng = (const float*)d_in[28];
  const float* hnb = (const float*)d_in[29];
  const float* W1  = (const float*)d_in[30];
  const float* b1  = (const float*)d_in[31];
  const float* W2  = (const float*)d_in[32];
  const float* b2  = (const float*)d_in[33];
  const float* Wout = (const float*)d_in[34];
  const float* bout = (const float*)d_in[35];

  char* wp = (char*)d_ws;
  auto alloc = [&](size_t bytes) -> void* {
    void* r = (void*)wp;
    wp += (bytes + 255) & ~(size_t)255;
    return r;
  };
  float*          x         = (float*)alloc((size_t)S_LEN * DMODEL * 4);
  unsigned short* xb        = (unsigned short*)alloc((size_t)S_LEN * DMODEL * 2);
  unsigned short* qkvb      = (unsigned short*)alloc((size_t)S_LEN * QKV_N * 2);
  unsigned short* attnb     = (unsigned short*)alloc((size_t)S_LEN * DMODEL * 2);
  unsigned short* tmpb      = (unsigned short*)alloc((size_t)S_LEN * FFDIM * 2);
  float*          tmpf      = (float*)alloc((size_t)S_LEN * DMODEL * 4);
  unsigned short* WqkvT_all = (unsigned short*)alloc((size_t)NLAYER * 5 * DD * 2);
  unsigned short* WoT_all   = (unsigned short*)alloc((size_t)NLAYER * DD * 2);
  unsigned short* Wf1T_all  = (unsigned short*)alloc((size_t)NLAYER * DF * 2);
  unsigned short* Wf2T_all  = (unsigned short*)alloc((size_t)NLAYER * DF * 2);
  float*          bqkv_all  = (float*)alloc((size_t)NLAYER * QKV_N * 4);
  float*          glbp      = (float*)alloc((size_t)NHEAD * 8 * 66 * 4);
  float*          gpart     = (float*)alloc((size_t)16 * DMODEL * 4);
  float*          hb        = (float*)alloc((size_t)3 * DMODEL * 4);

  // one-shot weight conversion for all layers (BW-bound, 2 launches)
  conv_all_dd_kernel<<<dim3(12, 12, 6 * NLAYER), 256, 0, stream>>>(
      Wq, Wk, Wv, Wkg, Wvg, Wo, bq, bk, bv, bkg, bvg, WqkvT_all, WoT_all, bqkv_all);
  conv_all_ffn_kernel<<<dim3(48, 12, 2 * NLAYER), 256, 0, stream>>>(
      Wf1, Wf2, Wf1T_all, Wf2T_all);

  embed_ln_kernel<<<S_LEN, 256, 0, stream>>>(ids, wemb, pemb, emb_g, emb_b, x, xb);

  for (int l = 0; l < NLAYER; ++l) {
    const size_t wdd = (size_t)l * DD;
    const size_t vd  = (size_t)l * DMODEL;
    const size_t vf  = (size_t)l * FFDIM;
    const unsigned short* WqkvT = WqkvT_all + (size_t)l * 5 * DD;
    const unsigned short* WoT   = WoT_all + wdd;
    const unsigned short* Wf1T  = Wf1T_all + (size_t)l * DF;
    const unsigned short* Wf2T  = Wf2T_all + (size_t)l * DF;
    const float* bqkv = bqkv_all + (size_t)l * QKV_N;

    // fused q|k|v|kg|vg projection: [2048,768] @ [768,3840] -> bf16
    gemm_mfma_kernel<128><<<dim3(16, 30), 256, 0, stream>>>(
        xb, WqkvT, bqkv, (const float*)nullptr, (float*)nullptr, qkvb, QKV_N, DMODEL, 0);

    // banded flash (192 blocks) + global CLS segments (96 blocks) in one launch
    attn_fused_kernel<<<dim3(NHEAD, NCHUNK + 8), 256, 0, stream>>>(
        qkvb, x, Wqg + wdd, bqg + vd, am, attnb, glbp);
    glb_attn_combine_kernel<<<NHEAD, 64, 0, stream>>>(glbp, attnb);

    // Wo projection + residual add fused
    gemm_mfma_kernel<64><<<dim3(32, 6), 256, 0, stream>>>(
        attnb, WoT, bo + vd, x, tmpf, (unsigned short*)nullptr, DMODEL, DMODEL, 0);
    ln_fused_kernel<<<S_LEN, 256, 0, stream>>>(tmpf, ln1g + vd, ln1b + vd, x, xb);

    gemm_mfma_kernel<128><<<dim3(16, 24), 256, 0, stream>>>(
        xb, Wf1T, bf1 + vf, (const float*)nullptr, (float*)nullptr, tmpb, FFDIM, DMODEL, 1);
    gemm_mfma_kernel<64><<<dim3(32, 6), 256, 0, stream>>>(
        tmpb, Wf2T, bf2 + vd, x, tmpf, (unsigned short*)nullptr, DMODEL, FFDIM, 0);
    ln_fused_kernel<<<S_LEN, 256, 0, stream>>>(tmpf, ln2g + vd, ln2b + vd, x, xb);
  }

  ln_vec_kernel<<<1, 256, 0, stream>>>(x, hng, hnb, hb);
  gemv_partial_kernel<<<16, 256, 0, stream>>>(hb, W1, gpart);
  gemv_reduce_kernel<<<3, 256, 0, stream>>>(gpart, b1, hb + DMODEL, 1);
  gemv_partial_kernel<<<16, 256, 0, stream>>>(hb + DMODEL, W2, gpart);
  gemv_reduce_kernel<<<3, 256, 0, stream>>>(gpart, b2, hb + 2 * DMODEL, 1);
  head_final_kernel<<<1, 256, 0, stream>>>(hb + 2 * DMODEL, Wout, bout, (float*)d_out);
}

// Round 9
// 1815.016 us; speedup vs baseline: 2.2389x; 1.3310x over previous
//
#include <hip/hip_runtime.h>
#include <math.h>

#define S_LEN 2048
#define DMODEL 768
#define NHEAD 12
#define DHEAD 64
#define NLAYER 12
#define FFDIM 3072
#define CHUNK 128
#define NCHUNK 16
#define QKV_N 3840   // q|k|v|kg|vg concatenated
#define DD (DMODEL * DMODEL)
#define DF (DMODEL * FFDIM)

typedef __attribute__((ext_vector_type(8))) short short8;
typedef __attribute__((ext_vector_type(4))) float f32x4;

__device__ __forceinline__ float gelu_f(float x) {
  return 0.5f * x * (1.0f + erff(x * 0.7071067811865476f));
}
// float -> bf16 bits (RNE)
__device__ __forceinline__ unsigned short f2b(float f) {
  unsigned int u = __float_as_uint(f);
  return (unsigned short)((u + 0x7FFFu + ((u >> 16) & 1u)) >> 16);
}
__device__ __forceinline__ float b2f(unsigned short u) {
  return __uint_as_float((unsigned int)u << 16);
}

// ================= embedding + LN =================
__global__ __launch_bounds__(256) void embed_ln_kernel(
    const int* __restrict__ ids, const float* __restrict__ wemb,
    const float* __restrict__ pemb, const float* __restrict__ g,
    const float* __restrict__ b, float* __restrict__ x, unsigned short* __restrict__ xb)
{
  const int s = blockIdx.x, tid = threadIdx.x;
  __shared__ float red[4];
  const size_t wbase = (size_t)ids[s] * DMODEL;
  const size_t pbase = (size_t)s * DMODEL;
  float y0 = wemb[wbase + tid]       + pemb[pbase + tid];
  float y1 = wemb[wbase + tid + 256] + pemb[pbase + tid + 256];
  float y2 = wemb[wbase + tid + 512] + pemb[pbase + tid + 512];
  float sum = y0 + y1 + y2;
  #pragma unroll
  for (int off = 32; off; off >>= 1) sum += __shfl_down(sum, off);
  if ((tid & 63) == 0) red[tid >> 6] = sum;
  __syncthreads();
  const float mean = (red[0] + red[1] + red[2] + red[3]) * (1.0f / 768.0f);
  __syncthreads();
  float d0 = y0 - mean, d1 = y1 - mean, d2 = y2 - mean;
  float vs = d0*d0 + d1*d1 + d2*d2;
  #pragma unroll
  for (int off = 32; off; off >>= 1) vs += __shfl_down(vs, off);
  if ((tid & 63) == 0) red[tid >> 6] = vs;
  __syncthreads();
  const float rstd = rsqrtf((red[0]+red[1]+red[2]+red[3]) * (1.0f/768.0f) + 1e-5f);
  float o0 = d0 * rstd * g[tid]       + b[tid];
  float o1 = d1 * rstd * g[tid + 256] + b[tid + 256];
  float o2 = d2 * rstd * g[tid + 512] + b[tid + 512];
  x[pbase + tid] = o0; x[pbase + tid + 256] = o1; x[pbase + tid + 512] = o2;
  xb[pbase + tid] = f2b(o0); xb[pbase + tid + 256] = f2b(o1); xb[pbase + tid + 512] = f2b(o2);
}

// ====== residual(x) + bias + sum of SK split-K partials -> LN -> x (f32) + xb (bf16) ==
template <int SK>
__global__ __launch_bounds__(256) void ln_reduce_kernel(
    const float* __restrict__ parts, const float* __restrict__ bias,
    const float* __restrict__ g, const float* __restrict__ b,
    float* __restrict__ x, unsigned short* __restrict__ xb)
{
  const int s = blockIdx.x, tid = threadIdx.x;
  __shared__ float red[4];
  const size_t base = (size_t)s * DMODEL;
  float y0 = x[base + tid]       + bias[tid];
  float y1 = x[base + tid + 256] + bias[tid + 256];
  float y2 = x[base + tid + 512] + bias[tid + 512];
  #pragma unroll
  for (int k = 0; k < SK; ++k) {
    const float* p = parts + (size_t)k * S_LEN * DMODEL + base;
    y0 += p[tid]; y1 += p[tid + 256]; y2 += p[tid + 512];
  }
  float sum = y0 + y1 + y2;
  #pragma unroll
  for (int off = 32; off; off >>= 1) sum += __shfl_down(sum, off);
  if ((tid & 63) == 0) red[tid >> 6] = sum;
  __syncthreads();
  const float mean = (red[0] + red[1] + red[2] + red[3]) * (1.0f / 768.0f);
  __syncthreads();
  float d0 = y0 - mean, d1 = y1 - mean, d2 = y2 - mean;
  float vs = d0*d0 + d1*d1 + d2*d2;
  #pragma unroll
  for (int off = 32; off; off >>= 1) vs += __shfl_down(vs, off);
  if ((tid & 63) == 0) red[tid >> 6] = vs;
  __syncthreads();
  const float rstd = rsqrtf((red[0]+red[1]+red[2]+red[3]) * (1.0f/768.0f) + 1e-5f);
  float o0 = d0 * rstd * g[tid]       + b[tid];
  float o1 = d1 * rstd * g[tid + 256] + b[tid + 256];
  float o2 = d2 * rstd * g[tid + 512] + b[tid + 512];
  x[base + tid] = o0; x[base + tid + 256] = o1; x[base + tid + 512] = o2;
  xb[base + tid] = f2b(o0); xb[base + tid + 256] = f2b(o1); xb[base + tid + 512] = f2b(o2);
}

__global__ __launch_bounds__(256) void ln_vec_kernel(
    const float* __restrict__ in, const float* __restrict__ g,
    const float* __restrict__ b, float* __restrict__ out)
{
  const int tid = threadIdx.x;
  __shared__ float red[4];
  float y0 = in[tid], y1 = in[tid + 256], y2 = in[tid + 512];
  float sum = y0 + y1 + y2;
  #pragma unroll
  for (int off = 32; off; off >>= 1) sum += __shfl_down(sum, off);
  if ((tid & 63) == 0) red[tid >> 6] = sum;
  __syncthreads();
  const float mean = (red[0] + red[1] + red[2] + red[3]) * (1.0f / 768.0f);
  __syncthreads();
  float d0 = y0 - mean, d1 = y1 - mean, d2 = y2 - mean;
  float vs = d0*d0 + d1*d1 + d2*d2;
  #pragma unroll
  for (int off = 32; off; off >>= 1) vs += __shfl_down(vs, off);
  if ((tid & 63) == 0) red[tid >> 6] = vs;
  __syncthreads();
  const float rstd = rsqrtf((red[0]+red[1]+red[2]+red[3]) * (1.0f/768.0f) + 1e-5f);
  out[tid]       = d0 * rstd * g[tid]       + b[tid];
  out[tid + 256] = d1 * rstd * g[tid + 256] + b[tid + 256];
  out[tid + 512] = d2 * rstd * g[tid + 512] + b[tid + 512];
}

// ====== one-shot weight convert+transpose, 64x64 tiles (f32 [K][N] -> bf16 [N][K]) ====
__global__ __launch_bounds__(256) void conv_all_dd_kernel(
    const float* __restrict__ Wq, const float* __restrict__ Wk, const float* __restrict__ Wv,
    const float* __restrict__ Wkg, const float* __restrict__ Wvg, const float* __restrict__ Wo,
    const float* __restrict__ bq, const float* __restrict__ bk, const float* __restrict__ bv,
    const float* __restrict__ bkg, const float* __restrict__ bvg,
    unsigned short* __restrict__ WqkvT, unsigned short* __restrict__ WoT,
    float* __restrict__ bqkv)
{
  const int z = blockIdx.z, layer = z / 6, mat = z % 6;
  const size_t off = (size_t)layer * DD;
  const float* src = (mat==0?Wq: mat==1?Wk: mat==2?Wv: mat==3?Wkg: mat==4?Wvg: Wo) + off;
  unsigned short* dst = (mat < 5)
      ? (WqkvT + (size_t)layer * 5 * DD + (size_t)mat * DD)
      : (WoT + off);
  __shared__ float tbuf[64][65];
  const int n0 = blockIdx.x * 64, k0 = blockIdx.y * 64;
  const int t = threadIdx.x;
  #pragma unroll
  for (int i = 0; i < 4; ++i) {
    const int idx = i * 256 + t;
    const int r = idx >> 4, c4 = (idx & 15) * 4;
    const float4 v = *(const float4*)&src[(size_t)(k0 + r) * DMODEL + n0 + c4];
    tbuf[r][c4] = v.x; tbuf[r][c4+1] = v.y; tbuf[r][c4+2] = v.z; tbuf[r][c4+3] = v.w;
  }
  __syncthreads();
  const int n = t >> 2, seg = (t & 3) * 16;
  unsigned short o[16];
  #pragma unroll
  for (int i = 0; i < 16; ++i) o[i] = f2b(tbuf[seg + i][n]);
  unsigned short* dp = &dst[(size_t)(n0 + n) * DMODEL + k0 + seg];
  *(short8*)dp = *(const short8*)&o[0];
  *(short8*)(dp + 8) = *(const short8*)&o[8];
  if (mat < 5 && blockIdx.x == 0 && blockIdx.y == 0) {
    const float* bs = (mat==0?bq: mat==1?bk: mat==2?bv: mat==3?bkg: bvg) + (size_t)layer * DMODEL;
    for (int i = t; i < DMODEL; i += 256) bqkv[(size_t)layer * QKV_N + mat * DMODEL + i] = bs[i];
  }
}

__global__ __launch_bounds__(256) void conv_all_ffn_kernel(
    const float* __restrict__ Wf1, const float* __restrict__ Wf2,
    unsigned short* __restrict__ Wf1T, unsigned short* __restrict__ Wf2T)
{
  const int z = blockIdx.z, layer = z / 2, which = z % 2;
  __shared__ float tbuf[64][65];
  const float* src; unsigned short* dst; int Kd, Nd, n0, k0;
  if (which == 0) { src = Wf1 + (size_t)layer * DF; dst = Wf1T + (size_t)layer * DF;
                    Kd = DMODEL; Nd = FFDIM; n0 = blockIdx.x * 64; k0 = blockIdx.y * 64; }
  else            { src = Wf2 + (size_t)layer * DF; dst = Wf2T + (size_t)layer * DF;
                    Kd = FFDIM; Nd = DMODEL; n0 = blockIdx.y * 64; k0 = blockIdx.x * 64; }
  const int t = threadIdx.x;
  #pragma unroll
  for (int i = 0; i < 4; ++i) {
    const int idx = i * 256 + t;
    const int r = idx >> 4, c4 = (idx & 15) * 4;
    const float4 v = *(const float4*)&src[(size_t)(k0 + r) * Nd + n0 + c4];
    tbuf[r][c4] = v.x; tbuf[r][c4+1] = v.y; tbuf[r][c4+2] = v.z; tbuf[r][c4+3] = v.w;
  }
  __syncthreads();
  const int n = t >> 2, seg = (t & 3) * 16;
  unsigned short o[16];
  #pragma unroll
  for (int i = 0; i < 16; ++i) o[i] = f2b(tbuf[seg + i][n]);
  unsigned short* dp = &dst[(size_t)(n0 + n) * Kd + k0 + seg];
  *(short8*)dp = *(const short8*)&o[0];
  *(short8*)(dp + 8) = *(const short8*)&o[8];
}

// ======= bf16 MFMA GEMM (BMx128 tile, BK=64, swizzled LDS, XCD swizzle, residual) =====
template <int BM>
__global__ __launch_bounds__(256) void gemm_mfma_kernel(
    const unsigned short* __restrict__ A, const unsigned short* __restrict__ Bt,
    const float* __restrict__ bias, const float* __restrict__ Res,
    float* __restrict__ Cf, unsigned short* __restrict__ Cb, int N, int K, int act)
{
  constexpr int ASLOTS = BM * 8;
  constexpr int MI = BM / 32;
  __shared__ unsigned short As[ASLOTS * 8];
  __shared__ unsigned short Bs[8192];
  const int tid = threadIdx.x, wave = tid >> 6, lane = tid & 63;
  const int gx = gridDim.x, nwg = gx * gridDim.y;
  int flat = blockIdx.y * gx + blockIdx.x;
  flat = (flat & 7) * (nwg >> 3) + (flat >> 3);
  const int bm = (flat % gx) * BM, bn = (flat / gx) * 128;
  const int wr = (wave >> 1) * (BM / 2), wc = (wave & 1) * 64;
  f32x4 acc[MI][4];
  const f32x4 zz = {0.f, 0.f, 0.f, 0.f};
  #pragma unroll
  for (int i = 0; i < MI; ++i)
    #pragma unroll
    for (int j = 0; j < 4; ++j) acc[i][j] = zz;

  for (int k0 = 0; k0 < K; k0 += 64) {
    #pragma unroll
    for (int it = 0; it < ASLOTS / 256; ++it) {
      const int s = it * 256 + tid;
      const int mr = s >> 3;
      const int kg = (s & 7) ^ (mr & 7);
      const unsigned short* src = A + (size_t)(bm + mr) * K + k0 + kg * 8;
      __builtin_amdgcn_global_load_lds(
          (const __attribute__((address_space(1))) void*)src,
          (__attribute__((address_space(3))) void*)&As[(size_t)(it * 256 + wave * 64) * 8], 16, 0, 0);
    }
    #pragma unroll
    for (int it = 0; it < 4; ++it) {
      const int s = it * 256 + tid;
      const int mr = s >> 3;
      const int kg = (s & 7) ^ (mr & 7);
      const unsigned short* src = Bt + (size_t)(bn + mr) * K + k0 + kg * 8;
      __builtin_amdgcn_global_load_lds(
          (const __attribute__((address_space(1))) void*)src,
          (__attribute__((address_space(3))) void*)&Bs[(size_t)(it * 256 + wave * 64) * 8], 16, 0, 0);
    }
    __syncthreads();
    #pragma unroll
    for (int ks = 0; ks < 2; ++ks) {
      const int kg = ks * 4 + (lane >> 4);
      short8 af[MI], bfr[4];
      #pragma unroll
      for (int i = 0; i < MI; ++i) {
        const int m = wr + i * 16 + (lane & 15);
        af[i] = *(const short8*)&As[(m * 8 + (kg ^ (m & 7))) * 8];
      }
      #pragma unroll
      for (int j = 0; j < 4; ++j) {
        const int n = wc + j * 16 + (lane & 15);
        bfr[j] = *(const short8*)&Bs[(n * 8 + (kg ^ (n & 7))) * 8];
      }
      #pragma unroll
      for (int i = 0; i < MI; ++i)
        #pragma unroll
        for (int j = 0; j < 4; ++j)
          acc[i][j] = __builtin_amdgcn_mfma_f32_16x16x32_bf16(af[i], bfr[j], acc[i][j], 0, 0, 0);
    }
    __syncthreads();
  }

  const int lr = (lane >> 4) * 4, lc = lane & 15;
  #pragma unroll
  for (int i = 0; i < MI; ++i) {
    #pragma unroll
    for (int j = 0; j < 4; ++j) {
      const int n = bn + wc + j * 16 + lc;
      const float bv = bias[n];
      #pragma unroll
      for (int p = 0; p < 4; ++p) {
        const int m = bm + wr + i * 16 + lr + p;
        float val = acc[i][j][p] + bv;
        if (Res) val += Res[(size_t)m * N + n];
        if (act) val = gelu_f(val);
        if (Cf) Cf[(size_t)m * N + n] = val;
        if (Cb) Cb[(size_t)m * N + n] = f2b(val);
      }
    }
  }
}

// ======= split-K bf16 MFMA GEMM partial: Cp[sk][M][N] += A @ Bt^T over K-slice ========
template <int BM, int SK>
__global__ __launch_bounds__(256) void gemm_splitk_kernel(
    const unsigned short* __restrict__ A, const unsigned short* __restrict__ Bt,
    float* __restrict__ Cp, int N, int K)
{
  constexpr int ASLOTS = BM * 8;
  constexpr int MI = BM / 32;
  __shared__ unsigned short As[ASLOTS * 8];
  __shared__ unsigned short Bs[8192];
  const int tid = threadIdx.x, wave = tid >> 6, lane = tid & 63;
  const int gx = gridDim.x, nwg = gx * gridDim.y;
  int flat = blockIdx.y * gx + blockIdx.x;
  flat = (flat & 7) * (nwg >> 3) + (flat >> 3);
  const int bm = (flat % gx) * BM, bn = (flat / gx) * 128;
  const int sk = blockIdx.z;
  const int KS = K / SK;
  const int kbeg = sk * KS;
  const int wr = (wave >> 1) * (BM / 2), wc = (wave & 1) * 64;
  f32x4 acc[MI][4];
  const f32x4 zz = {0.f, 0.f, 0.f, 0.f};
  #pragma unroll
  for (int i = 0; i < MI; ++i)
    #pragma unroll
    for (int j = 0; j < 4; ++j) acc[i][j] = zz;

  for (int k0 = kbeg; k0 < kbeg + KS; k0 += 64) {
    #pragma unroll
    for (int it = 0; it < ASLOTS / 256; ++it) {
      const int s = it * 256 + tid;
      const int mr = s >> 3;
      const int kg = (s & 7) ^ (mr & 7);
      const unsigned short* src = A + (size_t)(bm + mr) * K + k0 + kg * 8;
      __builtin_amdgcn_global_load_lds(
          (const __attribute__((address_space(1))) void*)src,
          (__attribute__((address_space(3))) void*)&As[(size_t)(it * 256 + wave * 64) * 8], 16, 0, 0);
    }
    #pragma unroll
    for (int it = 0; it < 4; ++it) {
      const int s = it * 256 + tid;
      const int mr = s >> 3;
      const int kg = (s & 7) ^ (mr & 7);
      const unsigned short* src = Bt + (size_t)(bn + mr) * K + k0 + kg * 8;
      __builtin_amdgcn_global_load_lds(
          (const __attribute__((address_space(1))) void*)src,
          (__attribute__((address_space(3))) void*)&Bs[(size_t)(it * 256 + wave * 64) * 8], 16, 0, 0);
    }
    __syncthreads();
    #pragma unroll
    for (int ks = 0; ks < 2; ++ks) {
      const int kg = ks * 4 + (lane >> 4);
      short8 af[MI], bfr[4];
      #pragma unroll
      for (int i = 0; i < MI; ++i) {
        const int m = wr + i * 16 + (lane & 15);
        af[i] = *(const short8*)&As[(m * 8 + (kg ^ (m & 7))) * 8];
      }
      #pragma unroll
      for (int j = 0; j < 4; ++j) {
        const int n = wc + j * 16 + (lane & 15);
        bfr[j] = *(const short8*)&Bs[(n * 8 + (kg ^ (n & 7))) * 8];
      }
      #pragma unroll
      for (int i = 0; i < MI; ++i)
        #pragma unroll
        for (int j = 0; j < 4; ++j)
          acc[i][j] = __builtin_amdgcn_mfma_f32_16x16x32_bf16(af[i], bfr[j], acc[i][j], 0, 0, 0);
    }
    __syncthreads();
  }

  float* Co = Cp + (size_t)sk * S_LEN * DMODEL;
  const int lr = (lane >> 4) * 4, lc = lane & 15;
  #pragma unroll
  for (int i = 0; i < MI; ++i) {
    #pragma unroll
    for (int j = 0; j < 4; ++j) {
      const int n = bn + wc + j * 16 + lc;
      #pragma unroll
      for (int p = 0; p < 4; ++p) {
        const int m = bm + wr + i * 16 + lr + p;
        Co[(size_t)m * N + n] = acc[i][j][p];
      }
    }
  }
}

// == fused attention: banded flash (y<16) + global CLS row 8-way segments (y in 16..23) ==
// LDS: Ks 16K | Vt 16K | Ps 16K (64-key half-tile) | smcls/sv0/sam -> 50.4 KB total
__global__ __launch_bounds__(256) void attn_fused_kernel(
    const unsigned short* __restrict__ qkvb, const float* __restrict__ xf,
    const float* __restrict__ Wqg, const float* __restrict__ bqg,
    const int* __restrict__ am, unsigned short* __restrict__ outb,
    float* __restrict__ glbp)
{
  __shared__ __align__(16) unsigned char smem[50432];
  const int h = blockIdx.x, tid = threadIdx.x;

  if (blockIdx.y >= NCHUNK) {
    // ---------------- global CLS query row: segment g of 256 keys ----------------
    const int g = blockIdx.y - NCHUNK;    // 0..7
    float* sc  = (float*)smem;            // 256 f32
    float* qs  = (float*)(smem + 1024);   // 64
    float* red = (float*)(smem + 1280);   // 4
    float* pqg = (float*)(smem + 1296);   // 4*64
    float* pb  = (float*)(smem + 2320);   // 32*64 f32 (8 KB)
    const int d = tid & 63, grp = tid >> 6;
    // qg0 slice for this head (redundant per segment block; cheap, concurrent)
    {
      float p = 0.f;
      const float* wcol = Wqg + (size_t)(grp * 192) * DMODEL + h * DHEAD + d;
      #pragma unroll 4
      for (int k = 0; k < 192; ++k)
        p = fmaf(xf[grp * 192 + k], wcol[(size_t)k * DMODEL], p);
      pqg[grp * 64 + d] = p;
    }
    __syncthreads();
    if (tid < 64)
      qs[tid] = (pqg[tid] + pqg[64 + tid] + pqg[128 + tid] + pqg[192 + tid]
                 + bqg[h * DHEAD + tid]) * 0.125f;
    __syncthreads();
    const unsigned short* kg = qkvb + 3 * DMODEL + h * DHEAD;
    const unsigned short* vg = qkvb + 4 * DMODEL + h * DHEAD;
    const int s0 = g * 256 + tid;
    float dd = 0.f;
    {
      const unsigned short* kr = kg + (size_t)s0 * QKV_N;
      #pragma unroll
      for (int d0 = 0; d0 < DHEAD; d0 += 8) {
        const short8 k8 = *(const short8*)(kr + d0);
        #pragma unroll
        for (int e = 0; e < 8; ++e) dd += qs[d0 + e] * b2f((unsigned short)k8[e]);
      }
    }
    const float mysc = (am[s0] > 0) ? dd : -1e9f;
    float mx = mysc;
    #pragma unroll
    for (int off = 32; off; off >>= 1) mx = fmaxf(mx, __shfl_down(mx, off));
    if ((tid & 63) == 0) red[tid >> 6] = mx;
    __syncthreads();
    mx = fmaxf(fmaxf(red[0], red[1]), fmaxf(red[2], red[3]));
    __syncthreads();
    const float e = __expf(mysc - mx);
    sc[tid] = e;
    float sum = e;
    #pragma unroll
    for (int off = 32; off; off >>= 1) sum += __shfl_down(sum, off);
    if ((tid & 63) == 0) red[tid >> 6] = sum;
    __syncthreads();
    const float lsum = red[0] + red[1] + red[2] + red[3];
    // ---- PV over this segment (unnormalized): 32-key x 8-dim split, short8 loads ----
    const int d8 = (tid & 7) * 8, kgrp = tid >> 3;
    float a8[8] = {};
    #pragma unroll
    for (int ii = 0; ii < 8; ++ii) {
      const int loc = kgrp + ii * 32;
      const float p = sc[loc];
      const short8 v8 = *(const short8*)(vg + (size_t)(g * 256 + loc) * QKV_N + d8);
      #pragma unroll
      for (int ee = 0; ee < 8; ++ee) a8[ee] = fmaf(p, b2f((unsigned short)v8[ee]), a8[ee]);
    }
    #pragma unroll
    for (int ee = 0; ee < 8; ++ee) pb[kgrp * 64 + d8 + ee] = a8[ee];
    __syncthreads();
    float* pr = glbp + (size_t)(h * 8 + g) * 66;
    if (tid < 64) {
      float o = 0.f;
      #pragma unroll
      for (int k = 0; k < 32; ++k) o += pb[k * 64 + tid];
      pr[2 + tid] = o;
    }
    if (tid == 0) { pr[0] = mx; pr[1] = lsum; }
    return;
  }

  // ---------------- banded sliding-window flash ----------------
  const int nc = blockIdx.y;
  const int wave = tid >> 6, lane = tid & 63;
  const int c = lane & 15, g = lane >> 4;
  unsigned short* Ks = (unsigned short*)smem;             // 16 KB
  unsigned short* Vt = (unsigned short*)(smem + 16384);   // 16 KB
  unsigned short* Ps = (unsigned short*)(smem + 32768);   // 16 KB ([128 rows][64 keys])
  float* smcls = (float*)(smem + 49152);                  // 512 B
  float* sv0   = (float*)(smem + 49664);                  // 256 B
  int*   sam   = (int*)(smem + 49920);                    // 512 B

  if (tid < 64) sv0[tid] = b2f(qkvb[2 * DMODEL + h * DHEAD + tid]);
  if (tid < 128) {
    const int qrow = nc * CHUNK + tid;
    const unsigned short* qp = qkvb + (size_t)qrow * QKV_N + h * DHEAD;
    const unsigned short* k0 = qkvb + DMODEL + h * DHEAD;
    float d = 0.f;
    #pragma unroll
    for (int dd = 0; dd < 64; dd += 8) {
      const short8 a8 = *(const short8*)(qp + dd);
      const short8 b8 = *(const short8*)(k0 + dd);
      #pragma unroll
      for (int e = 0; e < 8; ++e)
        d += b2f((unsigned short)a8[e]) * b2f((unsigned short)b8[e]);
    }
    smcls[tid] = (am[0] > 0) ? d * 0.125f : -1e9f;
  }

  short8 af[2][2];
  #pragma unroll
  for (int i = 0; i < 2; ++i)
    #pragma unroll
    for (int ks = 0; ks < 2; ++ks) {
      const int qrow = nc * CHUNK + wave * 32 + i * 16 + c;
      af[i][ks] = *(const short8*)(qkvb + (size_t)qrow * QKV_N + h * DHEAD + (ks * 4 + g) * 8);
    }

  __syncthreads();

  float mrow[2][4], lrow[2][4];
  f32x4 acc_o[2][4];
  #pragma unroll
  for (int i = 0; i < 2; ++i)
    #pragma unroll
    for (int p = 0; p < 4; ++p) {
      mrow[i][p] = smcls[wave * 32 + i * 16 + g * 4 + p];
      lrow[i][p] = 1.f;
    }
  #pragma unroll
  for (int i = 0; i < 2; ++i)
    #pragma unroll
    for (int j = 0; j < 4; ++j) {
      const float v0 = sv0[j * 16 + c];
      acc_o[i][j][0] = v0; acc_o[i][j][1] = v0; acc_o[i][j][2] = v0; acc_o[i][j][3] = v0;
    }

  for (int kci = 0; kci < 3; ++kci) {
    const int ck = nc - 1 + kci;
    if (ck < 0 || ck > 15) continue;
    __syncthreads();

    #pragma unroll
    for (int it = 0; it < 4; ++it) {
      const int sidx = it * 256 + tid;
      const int mr = sidx >> 3;
      const int kg = (sidx & 7) ^ (mr & 7);
      const unsigned short* src = qkvb + (size_t)(ck * CHUNK + mr) * QKV_N + DMODEL + h * DHEAD + kg * 8;
      __builtin_amdgcn_global_load_lds(
          (const __attribute__((address_space(1))) void*)src,
          (__attribute__((address_space(3))) void*)&Ks[(size_t)(it * 256 + wave * 64) * 8], 16, 0, 0);
    }
    {
      const int kp = tid & 63, dh = tid >> 6;
      const unsigned short* v0p = qkvb + (size_t)(ck * CHUNK + 2 * kp) * QKV_N + 2 * DMODEL + h * DHEAD + dh * 16;
      const short8 a0 = *(const short8*)(v0p);
      const short8 a1 = *(const short8*)(v0p + 8);
      const short8 b0 = *(const short8*)(v0p + QKV_N);
      const short8 b1 = *(const short8*)(v0p + QKV_N + 8);
      #pragma unroll
      for (int dd = 0; dd < 16; ++dd) {
        const int dim = dh * 16 + dd;
        const unsigned short lo = (unsigned short)(dd < 8 ? a0[dd] : a1[dd - 8]);
        const unsigned short hi = (unsigned short)(dd < 8 ? b0[dd] : b1[dd - 8]);
        const unsigned int w = (unsigned int)lo | ((unsigned int)hi << 16);
        const int si = dim * 128 + (((kp >> 2) ^ (dim & 7)) << 3) + ((kp & 3) << 1);
        *(unsigned int*)&Vt[si] = w;
      }
    }
    if (tid < 128) sam[tid] = am[ck * CHUNK + tid];
    __syncthreads();

    // preload this thread's am-mask values (one per key-frag column)
    int am8[8];
    #pragma unroll
    for (int j = 0; j < 8; ++j) am8[j] = sam[j * 16 + c];

    // ---- S = Q @ K^T (full 128-key tile) ----
    f32x4 accs[2][8];
    const f32x4 zz = {0.f, 0.f, 0.f, 0.f};
    #pragma unroll
    for (int i = 0; i < 2; ++i)
      #pragma unroll
      for (int j = 0; j < 8; ++j) accs[i][j] = zz;
    __builtin_amdgcn_s_setprio(1);
    #pragma unroll
    for (int ks = 0; ks < 2; ++ks) {
      const int kg = ks * 4 + g;
      short8 bfr[8];
      #pragma unroll
      for (int j = 0; j < 8; ++j) {
        const int jj = j * 16 + c;
        bfr[j] = *(const short8*)&Ks[(jj * 8 + (kg ^ (jj & 7))) * 8];
      }
      #pragma unroll
      for (int i = 0; i < 2; ++i)
        #pragma unroll
        for (int j = 0; j < 8; ++j)
          accs[i][j] = __builtin_amdgcn_mfma_f32_16x16x32_bf16(af[i][ks], bfr[j], accs[i][j], 0, 0, 0);
    }
    __builtin_amdgcn_s_setprio(0);

    // ---- two 64-key halves: mask + online softmax + P write + PV ----
    #pragma unroll
    for (int h2 = 0; h2 < 2; ++h2) {
      #pragma unroll
      for (int i = 0; i < 2; ++i) {
        #pragma unroll
        for (int p = 0; p < 4; ++p) {
          const int mloc = wave * 32 + i * 16 + g * 4 + p;
          const int qi = nc * CHUNK + mloc;
          float sv[4];
          float rmax = -1e30f;
          #pragma unroll
          for (int j = 0; j < 4; ++j) {
            const int jg = h2 * 4 + j;
            const int jj = jg * 16 + c;
            const int kj = ck * CHUNK + jj;
            const int diff = qi - kj;
            const bool ok = (diff <= 128) && (diff >= -128) && (kj != 0) && (am8[jg] > 0);
            const float s = ok ? accs[i][jg][p] * 0.125f : -1e9f;
            sv[j] = s;
            rmax = fmaxf(rmax, s);
          }
          rmax = fmaxf(rmax, __shfl_xor(rmax, 1));
          rmax = fmaxf(rmax, __shfl_xor(rmax, 2));
          rmax = fmaxf(rmax, __shfl_xor(rmax, 4));
          rmax = fmaxf(rmax, __shfl_xor(rmax, 8));
          const float mnew = fmaxf(mrow[i][p], rmax);
          const float corr = __expf(mrow[i][p] - mnew);
          float psum = 0.f;
          #pragma unroll
          for (int j = 0; j < 4; ++j) {
            const float pv = __expf(sv[j] - mnew);
            sv[j] = pv;
            psum += pv;
          }
          psum += __shfl_xor(psum, 1);
          psum += __shfl_xor(psum, 2);
          psum += __shfl_xor(psum, 4);
          psum += __shfl_xor(psum, 8);
          lrow[i][p] = lrow[i][p] * corr + psum;
          mrow[i][p] = mnew;
          #pragma unroll
          for (int j = 0; j < 4; ++j) acc_o[i][j][p] *= corr;
          #pragma unroll
          for (int j = 0; j < 4; ++j) {
            const int keyh = j * 16 + c;            // key within half
            const int kslot = keyh >> 3;            // 0..7
            Ps[mloc * 64 + ((kslot ^ (mloc & 7)) << 3) + (keyh & 7)] = f2b(sv[j]);
          }
        }
      }
      // wave-private P rows: drain LDS writes before cross-lane reads
      asm volatile("s_waitcnt lgkmcnt(0)" ::: "memory");

      __builtin_amdgcn_s_setprio(1);
      #pragma unroll
      for (int s2 = 0; s2 < 2; ++s2) {
        const int kslot = s2 * 4 + g;               // within half: 0..7
        const int kg2 = h2 * 8 + kslot;             // within tile: 0..15
        short8 pa[2], vb[4];
        #pragma unroll
        for (int i = 0; i < 2; ++i) {
          const int row = wave * 32 + i * 16 + c;
          pa[i] = *(const short8*)&Ps[row * 64 + ((kslot ^ (row & 7)) << 3)];
        }
        #pragma unroll
        for (int j = 0; j < 4; ++j) {
          const int n = j * 16 + c;
          vb[j] = *(const short8*)&Vt[n * 128 + ((kg2 ^ (n & 7)) << 3)];
        }
        #pragma unroll
        for (int i = 0; i < 2; ++i)
          #pragma unroll
          for (int j = 0; j < 4; ++j)
            acc_o[i][j] = __builtin_amdgcn_mfma_f32_16x16x32_bf16(pa[i], vb[j], acc_o[i][j], 0, 0, 0);
      }
      __builtin_amdgcn_s_setprio(0);
    }
  }

  #pragma unroll
  for (int i = 0; i < 2; ++i) {
    #pragma unroll
    for (int p = 0; p < 4; ++p) {
      const float rl = (lrow[i][p] > 0.f) ? 1.f / lrow[i][p] : 0.f;
      const int row = nc * CHUNK + wave * 32 + i * 16 + g * 4 + p;
      if (row == 0) continue;  // row 0 owned by the global path
      #pragma unroll
      for (int j = 0; j < 4; ++j)
        outb[(size_t)row * DMODEL + h * DHEAD + j * 16 + c] = f2b(acc_o[i][j][p] * rl);
    }
  }
}

// ================= global CLS combine: merge 8 segment partials -> row 0 =============
__global__ __launch_bounds__(64) void glb_attn_combine_kernel(
    const float* __restrict__ part, unsigned short* __restrict__ outb)
{
  const int h = blockIdx.x, d = threadIdx.x;
  float M = -1e30f;
  for (int g = 0; g < 8; ++g) M = fmaxf(M, part[(size_t)(h * 8 + g) * 66]);
  float L = 0.f, o = 0.f;
  for (int g = 0; g < 8; ++g) {
    const float* pr = part + (size_t)(h * 8 + g) * 66;
    const float cc = (pr[0] > -1e8f) ? __expf(pr[0] - M) : 0.f;
    L += pr[1] * cc;
    o += pr[2 + d] * cc;
  }
  outb[h * DHEAD + d] = f2b(o / L);
}

// ================= split-k GEMV (head MLP only) =================
__global__ __launch_bounds__(256) void gemv_partial_kernel(
    const float* __restrict__ xrow, const float* __restrict__ W, float* __restrict__ part)
{
  const int b = blockIdx.x, t = threadIdx.x;
  float s0 = 0.f, s1 = 0.f, s2 = 0.f;
  for (int kk = 0; kk < 48; ++kk) {
    const int k = b * 48 + kk;
    const float xv = xrow[k];
    const float* wr = W + (size_t)k * DMODEL;
    s0 = fmaf(xv, wr[t], s0);
    s1 = fmaf(xv, wr[t + 256], s1);
    s2 = fmaf(xv, wr[t + 512], s2);
  }
  part[b * DMODEL + t] = s0;
  part[b * DMODEL + t + 256] = s1;
  part[b * DMODEL + t + 512] = s2;
}

__global__ __launch_bounds__(256) void gemv_reduce_kernel(
    const float* __restrict__ part, const float* __restrict__ bias,
    float* __restrict__ y, int act)
{
  const int n = blockIdx.x * 256 + threadIdx.x;
  float s = bias[n];
  #pragma unroll
  for (int b = 0; b < 16; ++b) s += part[b * DMODEL + n];
  if (act) s = gelu_f(s);
  y[n] = s;
}

// ================= final head =================
__global__ __launch_bounds__(256) void head_final_kernel(
    const float* __restrict__ h2, const float* __restrict__ Wout,
    const float* __restrict__ bout, float* __restrict__ out)
{
  const int tid = threadIdx.x;
  __shared__ float red[4];
  float p = h2[tid]*Wout[tid] + h2[tid+256]*Wout[tid+256] + h2[tid+512]*Wout[tid+512];
  #pragma unroll
  for (int off = 32; off; off >>= 1) p += __shfl_down(p, off);
  if ((tid & 63) == 0) red[tid >> 6] = p;
  __syncthreads();
  if (tid == 0) {
    const float logit = red[0] + red[1] + red[2] + red[3] + bout[0];
    const float sig = 1.0f / (1.0f + expf(-logit));
    const unsigned int bits = __float_as_uint(sig);
    const unsigned int bf = (bits + 0x7FFFu + ((bits >> 16) & 1u)) >> 16;
    out[0] = __uint_as_float((bits & 0xFFFF0000u) | (bf & 0xFFFFu));
  }
}

extern "C" void kernel_launch(void* const* d_in, const int* in_sizes, int n_in,
                              void* d_out, int out_size, void* d_ws, size_t ws_size,
                              hipStream_t stream)
{
  const int*   ids  = (const int*)d_in[0];
  const int*   am   = (const int*)d_in[1];
  const float* wemb = (const float*)d_in[2];
  const float* pemb = (const float*)d_in[3];
  const float* emb_g = (const float*)d_in[4];
  const float* emb_b = (const float*)d_in[5];
  const float* Wq  = (const float*)d_in[6];
  const float* bq  = (const float*)d_in[7];
  const float* Wk  = (const float*)d_in[8];
  const float* bk  = (const float*)d_in[9];
  const float* Wv  = (const float*)d_in[10];
  const float* bv  = (const float*)d_in[11];
  const float* Wqg = (const float*)d_in[12];
  const float* bqg = (const float*)d_in[13];
  const float* Wkg = (const float*)d_in[14];
  const float* bkg = (const float*)d_in[15];
  const float* Wvg = (const float*)d_in[16];
  const float* bvg = (const float*)d_in[17];
  const float* Wo  = (const float*)d_in[18];
  const float* bo  = (const float*)d_in[19];
  const float* ln1g = (const float*)d_in[20];
  const float* ln1b = (const float*)d_in[21];
  const float* Wf1 = (const float*)d_in[22];
  const float* bf1 = (const float*)d_in[23];
  const float* Wf2 = (const float*)d_in[24];
  const float* bf2 = (const float*)d_in[25];
  const float* ln2g = (const float*)d_in[26];
  const float* ln2b = (const float*)d_in[27];
  const float* hng = (const float*)d_in[28];
  const float* hnb = (const float*)d_in[29];
  const float* W1  = (const float*)d_in[30];
  const float* b1  = (const float*)d_in[31];
  const float* W2  = (const float*)d_in[32];
  const float* b2  = (const float*)d_in[33];
  const float* Wout = (const float*)d_in[34];
  const float* bout = (const float*)d_in[35];

  char* wp = (char*)d_ws;
  auto alloc = [&](size_t bytes) -> void* {
    void* r = (void*)wp;
    wp += (bytes + 255) & ~(size_t)255;
    return r;
  };
  float*          x         = (float*)alloc((size_t)S_LEN * DMODEL * 4);
  unsigned short* xb        = (unsigned short*)alloc((size_t)S_LEN * DMODEL * 2);
  unsigned short* qkvb      = (unsigned short*)alloc((size_t)S_LEN * QKV_N * 2);
  unsigned short* attnb     = (unsigned short*)alloc((size_t)S_LEN * DMODEL * 2);
  unsigned short* tmpb      = (unsigned short*)alloc((size_t)S_LEN * FFDIM * 2);
  float*          parts     = (float*)alloc((size_t)4 * S_LEN * DMODEL * 4);
  unsigned short* WqkvT_all = (unsigned short*)alloc((size_t)NLAYER * 5 * DD * 2);
  unsigned short* WoT_all   = (unsigned short*)alloc((size_t)NLAYER * DD * 2);
  unsigned short* Wf1T_all  = (unsigned short*)alloc((size_t)NLAYER * DF * 2);
  unsigned short* Wf2T_all  = (unsigned short*)alloc((size_t)NLAYER * DF * 2);
  float*          bqkv_all  = (float*)alloc((size_t)NLAYER * QKV_N * 4);
  float*          glbp      = (float*)alloc((size_t)NHEAD * 8 * 66 * 4);
  float*          gpart     = (float*)alloc((size_t)16 * DMODEL * 4);
  float*          hb        = (float*)alloc((size_t)3 * DMODEL * 4);

  // one-shot weight conversion for all layers (BW-bound, 2 launches)
  conv_all_dd_kernel<<<dim3(12, 12, 6 * NLAYER), 256, 0, stream>>>(
      Wq, Wk, Wv, Wkg, Wvg, Wo, bq, bk, bv, bkg, bvg, WqkvT_all, WoT_all, bqkv_all);
  conv_all_ffn_kernel<<<dim3(48, 12, 2 * NLAYER), 256, 0, stream>>>(
      Wf1, Wf2, Wf1T_all, Wf2T_all);

  embed_ln_kernel<<<S_LEN, 256, 0, stream>>>(ids, wemb, pemb, emb_g, emb_b, x, xb);

  for (int l = 0; l < NLAYER; ++l) {
    const size_t wdd = (size_t)l * DD;
    const size_t vd  = (size_t)l * DMODEL;
    const size_t vf  = (size_t)l * FFDIM;
    const unsigned short* WqkvT = WqkvT_all + (size_t)l * 5 * DD;
    const unsigned short* WoT   = WoT_all + wdd;
    const unsigned short* Wf1T  = Wf1T_all + (size_t)l * DF;
    const unsigned short* Wf2T  = Wf2T_all + (size_t)l * DF;
    const float* bqkv = bqkv_all + (size_t)l * QKV_N;

    // fused q|k|v|kg|vg projection: [2048,768] @ [768,3840] -> bf16
    gemm_mfma_kernel<128><<<dim3(16, 30), 256, 0, stream>>>(
        xb, WqkvT, bqkv, (const float*)nullptr, (float*)nullptr, qkvb, QKV_N, DMODEL, 0);

    // banded flash (192 blocks) + global CLS segments (96 blocks) in one launch
    attn_fused_kernel<<<dim3(NHEAD, NCHUNK + 8), 256, 0, stream>>>(
        qkvb, x, Wqg + wdd, bqg + vd, am, attnb, glbp);
    glb_attn_combine_kernel<<<NHEAD, 64, 0, stream>>>(glbp, attnb);

    // Wo projection: split-K=2 partials, then fused reduce+bias+residual+LN
    gemm_splitk_kernel<64, 2><<<dim3(32, 6, 2), 256, 0, stream>>>(
        attnb, WoT, parts, DMODEL, DMODEL);
    ln_reduce_kernel<2><<<S_LEN, 256, 0, stream>>>(
        parts, bo + vd, ln1g + vd, ln1b + vd, x, xb);

    // FFN1: [2048,768] @ [768,3072] + GELU -> bf16
    gemm_mfma_kernel<128><<<dim3(16, 24), 256, 0, stream>>>(
        xb, Wf1T, bf1 + vf, (const float*)nullptr, (float*)nullptr, tmpb, FFDIM, DMODEL, 1);

    // FFN2: split-K=4 partials, then fused reduce+bias+residual+LN
    gemm_splitk_kernel<64, 4><<<dim3(32, 6, 4), 256, 0, stream>>>(
        tmpb, Wf2T, parts, DMODEL, FFDIM);
    ln_reduce_kernel<4><<<S_LEN, 256, 0, stream>>>(
        parts, bf2 + vd, ln2g + vd, ln2b + vd, x, xb);
  }

  ln_vec_kernel<<<1, 256, 0, stream>>>(x, hng, hnb, hb);
  gemv_partial_kernel<<<16, 256, 0, stream>>>(hb, W1, gpart);
  gemv_reduce_kernel<<<3, 256, 0, stream>>>(gpart, b1, hb + DMODEL, 1);
  gemv_partial_kernel<<<16, 256, 0, stream>>>(hb + DMODEL, W2, gpart);
  gemv_reduce_kernel<<<3, 256, 0, stream>>>(gpart, b2, hb + 2 * DMODEL, 1);
  head_final_kernel<<<1, 256, 0, stream>>>(hb + 2 * DMODEL, Wout, bout, (float*)d_out);
}

// Round 10
// 1713.027 us; speedup vs baseline: 2.3722x; 1.0595x over previous
//
#include <hip/hip_runtime.h>
#include <math.h>

#define S_LEN 2048
#define DMODEL 768
#define NHEAD 12
#define DHEAD 64
#define NLAYER 12
#define FFDIM 3072
#define CHUNK 128
#define NCHUNK 16
#define QKV_N 3840   // q|k|v|kg|vg concatenated
#define DD (DMODEL * DMODEL)
#define DF (DMODEL * FFDIM)

typedef __attribute__((ext_vector_type(8))) short short8;
typedef __attribute__((ext_vector_type(4))) float f32x4;

__device__ __forceinline__ float gelu_f(float x) {
  return 0.5f * x * (1.0f + erff(x * 0.7071067811865476f));
}
// float -> bf16 bits (RNE)
__device__ __forceinline__ unsigned short f2b(float f) {
  unsigned int u = __float_as_uint(f);
  return (unsigned short)((u + 0x7FFFu + ((u >> 16) & 1u)) >> 16);
}
__device__ __forceinline__ float b2f(unsigned short u) {
  return __uint_as_float((unsigned int)u << 16);
}

// ================= embedding + LN =================
__global__ __launch_bounds__(256) void embed_ln_kernel(
    const int* __restrict__ ids, const float* __restrict__ wemb,
    const float* __restrict__ pemb, const float* __restrict__ g,
    const float* __restrict__ b, float* __restrict__ x, unsigned short* __restrict__ xb)
{
  const int s = blockIdx.x, tid = threadIdx.x;
  __shared__ float red[4];
  const size_t wbase = (size_t)ids[s] * DMODEL;
  const size_t pbase = (size_t)s * DMODEL;
  float y0 = wemb[wbase + tid]       + pemb[pbase + tid];
  float y1 = wemb[wbase + tid + 256] + pemb[pbase + tid + 256];
  float y2 = wemb[wbase + tid + 512] + pemb[pbase + tid + 512];
  float sum = y0 + y1 + y2;
  #pragma unroll
  for (int off = 32; off; off >>= 1) sum += __shfl_down(sum, off);
  if ((tid & 63) == 0) red[tid >> 6] = sum;
  __syncthreads();
  const float mean = (red[0] + red[1] + red[2] + red[3]) * (1.0f / 768.0f);
  __syncthreads();
  float d0 = y0 - mean, d1 = y1 - mean, d2 = y2 - mean;
  float vs = d0*d0 + d1*d1 + d2*d2;
  #pragma unroll
  for (int off = 32; off; off >>= 1) vs += __shfl_down(vs, off);
  if ((tid & 63) == 0) red[tid >> 6] = vs;
  __syncthreads();
  const float rstd = rsqrtf((red[0]+red[1]+red[2]+red[3]) * (1.0f/768.0f) + 1e-5f);
  float o0 = d0 * rstd * g[tid]       + b[tid];
  float o1 = d1 * rstd * g[tid + 256] + b[tid + 256];
  float o2 = d2 * rstd * g[tid + 512] + b[tid + 512];
  x[pbase + tid] = o0; x[pbase + tid + 256] = o1; x[pbase + tid + 512] = o2;
  xb[pbase + tid] = f2b(o0); xb[pbase + tid + 256] = f2b(o1); xb[pbase + tid + 512] = f2b(o2);
}

// ====== residual(x) + bias + sum of SK split-K partials -> LN -> x (f32) + xb (bf16) ==
template <int SK>
__global__ __launch_bounds__(256) void ln_reduce_kernel(
    const float* __restrict__ parts, const float* __restrict__ bias,
    const float* __restrict__ g, const float* __restrict__ b,
    float* __restrict__ x, unsigned short* __restrict__ xb)
{
  const int s = blockIdx.x, tid = threadIdx.x;
  __shared__ float red[4];
  const size_t base = (size_t)s * DMODEL;
  float y0 = x[base + tid]       + bias[tid];
  float y1 = x[base + tid + 256] + bias[tid + 256];
  float y2 = x[base + tid + 512] + bias[tid + 512];
  #pragma unroll
  for (int k = 0; k < SK; ++k) {
    const float* p = parts + (size_t)k * S_LEN * DMODEL + base;
    y0 += p[tid]; y1 += p[tid + 256]; y2 += p[tid + 512];
  }
  float sum = y0 + y1 + y2;
  #pragma unroll
  for (int off = 32; off; off >>= 1) sum += __shfl_down(sum, off);
  if ((tid & 63) == 0) red[tid >> 6] = sum;
  __syncthreads();
  const float mean = (red[0] + red[1] + red[2] + red[3]) * (1.0f / 768.0f);
  __syncthreads();
  float d0 = y0 - mean, d1 = y1 - mean, d2 = y2 - mean;
  float vs = d0*d0 + d1*d1 + d2*d2;
  #pragma unroll
  for (int off = 32; off; off >>= 1) vs += __shfl_down(vs, off);
  if ((tid & 63) == 0) red[tid >> 6] = vs;
  __syncthreads();
  const float rstd = rsqrtf((red[0]+red[1]+red[2]+red[3]) * (1.0f/768.0f) + 1e-5f);
  float o0 = d0 * rstd * g[tid]       + b[tid];
  float o1 = d1 * rstd * g[tid + 256] + b[tid + 256];
  float o2 = d2 * rstd * g[tid + 512] + b[tid + 512];
  x[base + tid] = o0; x[base + tid + 256] = o1; x[base + tid + 512] = o2;
  xb[base + tid] = f2b(o0); xb[base + tid + 256] = f2b(o1); xb[base + tid + 512] = f2b(o2);
}

__global__ __launch_bounds__(256) void ln_vec_kernel(
    const float* __restrict__ in, const float* __restrict__ g,
    const float* __restrict__ b, float* __restrict__ out)
{
  const int tid = threadIdx.x;
  __shared__ float red[4];
  float y0 = in[tid], y1 = in[tid + 256], y2 = in[tid + 512];
  float sum = y0 + y1 + y2;
  #pragma unroll
  for (int off = 32; off; off >>= 1) sum += __shfl_down(sum, off);
  if ((tid & 63) == 0) red[tid >> 6] = sum;
  __syncthreads();
  const float mean = (red[0] + red[1] + red[2] + red[3]) * (1.0f / 768.0f);
  __syncthreads();
  float d0 = y0 - mean, d1 = y1 - mean, d2 = y2 - mean;
  float vs = d0*d0 + d1*d1 + d2*d2;
  #pragma unroll
  for (int off = 32; off; off >>= 1) vs += __shfl_down(vs, off);
  if ((tid & 63) == 0) red[tid >> 6] = vs;
  __syncthreads();
  const float rstd = rsqrtf((red[0]+red[1]+red[2]+red[3]) * (1.0f/768.0f) + 1e-5f);
  out[tid]       = d0 * rstd * g[tid]       + b[tid];
  out[tid + 256] = d1 * rstd * g[tid + 256] + b[tid + 256];
  out[tid + 512] = d2 * rstd * g[tid + 512] + b[tid + 512];
}

// ====== one-shot weight convert+transpose, 64x64 tiles (f32 [K][N] -> bf16 [N][K]) ====
__global__ __launch_bounds__(256) void conv_all_dd_kernel(
    const float* __restrict__ Wq, const float* __restrict__ Wk, const float* __restrict__ Wv,
    const float* __restrict__ Wkg, const float* __restrict__ Wvg, const float* __restrict__ Wo,
    const float* __restrict__ bq, const float* __restrict__ bk, const float* __restrict__ bv,
    const float* __restrict__ bkg, const float* __restrict__ bvg,
    unsigned short* __restrict__ WqkvT, unsigned short* __restrict__ WoT,
    float* __restrict__ bqkv)
{
  const int z = blockIdx.z, layer = z / 6, mat = z % 6;
  const size_t off = (size_t)layer * DD;
  const float* src = (mat==0?Wq: mat==1?Wk: mat==2?Wv: mat==3?Wkg: mat==4?Wvg: Wo) + off;
  unsigned short* dst = (mat < 5)
      ? (WqkvT + (size_t)layer * 5 * DD + (size_t)mat * DD)
      : (WoT + off);
  __shared__ float tbuf[64][65];
  const int n0 = blockIdx.x * 64, k0 = blockIdx.y * 64;
  const int t = threadIdx.x;
  #pragma unroll
  for (int i = 0; i < 4; ++i) {
    const int idx = i * 256 + t;
    const int r = idx >> 4, c4 = (idx & 15) * 4;
    const float4 v = *(const float4*)&src[(size_t)(k0 + r) * DMODEL + n0 + c4];
    tbuf[r][c4] = v.x; tbuf[r][c4+1] = v.y; tbuf[r][c4+2] = v.z; tbuf[r][c4+3] = v.w;
  }
  __syncthreads();
  const int n = t >> 2, seg = (t & 3) * 16;
  unsigned short o[16];
  #pragma unroll
  for (int i = 0; i < 16; ++i) o[i] = f2b(tbuf[seg + i][n]);
  unsigned short* dp = &dst[(size_t)(n0 + n) * DMODEL + k0 + seg];
  *(short8*)dp = *(const short8*)&o[0];
  *(short8*)(dp + 8) = *(const short8*)&o[8];
  if (mat < 5 && blockIdx.x == 0 && blockIdx.y == 0) {
    const float* bs = (mat==0?bq: mat==1?bk: mat==2?bv: mat==3?bkg: bvg) + (size_t)layer * DMODEL;
    for (int i = t; i < DMODEL; i += 256) bqkv[(size_t)layer * QKV_N + mat * DMODEL + i] = bs[i];
  }
}

__global__ __launch_bounds__(256) void conv_all_ffn_kernel(
    const float* __restrict__ Wf1, const float* __restrict__ Wf2,
    unsigned short* __restrict__ Wf1T, unsigned short* __restrict__ Wf2T)
{
  const int z = blockIdx.z, layer = z / 2, which = z % 2;
  __shared__ float tbuf[64][65];
  const float* src; unsigned short* dst; int Kd, Nd, n0, k0;
  if (which == 0) { src = Wf1 + (size_t)layer * DF; dst = Wf1T + (size_t)layer * DF;
                    Kd = DMODEL; Nd = FFDIM; n0 = blockIdx.x * 64; k0 = blockIdx.y * 64; }
  else            { src = Wf2 + (size_t)layer * DF; dst = Wf2T + (size_t)layer * DF;
                    Kd = FFDIM; Nd = DMODEL; n0 = blockIdx.y * 64; k0 = blockIdx.x * 64; }
  const int t = threadIdx.x;
  #pragma unroll
  for (int i = 0; i < 4; ++i) {
    const int idx = i * 256 + t;
    const int r = idx >> 4, c4 = (idx & 15) * 4;
    const float4 v = *(const float4*)&src[(size_t)(k0 + r) * Nd + n0 + c4];
    tbuf[r][c4] = v.x; tbuf[r][c4+1] = v.y; tbuf[r][c4+2] = v.z; tbuf[r][c4+3] = v.w;
  }
  __syncthreads();
  const int n = t >> 2, seg = (t & 3) * 16;
  unsigned short o[16];
  #pragma unroll
  for (int i = 0; i < 16; ++i) o[i] = f2b(tbuf[seg + i][n]);
  unsigned short* dp = &dst[(size_t)(n0 + n) * Kd + k0 + seg];
  *(short8*)dp = *(const short8*)&o[0];
  *(short8*)(dp + 8) = *(const short8*)&o[8];
}

// ======= bf16 MFMA GEMM (BMx128 tile, BK=64, swizzled LDS, XCD swizzle, residual) =====
template <int BM>
__global__ __launch_bounds__(256) void gemm_mfma_kernel(
    const unsigned short* __restrict__ A, const unsigned short* __restrict__ Bt,
    const float* __restrict__ bias, const float* __restrict__ Res,
    float* __restrict__ Cf, unsigned short* __restrict__ Cb, int N, int K, int act)
{
  constexpr int ASLOTS = BM * 8;
  constexpr int MI = BM / 32;
  __shared__ unsigned short As[ASLOTS * 8];
  __shared__ unsigned short Bs[8192];
  const int tid = threadIdx.x, wave = tid >> 6, lane = tid & 63;
  const int gx = gridDim.x, nwg = gx * gridDim.y;
  int flat = blockIdx.y * gx + blockIdx.x;
  flat = (flat & 7) * (nwg >> 3) + (flat >> 3);
  const int bm = (flat % gx) * BM, bn = (flat / gx) * 128;
  const int wr = (wave >> 1) * (BM / 2), wc = (wave & 1) * 64;
  f32x4 acc[MI][4];
  const f32x4 zz = {0.f, 0.f, 0.f, 0.f};
  #pragma unroll
  for (int i = 0; i < MI; ++i)
    #pragma unroll
    for (int j = 0; j < 4; ++j) acc[i][j] = zz;

  for (int k0 = 0; k0 < K; k0 += 64) {
    #pragma unroll
    for (int it = 0; it < ASLOTS / 256; ++it) {
      const int s = it * 256 + tid;
      const int mr = s >> 3;
      const int kg = (s & 7) ^ (mr & 7);
      const unsigned short* src = A + (size_t)(bm + mr) * K + k0 + kg * 8;
      __builtin_amdgcn_global_load_lds(
          (const __attribute__((address_space(1))) void*)src,
          (__attribute__((address_space(3))) void*)&As[(size_t)(it * 256 + wave * 64) * 8], 16, 0, 0);
    }
    #pragma unroll
    for (int it = 0; it < 4; ++it) {
      const int s = it * 256 + tid;
      const int mr = s >> 3;
      const int kg = (s & 7) ^ (mr & 7);
      const unsigned short* src = Bt + (size_t)(bn + mr) * K + k0 + kg * 8;
      __builtin_amdgcn_global_load_lds(
          (const __attribute__((address_space(1))) void*)src,
          (__attribute__((address_space(3))) void*)&Bs[(size_t)(it * 256 + wave * 64) * 8], 16, 0, 0);
    }
    __syncthreads();
    #pragma unroll
    for (int ks = 0; ks < 2; ++ks) {
      const int kg = ks * 4 + (lane >> 4);
      short8 af[MI], bfr[4];
      #pragma unroll
      for (int i = 0; i < MI; ++i) {
        const int m = wr + i * 16 + (lane & 15);
        af[i] = *(const short8*)&As[(m * 8 + (kg ^ (m & 7))) * 8];
      }
      #pragma unroll
      for (int j = 0; j < 4; ++j) {
        const int n = wc + j * 16 + (lane & 15);
        bfr[j] = *(const short8*)&Bs[(n * 8 + (kg ^ (n & 7))) * 8];
      }
      #pragma unroll
      for (int i = 0; i < MI; ++i)
        #pragma unroll
        for (int j = 0; j < 4; ++j)
          acc[i][j] = __builtin_amdgcn_mfma_f32_16x16x32_bf16(af[i], bfr[j], acc[i][j], 0, 0, 0);
    }
    __syncthreads();
  }

  const int lr = (lane >> 4) * 4, lc = lane & 15;
  #pragma unroll
  for (int i = 0; i < MI; ++i) {
    #pragma unroll
    for (int j = 0; j < 4; ++j) {
      const int n = bn + wc + j * 16 + lc;
      const float bv = bias[n];
      #pragma unroll
      for (int p = 0; p < 4; ++p) {
        const int m = bm + wr + i * 16 + lr + p;
        float val = acc[i][j][p] + bv;
        if (Res) val += Res[(size_t)m * N + n];
        if (act) val = gelu_f(val);
        if (Cf) Cf[(size_t)m * N + n] = val;
        if (Cb) Cb[(size_t)m * N + n] = f2b(val);
      }
    }
  }
}

// ======= split-K bf16 MFMA GEMM partial: Cp[sk][M][N] += A @ Bt^T over K-slice ========
template <int BM, int SK>
__global__ __launch_bounds__(256) void gemm_splitk_kernel(
    const unsigned short* __restrict__ A, const unsigned short* __restrict__ Bt,
    float* __restrict__ Cp, int N, int K)
{
  constexpr int ASLOTS = BM * 8;
  constexpr int MI = BM / 32;
  __shared__ unsigned short As[ASLOTS * 8];
  __shared__ unsigned short Bs[8192];
  const int tid = threadIdx.x, wave = tid >> 6, lane = tid & 63;
  const int gx = gridDim.x, nwg = gx * gridDim.y;
  int flat = blockIdx.y * gx + blockIdx.x;
  flat = (flat & 7) * (nwg >> 3) + (flat >> 3);
  const int bm = (flat % gx) * BM, bn = (flat / gx) * 128;
  const int sk = blockIdx.z;
  const int KS = K / SK;
  const int kbeg = sk * KS;
  const int wr = (wave >> 1) * (BM / 2), wc = (wave & 1) * 64;
  f32x4 acc[MI][4];
  const f32x4 zz = {0.f, 0.f, 0.f, 0.f};
  #pragma unroll
  for (int i = 0; i < MI; ++i)
    #pragma unroll
    for (int j = 0; j < 4; ++j) acc[i][j] = zz;

  for (int k0 = kbeg; k0 < kbeg + KS; k0 += 64) {
    #pragma unroll
    for (int it = 0; it < ASLOTS / 256; ++it) {
      const int s = it * 256 + tid;
      const int mr = s >> 3;
      const int kg = (s & 7) ^ (mr & 7);
      const unsigned short* src = A + (size_t)(bm + mr) * K + k0 + kg * 8;
      __builtin_amdgcn_global_load_lds(
          (const __attribute__((address_space(1))) void*)src,
          (__attribute__((address_space(3))) void*)&As[(size_t)(it * 256 + wave * 64) * 8], 16, 0, 0);
    }
    #pragma unroll
    for (int it = 0; it < 4; ++it) {
      const int s = it * 256 + tid;
      const int mr = s >> 3;
      const int kg = (s & 7) ^ (mr & 7);
      const unsigned short* src = Bt + (size_t)(bn + mr) * K + k0 + kg * 8;
      __builtin_amdgcn_global_load_lds(
          (const __attribute__((address_space(1))) void*)src,
          (__attribute__((address_space(3))) void*)&Bs[(size_t)(it * 256 + wave * 64) * 8], 16, 0, 0);
    }
    __syncthreads();
    #pragma unroll
    for (int ks = 0; ks < 2; ++ks) {
      const int kg = ks * 4 + (lane >> 4);
      short8 af[MI], bfr[4];
      #pragma unroll
      for (int i = 0; i < MI; ++i) {
        const int m = wr + i * 16 + (lane & 15);
        af[i] = *(const short8*)&As[(m * 8 + (kg ^ (m & 7))) * 8];
      }
      #pragma unroll
      for (int j = 0; j < 4; ++j) {
        const int n = wc + j * 16 + (lane & 15);
        bfr[j] = *(const short8*)&Bs[(n * 8 + (kg ^ (n & 7))) * 8];
      }
      #pragma unroll
      for (int i = 0; i < MI; ++i)
        #pragma unroll
        for (int j = 0; j < 4; ++j)
          acc[i][j] = __builtin_amdgcn_mfma_f32_16x16x32_bf16(af[i], bfr[j], acc[i][j], 0, 0, 0);
    }
    __syncthreads();
  }

  float* Co = Cp + (size_t)sk * S_LEN * DMODEL;
  const int lr = (lane >> 4) * 4, lc = lane & 15;
  #pragma unroll
  for (int i = 0; i < MI; ++i) {
    #pragma unroll
    for (int j = 0; j < 4; ++j) {
      const int n = bn + wc + j * 16 + lc;
      #pragma unroll
      for (int p = 0; p < 4; ++p) {
        const int m = bm + wr + i * 16 + lr + p;
        Co[(size_t)m * N + n] = acc[i][j][p];
      }
    }
  }
}

// == fused attention: banded flash (y<16) + global CLS row 8-way segments (y in 16..23) ==
// LDS: Ks 16K | Vt 16K | Ps 16K (64-key half-tile) | smcls/sv0/sam -> 50.4 KB total
__global__ __launch_bounds__(256) void attn_fused_kernel(
    const unsigned short* __restrict__ qkvb, const float* __restrict__ xf,
    const float* __restrict__ Wqg, const float* __restrict__ bqg,
    const int* __restrict__ am, unsigned short* __restrict__ outb,
    float* __restrict__ glbp)
{
  __shared__ __align__(16) unsigned char smem[50432];
  const int h = blockIdx.x, tid = threadIdx.x;

  if (blockIdx.y >= NCHUNK) {
    // ---------------- global CLS query row: segment g of 256 keys ----------------
    const int g = blockIdx.y - NCHUNK;    // 0..7
    float* sc  = (float*)smem;            // 256 f32
    float* qs  = (float*)(smem + 1024);   // 64
    float* red = (float*)(smem + 1280);   // 4
    float* pqg = (float*)(smem + 1296);   // 4*64
    float* pb  = (float*)(smem + 2320);   // 32*64 f32 (8 KB)
    const int d = tid & 63, grp = tid >> 6;
    // qg0 slice for this head (redundant per segment block; cheap, concurrent)
    {
      float p = 0.f;
      const float* wcol = Wqg + (size_t)(grp * 192) * DMODEL + h * DHEAD + d;
      #pragma unroll 4
      for (int k = 0; k < 192; ++k)
        p = fmaf(xf[grp * 192 + k], wcol[(size_t)k * DMODEL], p);
      pqg[grp * 64 + d] = p;
    }
    __syncthreads();
    if (tid < 64)
      qs[tid] = (pqg[tid] + pqg[64 + tid] + pqg[128 + tid] + pqg[192 + tid]
                 + bqg[h * DHEAD + tid]) * 0.125f;
    __syncthreads();
    const unsigned short* kg = qkvb + 3 * DMODEL + h * DHEAD;
    const unsigned short* vg = qkvb + 4 * DMODEL + h * DHEAD;
    const int s0 = g * 256 + tid;
    float dd = 0.f;
    {
      const unsigned short* kr = kg + (size_t)s0 * QKV_N;
      #pragma unroll
      for (int d0 = 0; d0 < DHEAD; d0 += 8) {
        const short8 k8 = *(const short8*)(kr + d0);
        #pragma unroll
        for (int e = 0; e < 8; ++e) dd += qs[d0 + e] * b2f((unsigned short)k8[e]);
      }
    }
    const float mysc = (am[s0] > 0) ? dd : -1e9f;
    float mx = mysc;
    #pragma unroll
    for (int off = 32; off; off >>= 1) mx = fmaxf(mx, __shfl_down(mx, off));
    if ((tid & 63) == 0) red[tid >> 6] = mx;
    __syncthreads();
    mx = fmaxf(fmaxf(red[0], red[1]), fmaxf(red[2], red[3]));
    __syncthreads();
    const float e = __expf(mysc - mx);
    sc[tid] = e;
    float sum = e;
    #pragma unroll
    for (int off = 32; off; off >>= 1) sum += __shfl_down(sum, off);
    if ((tid & 63) == 0) red[tid >> 6] = sum;
    __syncthreads();
    const float lsum = red[0] + red[1] + red[2] + red[3];
    // ---- PV over this segment (unnormalized): 32-key x 8-dim split, short8 loads ----
    const int d8 = (tid & 7) * 8, kgrp = tid >> 3;
    float a8[8] = {};
    #pragma unroll
    for (int ii = 0; ii < 8; ++ii) {
      const int loc = kgrp + ii * 32;
      const float p = sc[loc];
      const short8 v8 = *(const short8*)(vg + (size_t)(g * 256 + loc) * QKV_N + d8);
      #pragma unroll
      for (int ee = 0; ee < 8; ++ee) a8[ee] = fmaf(p, b2f((unsigned short)v8[ee]), a8[ee]);
    }
    #pragma unroll
    for (int ee = 0; ee < 8; ++ee) pb[kgrp * 64 + d8 + ee] = a8[ee];
    __syncthreads();
    float* pr = glbp + (size_t)(h * 8 + g) * 66;
    if (tid < 64) {
      float o = 0.f;
      #pragma unroll
      for (int k = 0; k < 32; ++k) o += pb[k * 64 + tid];
      pr[2 + tid] = o;
    }
    if (tid == 0) { pr[0] = mx; pr[1] = lsum; }
    return;
  }

  // ---------------- banded sliding-window flash ----------------
  const int nc = blockIdx.y;
  const int wave = tid >> 6, lane = tid & 63;
  const int c = lane & 15, g = lane >> 4;
  unsigned short* Ks = (unsigned short*)smem;             // 16 KB
  unsigned short* Vt = (unsigned short*)(smem + 16384);   // 16 KB
  unsigned short* Ps = (unsigned short*)(smem + 32768);   // 16 KB ([128 rows][64 keys])
  float* smcls = (float*)(smem + 49152);                  // 512 B
  float* sv0   = (float*)(smem + 49664);                  // 256 B
  int*   sam   = (int*)(smem + 49920);                    // 512 B

  if (tid < 64) sv0[tid] = b2f(qkvb[2 * DMODEL + h * DHEAD + tid]);
  if (tid < 128) {
    const int qrow = nc * CHUNK + tid;
    const unsigned short* qp = qkvb + (size_t)qrow * QKV_N + h * DHEAD;
    const unsigned short* k0 = qkvb + DMODEL + h * DHEAD;
    float d = 0.f;
    #pragma unroll
    for (int dd = 0; dd < 64; dd += 8) {
      const short8 a8 = *(const short8*)(qp + dd);
      const short8 b8 = *(const short8*)(k0 + dd);
      #pragma unroll
      for (int e = 0; e < 8; ++e)
        d += b2f((unsigned short)a8[e]) * b2f((unsigned short)b8[e]);
    }
    smcls[tid] = (am[0] > 0) ? d * 0.125f : -1e9f;
  }

  short8 af[2][2];
  #pragma unroll
  for (int i = 0; i < 2; ++i)
    #pragma unroll
    for (int ks = 0; ks < 2; ++ks) {
      const int qrow = nc * CHUNK + wave * 32 + i * 16 + c;
      af[i][ks] = *(const short8*)(qkvb + (size_t)qrow * QKV_N + h * DHEAD + (ks * 4 + g) * 8);
    }

  __syncthreads();

  float mrow[2][4], lrow[2][4];
  f32x4 acc_o[2][4];
  #pragma unroll
  for (int i = 0; i < 2; ++i)
    #pragma unroll
    for (int p = 0; p < 4; ++p) {
      mrow[i][p] = smcls[wave * 32 + i * 16 + g * 4 + p];
      lrow[i][p] = 1.f;
    }
  #pragma unroll
  for (int i = 0; i < 2; ++i)
    #pragma unroll
    for (int j = 0; j < 4; ++j) {
      const float v0 = sv0[j * 16 + c];
      acc_o[i][j][0] = v0; acc_o[i][j][1] = v0; acc_o[i][j][2] = v0; acc_o[i][j][3] = v0;
    }

  for (int kci = 0; kci < 3; ++kci) {
    const int ck = nc - 1 + kci;
    if (ck < 0 || ck > 15) continue;
    __syncthreads();

    #pragma unroll
    for (int it = 0; it < 4; ++it) {
      const int sidx = it * 256 + tid;
      const int mr = sidx >> 3;
      const int kg = (sidx & 7) ^ (mr & 7);
      const unsigned short* src = qkvb + (size_t)(ck * CHUNK + mr) * QKV_N + DMODEL + h * DHEAD + kg * 8;
      __builtin_amdgcn_global_load_lds(
          (const __attribute__((address_space(1))) void*)src,
          (__attribute__((address_space(3))) void*)&Ks[(size_t)(it * 256 + wave * 64) * 8], 16, 0, 0);
    }
    {
      const int kp = tid & 63, dh = tid >> 6;
      const unsigned short* v0p = qkvb + (size_t)(ck * CHUNK + 2 * kp) * QKV_N + 2 * DMODEL + h * DHEAD + dh * 16;
      const short8 a0 = *(const short8*)(v0p);
      const short8 a1 = *(const short8*)(v0p + 8);
      const short8 b0 = *(const short8*)(v0p + QKV_N);
      const short8 b1 = *(const short8*)(v0p + QKV_N + 8);
      #pragma unroll
      for (int dd = 0; dd < 16; ++dd) {
        const int dim = dh * 16 + dd;
        const unsigned short lo = (unsigned short)(dd < 8 ? a0[dd] : a1[dd - 8]);
        const unsigned short hi = (unsigned short)(dd < 8 ? b0[dd] : b1[dd - 8]);
        const unsigned int w = (unsigned int)lo | ((unsigned int)hi << 16);
        const int si = dim * 128 + (((kp >> 2) ^ (dim & 7)) << 3) + ((kp & 3) << 1);
        *(unsigned int*)&Vt[si] = w;
      }
    }
    if (tid < 128) sam[tid] = am[ck * CHUNK + tid];
    __syncthreads();

    // preload this thread's am-mask values (one per key-frag column)
    int am8[8];
    #pragma unroll
    for (int j = 0; j < 8; ++j) am8[j] = sam[j * 16 + c];

    // ---- S = Q @ K^T (full 128-key tile) ----
    f32x4 accs[2][8];
    const f32x4 zz = {0.f, 0.f, 0.f, 0.f};
    #pragma unroll
    for (int i = 0; i < 2; ++i)
      #pragma unroll
      for (int j = 0; j < 8; ++j) accs[i][j] = zz;
    __builtin_amdgcn_s_setprio(1);
    #pragma unroll
    for (int ks = 0; ks < 2; ++ks) {
      const int kg = ks * 4 + g;
      short8 bfr[8];
      #pragma unroll
      for (int j = 0; j < 8; ++j) {
        const int jj = j * 16 + c;
        bfr[j] = *(const short8*)&Ks[(jj * 8 + (kg ^ (jj & 7))) * 8];
      }
      #pragma unroll
      for (int i = 0; i < 2; ++i)
        #pragma unroll
        for (int j = 0; j < 8; ++j)
          accs[i][j] = __builtin_amdgcn_mfma_f32_16x16x32_bf16(af[i][ks], bfr[j], accs[i][j], 0, 0, 0);
    }
    __builtin_amdgcn_s_setprio(0);

    // ---- two 64-key halves: mask + online softmax + P write + PV ----
    #pragma unroll
    for (int h2 = 0; h2 < 2; ++h2) {
      #pragma unroll
      for (int i = 0; i < 2; ++i) {
        #pragma unroll
        for (int p = 0; p < 4; ++p) {
          const int mloc = wave * 32 + i * 16 + g * 4 + p;
          const int qi = nc * CHUNK + mloc;
          float sv[4];
          float rmax = -1e30f;
          #pragma unroll
          for (int j = 0; j < 4; ++j) {
            const int jg = h2 * 4 + j;
            const int jj = jg * 16 + c;
            const int kj = ck * CHUNK + jj;
            const int diff = qi - kj;
            const bool ok = (diff <= 128) && (diff >= -128) && (kj != 0) && (am8[jg] > 0);
            const float s = ok ? accs[i][jg][p] * 0.125f : -1e9f;
            sv[j] = s;
            rmax = fmaxf(rmax, s);
          }
          rmax = fmaxf(rmax, __shfl_xor(rmax, 1));
          rmax = fmaxf(rmax, __shfl_xor(rmax, 2));
          rmax = fmaxf(rmax, __shfl_xor(rmax, 4));
          rmax = fmaxf(rmax, __shfl_xor(rmax, 8));
          const float mnew = fmaxf(mrow[i][p], rmax);
          const float corr = __expf(mrow[i][p] - mnew);
          float psum = 0.f;
          #pragma unroll
          for (int j = 0; j < 4; ++j) {
            const float pv = __expf(sv[j] - mnew);
            sv[j] = pv;
            psum += pv;
          }
          psum += __shfl_xor(psum, 1);
          psum += __shfl_xor(psum, 2);
          psum += __shfl_xor(psum, 4);
          psum += __shfl_xor(psum, 8);
          lrow[i][p] = lrow[i][p] * corr + psum;
          mrow[i][p] = mnew;
          #pragma unroll
          for (int j = 0; j < 4; ++j) acc_o[i][j][p] *= corr;
          #pragma unroll
          for (int j = 0; j < 4; ++j) {
            const int keyh = j * 16 + c;            // key within half
            const int kslot = keyh >> 3;            // 0..7
            Ps[mloc * 64 + ((kslot ^ (mloc & 7)) << 3) + (keyh & 7)] = f2b(sv[j]);
          }
        }
      }
      // wave-private P rows: drain LDS writes before cross-lane reads
      asm volatile("s_waitcnt lgkmcnt(0)" ::: "memory");

      __builtin_amdgcn_s_setprio(1);
      #pragma unroll
      for (int s2 = 0; s2 < 2; ++s2) {
        const int kslot = s2 * 4 + g;               // within half: 0..7
        const int kg2 = h2 * 8 + kslot;             // within tile: 0..15
        short8 pa[2], vb[4];
        #pragma unroll
        for (int i = 0; i < 2; ++i) {
          const int row = wave * 32 + i * 16 + c;
          pa[i] = *(const short8*)&Ps[row * 64 + ((kslot ^ (row & 7)) << 3)];
        }
        #pragma unroll
        for (int j = 0; j < 4; ++j) {
          const int n = j * 16 + c;
          vb[j] = *(const short8*)&Vt[n * 128 + ((kg2 ^ (n & 7)) << 3)];
        }
        #pragma unroll
        for (int i = 0; i < 2; ++i)
          #pragma unroll
          for (int j = 0; j < 4; ++j)
            acc_o[i][j] = __builtin_amdgcn_mfma_f32_16x16x32_bf16(pa[i], vb[j], acc_o[i][j], 0, 0, 0);
      }
      __builtin_amdgcn_s_setprio(0);
    }
  }

  #pragma unroll
  for (int i = 0; i < 2; ++i) {
    #pragma unroll
    for (int p = 0; p < 4; ++p) {
      const float rl = (lrow[i][p] > 0.f) ? 1.f / lrow[i][p] : 0.f;
      const int row = nc * CHUNK + wave * 32 + i * 16 + g * 4 + p;
      if (row == 0) continue;  // row 0 owned by the global path
      #pragma unroll
      for (int j = 0; j < 4; ++j)
        outb[(size_t)row * DMODEL + h * DHEAD + j * 16 + c] = f2b(acc_o[i][j][p] * rl);
    }
  }
}

// ================= global CLS combine: merge 8 segment partials -> row 0 =============
__global__ __launch_bounds__(64) void glb_attn_combine_kernel(
    const float* __restrict__ part, unsigned short* __restrict__ outb)
{
  const int h = blockIdx.x, d = threadIdx.x;
  float M = -1e30f;
  for (int g = 0; g < 8; ++g) M = fmaxf(M, part[(size_t)(h * 8 + g) * 66]);
  float L = 0.f, o = 0.f;
  for (int g = 0; g < 8; ++g) {
    const float* pr = part + (size_t)(h * 8 + g) * 66;
    const float cc = (pr[0] > -1e8f) ? __expf(pr[0] - M) : 0.f;
    L += pr[1] * cc;
    o += pr[2 + d] * cc;
  }
  outb[h * DHEAD + d] = f2b(o / L);
}

// ================= split-k GEMV (head MLP only) =================
__global__ __launch_bounds__(256) void gemv_partial_kernel(
    const float* __restrict__ xrow, const float* __restrict__ W, float* __restrict__ part)
{
  const int b = blockIdx.x, t = threadIdx.x;
  float s0 = 0.f, s1 = 0.f, s2 = 0.f;
  for (int kk = 0; kk < 48; ++kk) {
    const int k = b * 48 + kk;
    const float xv = xrow[k];
    const float* wr = W + (size_t)k * DMODEL;
    s0 = fmaf(xv, wr[t], s0);
    s1 = fmaf(xv, wr[t + 256], s1);
    s2 = fmaf(xv, wr[t + 512], s2);
  }
  part[b * DMODEL + t] = s0;
  part[b * DMODEL + t + 256] = s1;
  part[b * DMODEL + t + 512] = s2;
}

__global__ __launch_bounds__(256) void gemv_reduce_kernel(
    const float* __restrict__ part, const float* __restrict__ bias,
    float* __restrict__ y, int act)
{
  const int n = blockIdx.x * 256 + threadIdx.x;
  float s = bias[n];
  #pragma unroll
  for (int b = 0; b < 16; ++b) s += part[b * DMODEL + n];
  if (act) s = gelu_f(s);
  y[n] = s;
}

// ================= final head =================
__global__ __launch_bounds__(256) void head_final_kernel(
    const float* __restrict__ h2, const float* __restrict__ Wout,
    const float* __restrict__ bout, float* __restrict__ out)
{
  const int tid = threadIdx.x;
  __shared__ float red[4];
  float p = h2[tid]*Wout[tid] + h2[tid+256]*Wout[tid+256] + h2[tid+512]*Wout[tid+512];
  #pragma unroll
  for (int off = 32; off; off >>= 1) p += __shfl_down(p, off);
  if ((tid & 63) == 0) red[tid >> 6] = p;
  __syncthreads();
  if (tid == 0) {
    const float logit = red[0] + red[1] + red[2] + red[3] + bout[0];
    const float sig = 1.0f / (1.0f + expf(-logit));
    const unsigned int bits = __float_as_uint(sig);
    const unsigned int bf = (bits + 0x7FFFu + ((bits >> 16) & 1u)) >> 16;
    out[0] = __uint_as_float((bits & 0xFFFF0000u) | (bf & 0xFFFFu));
  }
}

extern "C" void kernel_launch(void* const* d_in, const int* in_sizes, int n_in,
                              void* d_out, int out_size, void* d_ws, size_t ws_size,
                              hipStream_t stream)
{
  const int*   ids  = (const int*)d_in[0];
  const int*   am   = (const int*)d_in[1];
  const float* wemb = (const float*)d_in[2];
  const float* pemb = (const float*)d_in[3];
  const float* emb_g = (const float*)d_in[4];
  const float* emb_b = (const float*)d_in[5];
  const float* Wq  = (const float*)d_in[6];
  const float* bq  = (const float*)d_in[7];
  const float* Wk  = (const float*)d_in[8];
  const float* bk  = (const float*)d_in[9];
  const float* Wv  = (const float*)d_in[10];
  const float* bv  = (const float*)d_in[11];
  const float* Wqg = (const float*)d_in[12];
  const float* bqg = (const float*)d_in[13];
  const float* Wkg = (const float*)d_in[14];
  const float* bkg = (const float*)d_in[15];
  const float* Wvg = (const float*)d_in[16];
  const float* bvg = (const float*)d_in[17];
  const float* Wo  = (const float*)d_in[18];
  const float* bo  = (const float*)d_in[19];
  const float* ln1g = (const float*)d_in[20];
  const float* ln1b = (const float*)d_in[21];
  const float* Wf1 = (const float*)d_in[22];
  const float* bf1 = (const float*)d_in[23];
  const float* Wf2 = (const float*)d_in[24];
  const float* bf2 = (const float*)d_in[25];
  const float* ln2g = (const float*)d_in[26];
  const float* ln2b = (const float*)d_in[27];
  const float* hng = (const float*)d_in[28];
  const float* hnb = (const float*)d_in[29];
  const float* W1  = (const float*)d_in[30];
  const float* b1  = (const float*)d_in[31];
  const float* W2  = (const float*)d_in[32];
  const float* b2  = (const float*)d_in[33];
  const float* Wout = (const float*)d_in[34];
  const float* bout = (const float*)d_in[35];

  char* wp = (char*)d_ws;
  auto alloc = [&](size_t bytes) -> void* {
    void* r = (void*)wp;
    wp += (bytes + 255) & ~(size_t)255;
    return r;
  };
  float*          x         = (float*)alloc((size_t)S_LEN * DMODEL * 4);
  unsigned short* xb        = (unsigned short*)alloc((size_t)S_LEN * DMODEL * 2);
  unsigned short* qkvb      = (unsigned short*)alloc((size_t)S_LEN * QKV_N * 2);
  unsigned short* attnb     = (unsigned short*)alloc((size_t)S_LEN * DMODEL * 2);
  unsigned short* tmpb      = (unsigned short*)alloc((size_t)S_LEN * FFDIM * 2);
  float*          parts     = (float*)alloc((size_t)4 * S_LEN * DMODEL * 4);
  unsigned short* WqkvT_all = (unsigned short*)alloc((size_t)NLAYER * 5 * DD * 2);
  unsigned short* WoT_all   = (unsigned short*)alloc((size_t)NLAYER * DD * 2);
  unsigned short* Wf1T_all  = (unsigned short*)alloc((size_t)NLAYER * DF * 2);
  unsigned short* Wf2T_all  = (unsigned short*)alloc((size_t)NLAYER * DF * 2);
  float*          bqkv_all  = (float*)alloc((size_t)NLAYER * QKV_N * 4);
  float*          glbp      = (float*)alloc((size_t)NHEAD * 8 * 66 * 4);
  float*          gpart     = (float*)alloc((size_t)16 * DMODEL * 4);
  float*          hb        = (float*)alloc((size_t)3 * DMODEL * 4);

  // one-shot weight conversion for all layers (BW-bound, 2 launches)
  conv_all_dd_kernel<<<dim3(12, 12, 6 * NLAYER), 256, 0, stream>>>(
      Wq, Wk, Wv, Wkg, Wvg, Wo, bq, bk, bv, bkg, bvg, WqkvT_all, WoT_all, bqkv_all);
  conv_all_ffn_kernel<<<dim3(48, 12, 2 * NLAYER), 256, 0, stream>>>(
      Wf1, Wf2, Wf1T_all, Wf2T_all);

  embed_ln_kernel<<<S_LEN, 256, 0, stream>>>(ids, wemb, pemb, emb_g, emb_b, x, xb);

  for (int l = 0; l < NLAYER; ++l) {
    const size_t wdd = (size_t)l * DD;
    const size_t vd  = (size_t)l * DMODEL;
    const size_t vf  = (size_t)l * FFDIM;
    const unsigned short* WqkvT = WqkvT_all + (size_t)l * 5 * DD;
    const unsigned short* WoT   = WoT_all + wdd;
    const unsigned short* Wf1T  = Wf1T_all + (size_t)l * DF;
    const unsigned short* Wf2T  = Wf2T_all + (size_t)l * DF;
    const float* bqkv = bqkv_all + (size_t)l * QKV_N;

    // fused q|k|v|kg|vg projection: [2048,768] @ [768,3840] -> bf16 (BM=64: 960 blocks)
    gemm_mfma_kernel<64><<<dim3(32, 30), 256, 0, stream>>>(
        xb, WqkvT, bqkv, (const float*)nullptr, (float*)nullptr, qkvb, QKV_N, DMODEL, 0);

    // banded flash (192 blocks) + global CLS segments (96 blocks) in one launch
    attn_fused_kernel<<<dim3(NHEAD, NCHUNK + 8), 256, 0, stream>>>(
        qkvb, x, Wqg + wdd, bqg + vd, am, attnb, glbp);
    glb_attn_combine_kernel<<<NHEAD, 64, 0, stream>>>(glbp, attnb);

    // Wo projection: split-K=2 partials, then fused reduce+bias+residual+LN
    gemm_splitk_kernel<64, 2><<<dim3(32, 6, 2), 256, 0, stream>>>(
        attnb, WoT, parts, DMODEL, DMODEL);
    ln_reduce_kernel<2><<<S_LEN, 256, 0, stream>>>(
        parts, bo + vd, ln1g + vd, ln1b + vd, x, xb);

    // FFN1: [2048,768] @ [768,3072] + GELU -> bf16 (BM=64: 768 blocks)
    gemm_mfma_kernel<64><<<dim3(32, 24), 256, 0, stream>>>(
        xb, Wf1T, bf1 + vf, (const float*)nullptr, (float*)nullptr, tmpb, FFDIM, DMODEL, 1);

    // FFN2: split-K=4 partials, then fused reduce+bias+residual+LN
    gemm_splitk_kernel<64, 4><<<dim3(32, 6, 4), 256, 0, stream>>>(
        tmpb, Wf2T, parts, DMODEL, FFDIM);
    ln_reduce_kernel<4><<<S_LEN, 256, 0, stream>>>(
        parts, bf2 + vd, ln2g + vd, ln2b + vd, x, xb);
  }

  ln_vec_kernel<<<1, 256, 0, stream>>>(x, hng, hnb, hb);
  gemv_partial_kernel<<<16, 256, 0, stream>>>(hb, W1, gpart);
  gemv_reduce_kernel<<<3, 256, 0, stream>>>(gpart, b1, hb + DMODEL, 1);
  gemv_partial_kernel<<<16, 256, 0, stream>>>(hb + DMODEL, W2, gpart);
  gemv_reduce_kernel<<<3, 256, 0, stream>>>(gpart, b2, hb + 2 * DMODEL, 1);
  head_final_kernel<<<1, 256, 0, stream>>>(hb + 2 * DMODEL, Wout, bout, (float*)d_out);
}

// Round 11
// 1679.224 us; speedup vs baseline: 2.4199x; 1.0201x over previous
//
#include <hip/hip_runtime.h>
#include <math.h>

#define S_LEN 2048
#define DMODEL 768
#define NHEAD 12
#define DHEAD 64
#define NLAYER 12
#define FFDIM 3072
#define CHUNK 128
#define NCHUNK 16
#define QKV_N 3840   // q|k|v|kg|vg concatenated
#define DD (DMODEL * DMODEL)
#define DF (DMODEL * FFDIM)

typedef __attribute__((ext_vector_type(8))) short short8;
typedef __attribute__((ext_vector_type(4))) float f32x4;

__device__ __forceinline__ float gelu_f(float x) {
  return 0.5f * x * (1.0f + erff(x * 0.7071067811865476f));
}
// float -> bf16 bits (RNE)
__device__ __forceinline__ unsigned short f2b(float f) {
  unsigned int u = __float_as_uint(f);
  return (unsigned short)((u + 0x7FFFu + ((u >> 16) & 1u)) >> 16);
}
__device__ __forceinline__ float b2f(unsigned short u) {
  return __uint_as_float((unsigned int)u << 16);
}

// ================= embedding + LN =================
__global__ __launch_bounds__(256) void embed_ln_kernel(
    const int* __restrict__ ids, const float* __restrict__ wemb,
    const float* __restrict__ pemb, const float* __restrict__ g,
    const float* __restrict__ b, float* __restrict__ x, unsigned short* __restrict__ xb)
{
  const int s = blockIdx.x, tid = threadIdx.x;
  __shared__ float red[4];
  const size_t wbase = (size_t)ids[s] * DMODEL;
  const size_t pbase = (size_t)s * DMODEL;
  float y0 = wemb[wbase + tid]       + pemb[pbase + tid];
  float y1 = wemb[wbase + tid + 256] + pemb[pbase + tid + 256];
  float y2 = wemb[wbase + tid + 512] + pemb[pbase + tid + 512];
  float sum = y0 + y1 + y2;
  #pragma unroll
  for (int off = 32; off; off >>= 1) sum += __shfl_down(sum, off);
  if ((tid & 63) == 0) red[tid >> 6] = sum;
  __syncthreads();
  const float mean = (red[0] + red[1] + red[2] + red[3]) * (1.0f / 768.0f);
  __syncthreads();
  float d0 = y0 - mean, d1 = y1 - mean, d2 = y2 - mean;
  float vs = d0*d0 + d1*d1 + d2*d2;
  #pragma unroll
  for (int off = 32; off; off >>= 1) vs += __shfl_down(vs, off);
  if ((tid & 63) == 0) red[tid >> 6] = vs;
  __syncthreads();
  const float rstd = rsqrtf((red[0]+red[1]+red[2]+red[3]) * (1.0f/768.0f) + 1e-5f);
  float o0 = d0 * rstd * g[tid]       + b[tid];
  float o1 = d1 * rstd * g[tid + 256] + b[tid + 256];
  float o2 = d2 * rstd * g[tid + 512] + b[tid + 512];
  x[pbase + tid] = o0; x[pbase + tid + 256] = o1; x[pbase + tid + 512] = o2;
  xb[pbase + tid] = f2b(o0); xb[pbase + tid + 256] = f2b(o1); xb[pbase + tid + 512] = f2b(o2);
}

// ====== residual(x) + bias + sum of SK split-K partials -> LN -> x (f32) + xb (bf16) ==
template <int SK>
__global__ __launch_bounds__(256) void ln_reduce_kernel(
    const float* __restrict__ parts, const float* __restrict__ bias,
    const float* __restrict__ g, const float* __restrict__ b,
    float* __restrict__ x, unsigned short* __restrict__ xb)
{
  const int s = blockIdx.x, tid = threadIdx.x;
  __shared__ float red[4];
  const size_t base = (size_t)s * DMODEL;
  float y0 = x[base + tid]       + bias[tid];
  float y1 = x[base + tid + 256] + bias[tid + 256];
  float y2 = x[base + tid + 512] + bias[tid + 512];
  #pragma unroll
  for (int k = 0; k < SK; ++k) {
    const float* p = parts + (size_t)k * S_LEN * DMODEL + base;
    y0 += p[tid]; y1 += p[tid + 256]; y2 += p[tid + 512];
  }
  float sum = y0 + y1 + y2;
  #pragma unroll
  for (int off = 32; off; off >>= 1) sum += __shfl_down(sum, off);
  if ((tid & 63) == 0) red[tid >> 6] = sum;
  __syncthreads();
  const float mean = (red[0] + red[1] + red[2] + red[3]) * (1.0f / 768.0f);
  __syncthreads();
  float d0 = y0 - mean, d1 = y1 - mean, d2 = y2 - mean;
  float vs = d0*d0 + d1*d1 + d2*d2;
  #pragma unroll
  for (int off = 32; off; off >>= 1) vs += __shfl_down(vs, off);
  if ((tid & 63) == 0) red[tid >> 6] = vs;
  __syncthreads();
  const float rstd = rsqrtf((red[0]+red[1]+red[2]+red[3]) * (1.0f/768.0f) + 1e-5f);
  float o0 = d0 * rstd * g[tid]       + b[tid];
  float o1 = d1 * rstd * g[tid + 256] + b[tid + 256];
  float o2 = d2 * rstd * g[tid + 512] + b[tid + 512];
  x[base + tid] = o0; x[base + tid + 256] = o1; x[base + tid + 512] = o2;
  xb[base + tid] = f2b(o0); xb[base + tid + 256] = f2b(o1); xb[base + tid + 512] = f2b(o2);
}

__global__ __launch_bounds__(256) void ln_vec_kernel(
    const float* __restrict__ in, const float* __restrict__ g,
    const float* __restrict__ b, float* __restrict__ out)
{
  const int tid = threadIdx.x;
  __shared__ float red[4];
  float y0 = in[tid], y1 = in[tid + 256], y2 = in[tid + 512];
  float sum = y0 + y1 + y2;
  #pragma unroll
  for (int off = 32; off; off >>= 1) sum += __shfl_down(sum, off);
  if ((tid & 63) == 0) red[tid >> 6] = sum;
  __syncthreads();
  const float mean = (red[0] + red[1] + red[2] + red[3]) * (1.0f / 768.0f);
  __syncthreads();
  float d0 = y0 - mean, d1 = y1 - mean, d2 = y2 - mean;
  float vs = d0*d0 + d1*d1 + d2*d2;
  #pragma unroll
  for (int off = 32; off; off >>= 1) vs += __shfl_down(vs, off);
  if ((tid & 63) == 0) red[tid >> 6] = vs;
  __syncthreads();
  const float rstd = rsqrtf((red[0]+red[1]+red[2]+red[3]) * (1.0f/768.0f) + 1e-5f);
  out[tid]       = d0 * rstd * g[tid]       + b[tid];
  out[tid + 256] = d1 * rstd * g[tid + 256] + b[tid + 256];
  out[tid + 512] = d2 * rstd * g[tid + 512] + b[tid + 512];
}

// ====== one-shot weight convert+transpose, 64x64 tiles (f32 [K][N] -> bf16 [N][K]) ====
__global__ __launch_bounds__(256) void conv_all_dd_kernel(
    const float* __restrict__ Wq, const float* __restrict__ Wk, const float* __restrict__ Wv,
    const float* __restrict__ Wkg, const float* __restrict__ Wvg, const float* __restrict__ Wo,
    const float* __restrict__ bq, const float* __restrict__ bk, const float* __restrict__ bv,
    const float* __restrict__ bkg, const float* __restrict__ bvg,
    unsigned short* __restrict__ WqkvT, unsigned short* __restrict__ WoT,
    float* __restrict__ bqkv)
{
  const int z = blockIdx.z, layer = z / 6, mat = z % 6;
  const size_t off = (size_t)layer * DD;
  const float* src = (mat==0?Wq: mat==1?Wk: mat==2?Wv: mat==3?Wkg: mat==4?Wvg: Wo) + off;
  unsigned short* dst = (mat < 5)
      ? (WqkvT + (size_t)layer * 5 * DD + (size_t)mat * DD)
      : (WoT + off);
  __shared__ float tbuf[64][65];
  const int n0 = blockIdx.x * 64, k0 = blockIdx.y * 64;
  const int t = threadIdx.x;
  #pragma unroll
  for (int i = 0; i < 4; ++i) {
    const int idx = i * 256 + t;
    const int r = idx >> 4, c4 = (idx & 15) * 4;
    const float4 v = *(const float4*)&src[(size_t)(k0 + r) * DMODEL + n0 + c4];
    tbuf[r][c4] = v.x; tbuf[r][c4+1] = v.y; tbuf[r][c4+2] = v.z; tbuf[r][c4+3] = v.w;
  }
  __syncthreads();
  const int n = t >> 2, seg = (t & 3) * 16;
  unsigned short o[16];
  #pragma unroll
  for (int i = 0; i < 16; ++i) o[i] = f2b(tbuf[seg + i][n]);
  unsigned short* dp = &dst[(size_t)(n0 + n) * DMODEL + k0 + seg];
  *(short8*)dp = *(const short8*)&o[0];
  *(short8*)(dp + 8) = *(const short8*)&o[8];
  if (mat < 5 && blockIdx.x == 0 && blockIdx.y == 0) {
    const float* bs = (mat==0?bq: mat==1?bk: mat==2?bv: mat==3?bkg: bvg) + (size_t)layer * DMODEL;
    for (int i = t; i < DMODEL; i += 256) bqkv[(size_t)layer * QKV_N + mat * DMODEL + i] = bs[i];
  }
}

__global__ __launch_bounds__(256) void conv_all_ffn_kernel(
    const float* __restrict__ Wf1, const float* __restrict__ Wf2,
    unsigned short* __restrict__ Wf1T, unsigned short* __restrict__ Wf2T)
{
  const int z = blockIdx.z, layer = z / 2, which = z % 2;
  __shared__ float tbuf[64][65];
  const float* src; unsigned short* dst; int Kd, Nd, n0, k0;
  if (which == 0) { src = Wf1 + (size_t)layer * DF; dst = Wf1T + (size_t)layer * DF;
                    Kd = DMODEL; Nd = FFDIM; n0 = blockIdx.x * 64; k0 = blockIdx.y * 64; }
  else            { src = Wf2 + (size_t)layer * DF; dst = Wf2T + (size_t)layer * DF;
                    Kd = FFDIM; Nd = DMODEL; n0 = blockIdx.y * 64; k0 = blockIdx.x * 64; }
  const int t = threadIdx.x;
  #pragma unroll
  for (int i = 0; i < 4; ++i) {
    const int idx = i * 256 + t;
    const int r = idx >> 4, c4 = (idx & 15) * 4;
    const float4 v = *(const float4*)&src[(size_t)(k0 + r) * Nd + n0 + c4];
    tbuf[r][c4] = v.x; tbuf[r][c4+1] = v.y; tbuf[r][c4+2] = v.z; tbuf[r][c4+3] = v.w;
  }
  __syncthreads();
  const int n = t >> 2, seg = (t & 3) * 16;
  unsigned short o[16];
  #pragma unroll
  for (int i = 0; i < 16; ++i) o[i] = f2b(tbuf[seg + i][n]);
  unsigned short* dp = &dst[(size_t)(n0 + n) * Kd + k0 + seg];
  *(short8*)dp = *(const short8*)&o[0];
  *(short8*)(dp + 8) = *(const short8*)&o[8];
}

// ======= bf16 MFMA GEMM (BMx128 tile, BK=64, swizzled LDS, XCD swizzle, residual) =====
template <int BM>
__global__ __launch_bounds__(256) void gemm_mfma_kernel(
    const unsigned short* __restrict__ A, const unsigned short* __restrict__ Bt,
    const float* __restrict__ bias, const float* __restrict__ Res,
    float* __restrict__ Cf, unsigned short* __restrict__ Cb, int N, int K, int act)
{
  constexpr int ASLOTS = BM * 8;
  constexpr int MI = BM / 32;
  __shared__ unsigned short As[ASLOTS * 8];
  __shared__ unsigned short Bs[8192];
  const int tid = threadIdx.x, wave = tid >> 6, lane = tid & 63;
  const int gx = gridDim.x, nwg = gx * gridDim.y;
  int flat = blockIdx.y * gx + blockIdx.x;
  flat = (flat & 7) * (nwg >> 3) + (flat >> 3);
  const int bm = (flat % gx) * BM, bn = (flat / gx) * 128;
  const int wr = (wave >> 1) * (BM / 2), wc = (wave & 1) * 64;
  f32x4 acc[MI][4];
  const f32x4 zz = {0.f, 0.f, 0.f, 0.f};
  #pragma unroll
  for (int i = 0; i < MI; ++i)
    #pragma unroll
    for (int j = 0; j < 4; ++j) acc[i][j] = zz;

  for (int k0 = 0; k0 < K; k0 += 64) {
    #pragma unroll
    for (int it = 0; it < ASLOTS / 256; ++it) {
      const int s = it * 256 + tid;
      const int mr = s >> 3;
      const int kg = (s & 7) ^ (mr & 7);
      const unsigned short* src = A + (size_t)(bm + mr) * K + k0 + kg * 8;
      __builtin_amdgcn_global_load_lds(
          (const __attribute__((address_space(1))) void*)src,
          (__attribute__((address_space(3))) void*)&As[(size_t)(it * 256 + wave * 64) * 8], 16, 0, 0);
    }
    #pragma unroll
    for (int it = 0; it < 4; ++it) {
      const int s = it * 256 + tid;
      const int mr = s >> 3;
      const int kg = (s & 7) ^ (mr & 7);
      const unsigned short* src = Bt + (size_t)(bn + mr) * K + k0 + kg * 8;
      __builtin_amdgcn_global_load_lds(
          (const __attribute__((address_space(1))) void*)src,
          (__attribute__((address_space(3))) void*)&Bs[(size_t)(it * 256 + wave * 64) * 8], 16, 0, 0);
    }
    __syncthreads();
    #pragma unroll
    for (int ks = 0; ks < 2; ++ks) {
      const int kg = ks * 4 + (lane >> 4);
      short8 af[MI], bfr[4];
      #pragma unroll
      for (int i = 0; i < MI; ++i) {
        const int m = wr + i * 16 + (lane & 15);
        af[i] = *(const short8*)&As[(m * 8 + (kg ^ (m & 7))) * 8];
      }
      #pragma unroll
      for (int j = 0; j < 4; ++j) {
        const int n = wc + j * 16 + (lane & 15);
        bfr[j] = *(const short8*)&Bs[(n * 8 + (kg ^ (n & 7))) * 8];
      }
      #pragma unroll
      for (int i = 0; i < MI; ++i)
        #pragma unroll
        for (int j = 0; j < 4; ++j)
          acc[i][j] = __builtin_amdgcn_mfma_f32_16x16x32_bf16(af[i], bfr[j], acc[i][j], 0, 0, 0);
    }
    __syncthreads();
  }

  const int lr = (lane >> 4) * 4, lc = lane & 15;
  #pragma unroll
  for (int i = 0; i < MI; ++i) {
    #pragma unroll
    for (int j = 0; j < 4; ++j) {
      const int n = bn + wc + j * 16 + lc;
      const float bv = bias[n];
      #pragma unroll
      for (int p = 0; p < 4; ++p) {
        const int m = bm + wr + i * 16 + lr + p;
        float val = acc[i][j][p] + bv;
        if (Res) val += Res[(size_t)m * N + n];
        if (act) val = gelu_f(val);
        if (Cf) Cf[(size_t)m * N + n] = val;
        if (Cb) Cb[(size_t)m * N + n] = f2b(val);
      }
    }
  }
}

// ======= split-K bf16 MFMA GEMM partial: Cp[sk][M][N] += A @ Bt^T over K-slice ========
template <int BM, int SK>
__global__ __launch_bounds__(256) void gemm_splitk_kernel(
    const unsigned short* __restrict__ A, const unsigned short* __restrict__ Bt,
    float* __restrict__ Cp, int N, int K)
{
  constexpr int ASLOTS = BM * 8;
  constexpr int MI = BM / 32;
  __shared__ unsigned short As[ASLOTS * 8];
  __shared__ unsigned short Bs[8192];
  const int tid = threadIdx.x, wave = tid >> 6, lane = tid & 63;
  const int gx = gridDim.x, nwg = gx * gridDim.y;
  int flat = blockIdx.y * gx + blockIdx.x;
  flat = (flat & 7) * (nwg >> 3) + (flat >> 3);
  const int bm = (flat % gx) * BM, bn = (flat / gx) * 128;
  const int sk = blockIdx.z;
  const int KS = K / SK;
  const int kbeg = sk * KS;
  const int wr = (wave >> 1) * (BM / 2), wc = (wave & 1) * 64;
  f32x4 acc[MI][4];
  const f32x4 zz = {0.f, 0.f, 0.f, 0.f};
  #pragma unroll
  for (int i = 0; i < MI; ++i)
    #pragma unroll
    for (int j = 0; j < 4; ++j) acc[i][j] = zz;

  for (int k0 = kbeg; k0 < kbeg + KS; k0 += 64) {
    #pragma unroll
    for (int it = 0; it < ASLOTS / 256; ++it) {
      const int s = it * 256 + tid;
      const int mr = s >> 3;
      const int kg = (s & 7) ^ (mr & 7);
      const unsigned short* src = A + (size_t)(bm + mr) * K + k0 + kg * 8;
      __builtin_amdgcn_global_load_lds(
          (const __attribute__((address_space(1))) void*)src,
          (__attribute__((address_space(3))) void*)&As[(size_t)(it * 256 + wave * 64) * 8], 16, 0, 0);
    }
    #pragma unroll
    for (int it = 0; it < 4; ++it) {
      const int s = it * 256 + tid;
      const int mr = s >> 3;
      const int kg = (s & 7) ^ (mr & 7);
      const unsigned short* src = Bt + (size_t)(bn + mr) * K + k0 + kg * 8;
      __builtin_amdgcn_global_load_lds(
          (const __attribute__((address_space(1))) void*)src,
          (__attribute__((address_space(3))) void*)&Bs[(size_t)(it * 256 + wave * 64) * 8], 16, 0, 0);
    }
    __syncthreads();
    #pragma unroll
    for (int ks = 0; ks < 2; ++ks) {
      const int kg = ks * 4 + (lane >> 4);
      short8 af[MI], bfr[4];
      #pragma unroll
      for (int i = 0; i < MI; ++i) {
        const int m = wr + i * 16 + (lane & 15);
        af[i] = *(const short8*)&As[(m * 8 + (kg ^ (m & 7))) * 8];
      }
      #pragma unroll
      for (int j = 0; j < 4; ++j) {
        const int n = wc + j * 16 + (lane & 15);
        bfr[j] = *(const short8*)&Bs[(n * 8 + (kg ^ (n & 7))) * 8];
      }
      #pragma unroll
      for (int i = 0; i < MI; ++i)
        #pragma unroll
        for (int j = 0; j < 4; ++j)
          acc[i][j] = __builtin_amdgcn_mfma_f32_16x16x32_bf16(af[i], bfr[j], acc[i][j], 0, 0, 0);
    }
    __syncthreads();
  }

  float* Co = Cp + (size_t)sk * S_LEN * DMODEL;
  const int lr = (lane >> 4) * 4, lc = lane & 15;
  #pragma unroll
  for (int i = 0; i < MI; ++i) {
    #pragma unroll
    for (int j = 0; j < 4; ++j) {
      const int n = bn + wc + j * 16 + lc;
      #pragma unroll
      for (int p = 0; p < 4; ++p) {
        const int m = bm + wr + i * 16 + lr + p;
        Co[(size_t)m * N + n] = acc[i][j][p];
      }
    }
  }
}

// == fused attention: banded flash half-chunks (y<32) + global CLS segments (y in 32..39) ==
// Banded block = (head, half-chunk): 64 q-rows, 4 waves x 16 rows.
// LDS: Ks 16K | Vt 16K | Ps 8K (64x64) | smcls/sv0/sam -> 41 KB total
__global__ __launch_bounds__(256) void attn_fused_kernel(
    const unsigned short* __restrict__ qkvb, const float* __restrict__ xf,
    const float* __restrict__ Wqg, const float* __restrict__ bqg,
    const int* __restrict__ am, unsigned short* __restrict__ outb,
    float* __restrict__ glbp)
{
  __shared__ __align__(16) unsigned char smem[41984];
  const int h = blockIdx.x, tid = threadIdx.x;

  if (blockIdx.y >= 2 * NCHUNK) {
    // ---------------- global CLS query row: segment g of 256 keys ----------------
    const int g = blockIdx.y - 2 * NCHUNK;  // 0..7
    float* sc  = (float*)smem;            // 256 f32
    float* qs  = (float*)(smem + 1024);   // 64
    float* red = (float*)(smem + 1280);   // 4
    float* pqg = (float*)(smem + 1296);   // 4*64
    float* pb  = (float*)(smem + 2320);   // 32*64 f32 (8 KB)
    const int d = tid & 63, grp = tid >> 6;
    // qg0 slice for this head (redundant per segment block; cheap, concurrent)
    {
      float p = 0.f;
      const float* wcol = Wqg + (size_t)(grp * 192) * DMODEL + h * DHEAD + d;
      #pragma unroll 4
      for (int k = 0; k < 192; ++k)
        p = fmaf(xf[grp * 192 + k], wcol[(size_t)k * DMODEL], p);
      pqg[grp * 64 + d] = p;
    }
    __syncthreads();
    if (tid < 64)
      qs[tid] = (pqg[tid] + pqg[64 + tid] + pqg[128 + tid] + pqg[192 + tid]
                 + bqg[h * DHEAD + tid]) * 0.125f;
    __syncthreads();
    const unsigned short* kg = qkvb + 3 * DMODEL + h * DHEAD;
    const unsigned short* vg = qkvb + 4 * DMODEL + h * DHEAD;
    const int s0 = g * 256 + tid;
    float dd = 0.f;
    {
      const unsigned short* kr = kg + (size_t)s0 * QKV_N;
      #pragma unroll
      for (int d0 = 0; d0 < DHEAD; d0 += 8) {
        const short8 k8 = *(const short8*)(kr + d0);
        #pragma unroll
        for (int e = 0; e < 8; ++e) dd += qs[d0 + e] * b2f((unsigned short)k8[e]);
      }
    }
    const float mysc = (am[s0] > 0) ? dd : -1e9f;
    float mx = mysc;
    #pragma unroll
    for (int off = 32; off; off >>= 1) mx = fmaxf(mx, __shfl_down(mx, off));
    if ((tid & 63) == 0) red[tid >> 6] = mx;
    __syncthreads();
    mx = fmaxf(fmaxf(red[0], red[1]), fmaxf(red[2], red[3]));
    __syncthreads();
    const float e = __expf(mysc - mx);
    sc[tid] = e;
    float sum = e;
    #pragma unroll
    for (int off = 32; off; off >>= 1) sum += __shfl_down(sum, off);
    if ((tid & 63) == 0) red[tid >> 6] = sum;
    __syncthreads();
    const float lsum = red[0] + red[1] + red[2] + red[3];
    // ---- PV over this segment (unnormalized): 32-key x 8-dim split, short8 loads ----
    const int d8 = (tid & 7) * 8, kgrp = tid >> 3;
    float a8[8] = {};
    #pragma unroll
    for (int ii = 0; ii < 8; ++ii) {
      const int loc = kgrp + ii * 32;
      const float p = sc[loc];
      const short8 v8 = *(const short8*)(vg + (size_t)(g * 256 + loc) * QKV_N + d8);
      #pragma unroll
      for (int ee = 0; ee < 8; ++ee) a8[ee] = fmaf(p, b2f((unsigned short)v8[ee]), a8[ee]);
    }
    #pragma unroll
    for (int ee = 0; ee < 8; ++ee) pb[kgrp * 64 + d8 + ee] = a8[ee];
    __syncthreads();
    float* pr = glbp + (size_t)(h * 8 + g) * 66;
    if (tid < 64) {
      float o = 0.f;
      #pragma unroll
      for (int k = 0; k < 32; ++k) o += pb[k * 64 + tid];
      pr[2 + tid] = o;
    }
    if (tid == 0) { pr[0] = mx; pr[1] = lsum; }
    return;
  }

  // ---------------- banded sliding-window flash: 64 q-rows per block ----------------
  const int nc = blockIdx.y >> 1;            // chunk
  const int qoff = (blockIdx.y & 1) * 64;    // half within chunk
  const int wave = tid >> 6, lane = tid & 63;
  const int c = lane & 15, g = lane >> 4;
  unsigned short* Ks = (unsigned short*)smem;             // 16 KB
  unsigned short* Vt = (unsigned short*)(smem + 16384);   // 16 KB
  unsigned short* Ps = (unsigned short*)(smem + 32768);   // 8 KB ([64 rows][64 keys])
  float* smcls = (float*)(smem + 40960);                  // 256 B (64 rows)
  float* sv0   = (float*)(smem + 41216);                  // 256 B
  int*   sam   = (int*)(smem + 41472);                    // 512 B

  if (tid < 64) sv0[tid] = b2f(qkvb[2 * DMODEL + h * DHEAD + tid]);
  if (tid >= 128 && tid < 192) {
    const int rl = tid - 128;
    const int qrow = nc * CHUNK + qoff + rl;
    const unsigned short* qp = qkvb + (size_t)qrow * QKV_N + h * DHEAD;
    const unsigned short* k0 = qkvb + DMODEL + h * DHEAD;
    float d = 0.f;
    #pragma unroll
    for (int dd = 0; dd < 64; dd += 8) {
      const short8 a8 = *(const short8*)(qp + dd);
      const short8 b8 = *(const short8*)(k0 + dd);
      #pragma unroll
      for (int e = 0; e < 8; ++e)
        d += b2f((unsigned short)a8[e]) * b2f((unsigned short)b8[e]);
    }
    smcls[rl] = (am[0] > 0) ? d * 0.125f : -1e9f;
  }

  // Q fragments: wave owns 16 rows
  short8 af[2];
  #pragma unroll
  for (int ks = 0; ks < 2; ++ks) {
    const int qrow = nc * CHUNK + qoff + wave * 16 + c;
    af[ks] = *(const short8*)(qkvb + (size_t)qrow * QKV_N + h * DHEAD + (ks * 4 + g) * 8);
  }

  __syncthreads();

  float mrow[4], lrow[4];
  f32x4 acc_o[4];
  #pragma unroll
  for (int p = 0; p < 4; ++p) {
    mrow[p] = smcls[wave * 16 + g * 4 + p];
    lrow[p] = 1.f;
  }
  #pragma unroll
  for (int j = 0; j < 4; ++j) {
    const float v0 = sv0[j * 16 + c];
    acc_o[j][0] = v0; acc_o[j][1] = v0; acc_o[j][2] = v0; acc_o[j][3] = v0;
  }

  for (int kci = 0; kci < 3; ++kci) {
    const int ck = nc - 1 + kci;
    if (ck < 0 || ck > 15) continue;
    __syncthreads();

    #pragma unroll
    for (int it = 0; it < 4; ++it) {
      const int sidx = it * 256 + tid;
      const int mr = sidx >> 3;
      const int kg = (sidx & 7) ^ (mr & 7);
      const unsigned short* src = qkvb + (size_t)(ck * CHUNK + mr) * QKV_N + DMODEL + h * DHEAD + kg * 8;
      __builtin_amdgcn_global_load_lds(
          (const __attribute__((address_space(1))) void*)src,
          (__attribute__((address_space(3))) void*)&Ks[(size_t)(it * 256 + wave * 64) * 8], 16, 0, 0);
    }
    {
      const int kp = tid & 63, dh = tid >> 6;
      const unsigned short* v0p = qkvb + (size_t)(ck * CHUNK + 2 * kp) * QKV_N + 2 * DMODEL + h * DHEAD + dh * 16;
      const short8 a0 = *(const short8*)(v0p);
      const short8 a1 = *(const short8*)(v0p + 8);
      const short8 b0 = *(const short8*)(v0p + QKV_N);
      const short8 b1 = *(const short8*)(v0p + QKV_N + 8);
      #pragma unroll
      for (int dd = 0; dd < 16; ++dd) {
        const int dim = dh * 16 + dd;
        const unsigned short lo = (unsigned short)(dd < 8 ? a0[dd] : a1[dd - 8]);
        const unsigned short hi = (unsigned short)(dd < 8 ? b0[dd] : b1[dd - 8]);
        const unsigned int w = (unsigned int)lo | ((unsigned int)hi << 16);
        const int si = dim * 128 + (((kp >> 2) ^ (dim & 7)) << 3) + ((kp & 3) << 1);
        *(unsigned int*)&Vt[si] = w;
      }
    }
    if (tid < 128) sam[tid] = am[ck * CHUNK + tid];
    __syncthreads();

    // preload this thread's am-mask values (one per key-frag column)
    int am8[8];
    #pragma unroll
    for (int j = 0; j < 8; ++j) am8[j] = sam[j * 16 + c];

    // ---- S = Q @ K^T (16 q-rows x 128 keys per wave) ----
    f32x4 accs[8];
    const f32x4 zz = {0.f, 0.f, 0.f, 0.f};
    #pragma unroll
    for (int j = 0; j < 8; ++j) accs[j] = zz;
    __builtin_amdgcn_s_setprio(1);
    #pragma unroll
    for (int ks = 0; ks < 2; ++ks) {
      const int kg = ks * 4 + g;
      short8 bfr[8];
      #pragma unroll
      for (int j = 0; j < 8; ++j) {
        const int jj = j * 16 + c;
        bfr[j] = *(const short8*)&Ks[(jj * 8 + (kg ^ (jj & 7))) * 8];
      }
      #pragma unroll
      for (int j = 0; j < 8; ++j)
        accs[j] = __builtin_amdgcn_mfma_f32_16x16x32_bf16(af[ks], bfr[j], accs[j], 0, 0, 0);
    }
    __builtin_amdgcn_s_setprio(0);

    // ---- two 64-key halves: mask + online softmax + P write + PV ----
    #pragma unroll
    for (int h2 = 0; h2 < 2; ++h2) {
      #pragma unroll
      for (int p = 0; p < 4; ++p) {
        const int mlocal = wave * 16 + g * 4 + p;        // row within block (0..63)
        const int qi = nc * CHUNK + qoff + mlocal;
        float sv[4];
        float rmax = -1e30f;
        #pragma unroll
        for (int j = 0; j < 4; ++j) {
          const int jg = h2 * 4 + j;
          const int jj = jg * 16 + c;
          const int kj = ck * CHUNK + jj;
          const int diff = qi - kj;
          const bool ok = (diff <= 128) && (diff >= -128) && (kj != 0) && (am8[jg] > 0);
          const float s = ok ? accs[jg][p] * 0.125f : -1e9f;
          sv[j] = s;
          rmax = fmaxf(rmax, s);
        }
        rmax = fmaxf(rmax, __shfl_xor(rmax, 1));
        rmax = fmaxf(rmax, __shfl_xor(rmax, 2));
        rmax = fmaxf(rmax, __shfl_xor(rmax, 4));
        rmax = fmaxf(rmax, __shfl_xor(rmax, 8));
        const float mnew = fmaxf(mrow[p], rmax);
        const float corr = __expf(mrow[p] - mnew);
        float psum = 0.f;
        #pragma unroll
        for (int j = 0; j < 4; ++j) {
          const float pv = __expf(sv[j] - mnew);
          sv[j] = pv;
          psum += pv;
        }
        psum += __shfl_xor(psum, 1);
        psum += __shfl_xor(psum, 2);
        psum += __shfl_xor(psum, 4);
        psum += __shfl_xor(psum, 8);
        lrow[p] = lrow[p] * corr + psum;
        mrow[p] = mnew;
        #pragma unroll
        for (int j = 0; j < 4; ++j) acc_o[j][p] *= corr;
        #pragma unroll
        for (int j = 0; j < 4; ++j) {
          const int keyh = j * 16 + c;            // key within half
          const int kslot = keyh >> 3;            // 0..7
          Ps[mlocal * 64 + ((kslot ^ (mlocal & 7)) << 3) + (keyh & 7)] = f2b(sv[j]);
        }
      }
      // wave-private P rows: drain LDS writes before cross-lane reads
      asm volatile("s_waitcnt lgkmcnt(0)" ::: "memory");

      __builtin_amdgcn_s_setprio(1);
      #pragma unroll
      for (int s2 = 0; s2 < 2; ++s2) {
        const int kslot = s2 * 4 + g;               // within half: 0..7
        const int kg2 = h2 * 8 + kslot;             // within tile: 0..15
        short8 pa, vb[4];
        {
          const int row = wave * 16 + c;
          pa = *(const short8*)&Ps[row * 64 + ((kslot ^ (row & 7)) << 3)];
        }
        #pragma unroll
        for (int j = 0; j < 4; ++j) {
          const int n = j * 16 + c;
          vb[j] = *(const short8*)&Vt[n * 128 + ((kg2 ^ (n & 7)) << 3)];
        }
        #pragma unroll
        for (int j = 0; j < 4; ++j)
          acc_o[j] = __builtin_amdgcn_mfma_f32_16x16x32_bf16(pa, vb[j], acc_o[j], 0, 0, 0);
      }
      __builtin_amdgcn_s_setprio(0);
    }
  }

  #pragma unroll
  for (int p = 0; p < 4; ++p) {
    const float rl = (lrow[p] > 0.f) ? 1.f / lrow[p] : 0.f;
    const int row = nc * CHUNK + qoff + wave * 16 + g * 4 + p;
    if (row == 0) continue;  // row 0 owned by the global path
    #pragma unroll
    for (int j = 0; j < 4; ++j)
      outb[(size_t)row * DMODEL + h * DHEAD + j * 16 + c] = f2b(acc_o[j][p] * rl);
  }
}

// ================= global CLS combine: merge 8 segment partials -> row 0 =============
__global__ __launch_bounds__(64) void glb_attn_combine_kernel(
    const float* __restrict__ part, unsigned short* __restrict__ outb)
{
  const int h = blockIdx.x, d = threadIdx.x;
  float M = -1e30f;
  for (int g = 0; g < 8; ++g) M = fmaxf(M, part[(size_t)(h * 8 + g) * 66]);
  float L = 0.f, o = 0.f;
  for (int g = 0; g < 8; ++g) {
    const float* pr = part + (size_t)(h * 8 + g) * 66;
    const float cc = (pr[0] > -1e8f) ? __expf(pr[0] - M) : 0.f;
    L += pr[1] * cc;
    o += pr[2 + d] * cc;
  }
  outb[h * DHEAD + d] = f2b(o / L);
}

// ================= split-k GEMV (head MLP only) =================
__global__ __launch_bounds__(256) void gemv_partial_kernel(
    const float* __restrict__ xrow, const float* __restrict__ W, float* __restrict__ part)
{
  const int b = blockIdx.x, t = threadIdx.x;
  float s0 = 0.f, s1 = 0.f, s2 = 0.f;
  for (int kk = 0; kk < 48; ++kk) {
    const int k = b * 48 + kk;
    const float xv = xrow[k];
    const float* wr = W + (size_t)k * DMODEL;
    s0 = fmaf(xv, wr[t], s0);
    s1 = fmaf(xv, wr[t + 256], s1);
    s2 = fmaf(xv, wr[t + 512], s2);
  }
  part[b * DMODEL + t] = s0;
  part[b * DMODEL + t + 256] = s1;
  part[b * DMODEL + t + 512] = s2;
}

__global__ __launch_bounds__(256) void gemv_reduce_kernel(
    const float* __restrict__ part, const float* __restrict__ bias,
    float* __restrict__ y, int act)
{
  const int n = blockIdx.x * 256 + threadIdx.x;
  float s = bias[n];
  #pragma unroll
  for (int b = 0; b < 16; ++b) s += part[b * DMODEL + n];
  if (act) s = gelu_f(s);
  y[n] = s;
}

// ================= final head =================
__global__ __launch_bounds__(256) void head_final_kernel(
    const float* __restrict__ h2, const float* __restrict__ Wout,
    const float* __restrict__ bout, float* __restrict__ out)
{
  const int tid = threadIdx.x;
  __shared__ float red[4];
  float p = h2[tid]*Wout[tid] + h2[tid+256]*Wout[tid+256] + h2[tid+512]*Wout[tid+512];
  #pragma unroll
  for (int off = 32; off; off >>= 1) p += __shfl_down(p, off);
  if ((tid & 63) == 0) red[tid >> 6] = p;
  __syncthreads();
  if (tid == 0) {
    const float logit = red[0] + red[1] + red[2] + red[3] + bout[0];
    const float sig = 1.0f / (1.0f + expf(-logit));
    const unsigned int bits = __float_as_uint(sig);
    const unsigned int bf = (bits + 0x7FFFu + ((bits >> 16) & 1u)) >> 16;
    out[0] = __uint_as_float((bits & 0xFFFF0000u) | (bf & 0xFFFFu));
  }
}

extern "C" void kernel_launch(void* const* d_in, const int* in_sizes, int n_in,
                              void* d_out, int out_size, void* d_ws, size_t ws_size,
                              hipStream_t stream)
{
  const int*   ids  = (const int*)d_in[0];
  const int*   am   = (const int*)d_in[1];
  const float* wemb = (const float*)d_in[2];
  const float* pemb = (const float*)d_in[3];
  const float* emb_g = (const float*)d_in[4];
  const float* emb_b = (const float*)d_in[5];
  const float* Wq  = (const float*)d_in[6];
  const float* bq  = (const float*)d_in[7];
  const float* Wk  = (const float*)d_in[8];
  const float* bk  = (const float*)d_in[9];
  const float* Wv  = (const float*)d_in[10];
  const float* bv  = (const float*)d_in[11];
  const float* Wqg = (const float*)d_in[12];
  const float* bqg = (const float*)d_in[13];
  const float* Wkg = (const float*)d_in[14];
  const float* bkg = (const float*)d_in[15];
  const float* Wvg = (const float*)d_in[16];
  const float* bvg = (const float*)d_in[17];
  const float* Wo  = (const float*)d_in[18];
  const float* bo  = (const float*)d_in[19];
  const float* ln1g = (const float*)d_in[20];
  const float* ln1b = (const float*)d_in[21];
  const float* Wf1 = (const float*)d_in[22];
  const float* bf1 = (const float*)d_in[23];
  const float* Wf2 = (const float*)d_in[24];
  const float* bf2 = (const float*)d_in[25];
  const float* ln2g = (const float*)d_in[26];
  const float* ln2b = (const float*)d_in[27];
  const float* hng = (const float*)d_in[28];
  const float* hnb = (const float*)d_in[29];
  const float* W1  = (const float*)d_in[30];
  const float* b1  = (const float*)d_in[31];
  const float* W2  = (const float*)d_in[32];
  const float* b2  = (const float*)d_in[33];
  const float* Wout = (const float*)d_in[34];
  const float* bout = (const float*)d_in[35];

  char* wp = (char*)d_ws;
  auto alloc = [&](size_t bytes) -> void* {
    void* r = (void*)wp;
    wp += (bytes + 255) & ~(size_t)255;
    return r;
  };
  float*          x         = (float*)alloc((size_t)S_LEN * DMODEL * 4);
  unsigned short* xb        = (unsigned short*)alloc((size_t)S_LEN * DMODEL * 2);
  unsigned short* qkvb      = (unsigned short*)alloc((size_t)S_LEN * QKV_N * 2);
  unsigned short* attnb     = (unsigned short*)alloc((size_t)S_LEN * DMODEL * 2);
  unsigned short* tmpb      = (unsigned short*)alloc((size_t)S_LEN * FFDIM * 2);
  float*          parts     = (float*)alloc((size_t)4 * S_LEN * DMODEL * 4);
  unsigned short* WqkvT_all = (unsigned short*)alloc((size_t)NLAYER * 5 * DD * 2);
  unsigned short* WoT_all   = (unsigned short*)alloc((size_t)NLAYER * DD * 2);
  unsigned short* Wf1T_all  = (unsigned short*)alloc((size_t)NLAYER * DF * 2);
  unsigned short* Wf2T_all  = (unsigned short*)alloc((size_t)NLAYER * DF * 2);
  float*          bqkv_all  = (float*)alloc((size_t)NLAYER * QKV_N * 4);
  float*          glbp      = (float*)alloc((size_t)NHEAD * 8 * 66 * 4);
  float*          gpart     = (float*)alloc((size_t)16 * DMODEL * 4);
  float*          hb        = (float*)alloc((size_t)3 * DMODEL * 4);

  // one-shot weight conversion for all layers (BW-bound, 2 launches)
  conv_all_dd_kernel<<<dim3(12, 12, 6 * NLAYER), 256, 0, stream>>>(
      Wq, Wk, Wv, Wkg, Wvg, Wo, bq, bk, bv, bkg, bvg, WqkvT_all, WoT_all, bqkv_all);
  conv_all_ffn_kernel<<<dim3(48, 12, 2 * NLAYER), 256, 0, stream>>>(
      Wf1, Wf2, Wf1T_all, Wf2T_all);

  embed_ln_kernel<<<S_LEN, 256, 0, stream>>>(ids, wemb, pemb, emb_g, emb_b, x, xb);

  for (int l = 0; l < NLAYER; ++l) {
    const size_t wdd = (size_t)l * DD;
    const size_t vd  = (size_t)l * DMODEL;
    const size_t vf  = (size_t)l * FFDIM;
    const unsigned short* WqkvT = WqkvT_all + (size_t)l * 5 * DD;
    const unsigned short* WoT   = WoT_all + wdd;
    const unsigned short* Wf1T  = Wf1T_all + (size_t)l * DF;
    const unsigned short* Wf2T  = Wf2T_all + (size_t)l * DF;
    const float* bqkv = bqkv_all + (size_t)l * QKV_N;

    // fused q|k|v|kg|vg projection: [2048,768] @ [768,3840] -> bf16 (BM=64: 960 blocks)
    gemm_mfma_kernel<64><<<dim3(32, 30), 256, 0, stream>>>(
        xb, WqkvT, bqkv, (const float*)nullptr, (float*)nullptr, qkvb, QKV_N, DMODEL, 0);

    // banded flash half-chunks (384 blocks) + global CLS segments (96 blocks)
    attn_fused_kernel<<<dim3(NHEAD, 2 * NCHUNK + 8), 256, 0, stream>>>(
        qkvb, x, Wqg + wdd, bqg + vd, am, attnb, glbp);
    glb_attn_combine_kernel<<<NHEAD, 64, 0, stream>>>(glbp, attnb);

    // Wo projection: split-K=2 partials, then fused reduce+bias+residual+LN
    gemm_splitk_kernel<64, 2><<<dim3(32, 6, 2), 256, 0, stream>>>(
        attnb, WoT, parts, DMODEL, DMODEL);
    ln_reduce_kernel<2><<<S_LEN, 256, 0, stream>>>(
        parts, bo + vd, ln1g + vd, ln1b + vd, x, xb);

    // FFN1: [2048,768] @ [768,3072] + GELU -> bf16 (BM=64: 768 blocks)
    gemm_mfma_kernel<64><<<dim3(32, 24), 256, 0, stream>>>(
        xb, Wf1T, bf1 + vf, (const float*)nullptr, (float*)nullptr, tmpb, FFDIM, DMODEL, 1);

    // FFN2: split-K=4 partials, then fused reduce+bias+residual+LN
    gemm_splitk_kernel<64, 4><<<dim3(32, 6, 4), 256, 0, stream>>>(
        tmpb, Wf2T, parts, DMODEL, FFDIM);
    ln_reduce_kernel<4><<<S_LEN, 256, 0, stream>>>(
        parts, bf2 + vd, ln2g + vd, ln2b + vd, x, xb);
  }

  ln_vec_kernel<<<1, 256, 0, stream>>>(x, hng, hnb, hb);
  gemv_partial_kernel<<<16, 256, 0, stream>>>(hb, W1, gpart);
  gemv_reduce_kernel<<<3, 256, 0, stream>>>(gpart, b1, hb + DMODEL, 1);
  gemv_partial_kernel<<<16, 256, 0, stream>>>(hb + DMODEL, W2, gpart);
  gemv_reduce_kernel<<<3, 256, 0, stream>>>(gpart, b2, hb + 2 * DMODEL, 1);
  head_final_kernel<<<1, 256, 0, stream>>>(hb + 2 * DMODEL, Wout, bout, (float*)d_out);
}